// Round 3
// baseline (1033.531 us; speedup 1.0000x reference)
//
#include <hip/hip_runtime.h>
#include <cstdint>

typedef unsigned long long u64;

// ---------------------------------------------------------------------------
// HCHA (hypergraph conv with attention), f32.
// N=100000 nodes, M=20000 hyperedges, NNZ=1e6, C=128, HEADS=4, FH=32.
// CSR build via 2-pass counting sort (coarse bucket partition -> LDS sort),
// payloads packed u64 so sorted node/edge id streams come out coalesced.
// Packing assumes i < 2^20 (NNZ=1e6), e < 2^15 (M=20000), n < 2^17 (N=1e5).
// ---------------------------------------------------------------------------

#define E_SHIFT 6
#define N_SHIFT 7
#define EB_CAP 4096
#define NB_CAP 2048

__global__ __launch_bounds__(256) void count_deg(const int* __restrict__ node_idx,
                                                 const int* __restrict__ edge_idx,
                                                 unsigned* __restrict__ cnt_n,
                                                 unsigned* __restrict__ cnt_e, int nnz) {
  int i = blockIdx.x * 256 + threadIdx.x;
  if (i < nnz) {
    atomicAdd(&cnt_n[node_idx[i]], 1u);
    atomicAdd(&cnt_e[edge_idx[i]], 1u);
  }
}

__device__ __forceinline__ unsigned wave_incl_scan(unsigned x) {
#pragma unroll
  for (int s = 1; s < 64; s <<= 1) {
    unsigned t = __shfl_up(x, s, 64);
    if ((int)(threadIdx.x & 63) >= s) x += t;
  }
  return x;
}

__global__ __launch_bounds__(1024) void scan_pass1(const unsigned* __restrict__ cnt,
                                                   unsigned* __restrict__ bsum, int L) {
  int i = blockIdx.x * 1024 + threadIdx.x;
  unsigned v = (i < L) ? cnt[i] : 0u;
  unsigned incl = wave_incl_scan(v);
  __shared__ unsigned wsum[16];
  int lane = threadIdx.x & 63, wid = threadIdx.x >> 6;
  if (lane == 63) wsum[wid] = incl;
  __syncthreads();
  if (threadIdx.x == 0) {
    unsigned t = 0;
#pragma unroll
    for (int w = 0; w < 16; ++w) t += wsum[w];
    bsum[blockIdx.x] = t;
  }
}

__global__ __launch_bounds__(1024) void scan_pass2(const unsigned* __restrict__ bsum,
                                                   unsigned* __restrict__ boff, int nb) {
  int i = threadIdx.x;
  unsigned v = (i < nb) ? bsum[i] : 0u;
  unsigned incl = wave_incl_scan(v);
  __shared__ unsigned wsum[16];
  int lane = threadIdx.x & 63, wid = threadIdx.x >> 6;
  if (lane == 63) wsum[wid] = incl;
  __syncthreads();
  unsigned add = 0;
  for (int w = 0; w < wid; ++w) add += wsum[w];
  if (i < nb) boff[i] = add + incl - v;  // exclusive
}

__global__ __launch_bounds__(1024) void scan_pass3(const unsigned* __restrict__ cnt,
                                                   const unsigned* __restrict__ boff,
                                                   unsigned* __restrict__ off, int L) {
  int i = blockIdx.x * 1024 + threadIdx.x;
  unsigned v = (i < L) ? cnt[i] : 0u;
  unsigned incl = wave_incl_scan(v);
  __shared__ unsigned wsum[16];
  int lane = threadIdx.x & 63, wid = threadIdx.x >> 6;
  if (lane == 63) wsum[wid] = incl;
  __syncthreads();
  unsigned add = boff[blockIdx.x];
  for (int w = 0; w < wid; ++w) add += wsum[w];
  unsigned excl = add + incl - v;
  if (i < L) off[i] = excl;
  if (i == L) off[L] = excl;  // total
}

__global__ __launch_bounds__(256) void make_inv(const unsigned* __restrict__ cnt,
                                                float* __restrict__ inv, int L) {
  int i = blockIdx.x * 256 + threadIdx.x;
  if (i < L) inv[i] = cnt[i] ? 1.f / (float)cnt[i] : 0.f;
}

__global__ __launch_bounds__(256) void init_bcur(const unsigned* __restrict__ eoff,
                                                 const unsigned* __restrict__ noff,
                                                 unsigned* __restrict__ bcur_e,
                                                 unsigned* __restrict__ bcur_n,
                                                 int nbe, int nbn, int M_, int N_) {
  int i = blockIdx.x * 256 + threadIdx.x;
  if (i < nbe) bcur_e[i] = eoff[min(i << E_SHIFT, M_)];
  if (i < nbn) bcur_n[i] = noff[min(i << N_SHIFT, N_)];
}

// pass B: scatter packed payloads into coarse-bucket regions (frontier writes)
__global__ __launch_bounds__(256) void partition(const int* __restrict__ node_idx,
                                                 const int* __restrict__ edge_idx,
                                                 unsigned* __restrict__ bcur_e,
                                                 unsigned* __restrict__ bcur_n,
                                                 u64* __restrict__ tmp_e,
                                                 u64* __restrict__ tmp_n, int nnz) {
  int i = blockIdx.x * 256 + threadIdx.x;
  if (i >= nnz) return;
  unsigned n = (unsigned)node_idx[i], e = (unsigned)edge_idx[i];
  unsigned pe = atomicAdd(&bcur_e[e >> E_SHIFT], 1u);
  tmp_e[pe] = ((u64)(e & 63u) << 37) | ((u64)n << 20) | (unsigned)i;
  unsigned pn = atomicAdd(&bcur_n[n >> N_SHIFT], 1u);
  tmp_n[pn] = ((u64)(n & 127u) << 35) | ((u64)e << 20) | (unsigned)i;
}

// pass C (edges): per-bucket LDS counting sort; coalesced eperm + enid writes
__global__ __launch_bounds__(256) void sort_edge(const u64* __restrict__ tmp,
                                                 const unsigned* __restrict__ eoff,
                                                 int M_, unsigned* __restrict__ eperm,
                                                 int* __restrict__ enid) {
  __shared__ unsigned cur[64];
  __shared__ u64 sbuf[EB_CAP];
  int b = blockIdx.x, t = threadIdx.x;
  int e0 = b << E_SHIFT;
  unsigned base = eoff[min(e0, M_)];
  unsigned end  = eoff[min(e0 + 64, M_)];
  if (t < 64) cur[t] = eoff[min(e0 + t, M_)] - base;
  __syncthreads();
  int cnt = (int)(end - base);
  for (int idx = t; idx < cnt; idx += 256) {
    u64 p = tmp[base + idx];
    unsigned key = (unsigned)(p >> 37) & 63u;
    unsigned pos = atomicAdd(&cur[key], 1u);
    if (pos < EB_CAP) {
      sbuf[pos] = p;
    } else {  // overflow fallback (statistically never): direct global write
      eperm[base + pos] = (unsigned)(p & 0xFFFFFu);
      enid[base + pos]  = (int)((p >> 20) & 0x1FFFFu);
    }
  }
  __syncthreads();
  int lim = min(cnt, EB_CAP);
  for (int idx = t; idx < lim; idx += 256) {
    u64 p = sbuf[idx];
    eperm[base + idx] = (unsigned)(p & 0xFFFFFu);
    enid[base + idx]  = (int)((p >> 20) & 0x1FFFFu);
  }
}

// pass C (nodes): coalesced nperm + neid writes
__global__ __launch_bounds__(256) void sort_node(const u64* __restrict__ tmp,
                                                 const unsigned* __restrict__ noff,
                                                 int N_, unsigned* __restrict__ nperm,
                                                 int* __restrict__ neid) {
  __shared__ unsigned cur[128];
  __shared__ u64 sbuf[NB_CAP];
  int b = blockIdx.x, t = threadIdx.x;
  int n0 = b << N_SHIFT;
  unsigned base = noff[min(n0, N_)];
  unsigned end  = noff[min(n0 + 128, N_)];
  if (t < 128) cur[t] = noff[min(n0 + t, N_)] - base;
  __syncthreads();
  int cnt = (int)(end - base);
  for (int idx = t; idx < cnt; idx += 256) {
    u64 p = tmp[base + idx];
    unsigned key = (unsigned)(p >> 35) & 127u;
    unsigned pos = atomicAdd(&cur[key], 1u);
    if (pos < NB_CAP) {
      sbuf[pos] = p;
    } else {
      nperm[base + pos] = (unsigned)(p & 0xFFFFFu);
      neid[base + pos]  = (int)((p >> 20) & 0x7FFFu);
    }
  }
  __syncthreads();
  int lim = min(cnt, NB_CAP);
  for (int idx = t; idx < lim; idx += 256) {
    u64 p = sbuf[idx];
    nperm[base + idx] = (unsigned)(p & 0xFFFFFu);
    neid[base + idx]  = (int)((p >> 20) & 0x7FFFu);
  }
}

// C[r,o] = sum_k A[r,k] * W[o,k];  A: rows x 128, W: 128 x 128 (row-major)
#define GM 32
__global__ __launch_bounds__(256) void gemm128(const float* __restrict__ A,
                                               const float* __restrict__ W,
                                               float* __restrict__ C, int rows) {
  __shared__ __align__(16) float Ast[128 * 36];  // Ast[k][r], r-pad to 36
  __shared__ __align__(16) float Wt[64 * 132];   // Wt[k][o], k half-tile
  const int tid = threadIdx.x;
  const int row0 = blockIdx.x * GM;

  for (int idx = tid; idx < GM * 128; idx += 256) {
    int r = idx >> 7, k = idx & 127;
    int gr = row0 + r;
    Ast[k * 36 + r] = (gr < rows) ? A[(size_t)gr * 128 + k] : 0.f;
  }

  const int tr = tid >> 5, tc = tid & 31;
  const int r0 = tr * 4, c0 = tc * 4;
  float acc[4][4] = {{0.f}};

  for (int kh = 0; kh < 2; ++kh) {
    __syncthreads();
    for (int idx = tid; idx < 128 * 64; idx += 256) {
      int o = idx >> 6, k = idx & 63;
      Wt[k * 132 + o] = W[o * 128 + kh * 64 + k];
    }
    __syncthreads();
#pragma unroll 8
    for (int k = 0; k < 64; ++k) {
      const int kk = kh * 64 + k;
      float4 a = *(const float4*)&Ast[kk * 36 + r0];
      float4 b = *(const float4*)&Wt[k * 132 + c0];
      acc[0][0] += a.x * b.x; acc[0][1] += a.x * b.y; acc[0][2] += a.x * b.z; acc[0][3] += a.x * b.w;
      acc[1][0] += a.y * b.x; acc[1][1] += a.y * b.y; acc[1][2] += a.y * b.z; acc[1][3] += a.y * b.w;
      acc[2][0] += a.z * b.x; acc[2][1] += a.z * b.y; acc[2][2] += a.z * b.z; acc[2][3] += a.z * b.w;
      acc[3][0] += a.w * b.x; acc[3][1] += a.w * b.y; acc[3][2] += a.w * b.z; acc[3][3] += a.w * b.w;
    }
  }
#pragma unroll
  for (int i = 0; i < 4; ++i) {
    int gr = row0 + r0 + i;
    if (gr < rows)
      *(float4*)&C[(size_t)gr * 128 + c0] = make_float4(acc[i][0], acc[i][1], acc[i][2], acc[i][3]);
  }
}

// ai[v,h] = sum_f feat[v, h*32+f] * att[h*64 + f]
__global__ __launch_bounds__(256) void att_dot(const float* __restrict__ feat,
                                               const float* __restrict__ att,
                                               float* __restrict__ outv, int rows) {
  int idx = blockIdx.x * 256 + threadIdx.x;
  if (idx >= rows * 4) return;
  int v = idx >> 2, h = idx & 3;
  const float4* fp = (const float4*)(feat + (size_t)v * 128 + h * 32);
  const float4* ap = (const float4*)(att + h * 64);
  float s = 0.f;
#pragma unroll
  for (int q = 0; q < 8; ++q) {
    float4 a = ap[q], f = fp[q];
    s += a.x * f.x + a.y * f.y + a.z * f.z + a.w * f.w;
  }
  outv[idx] = s;
}

// u[h,k] = sum_f att1[h*64+32+f] * W_he[(h*32+f)*128 + k]
__global__ __launch_bounds__(256) void make_u(const float* __restrict__ W_he,
                                              const float* __restrict__ att1,
                                              float* __restrict__ u) {
  int idx = blockIdx.x * 256 + threadIdx.x;
  if (idx >= 512) return;
  int h = idx >> 7, k = idx & 127;
  float s = 0.f;
#pragma unroll
  for (int f = 0; f < 32; ++f)
    s += att1[h * 64 + 32 + f] * W_he[(size_t)(h * 32 + f) * 128 + k];
  u[h * 128 + k] = s;
}

// aj[e,h] = hea[e,:] . u[h,:]
__global__ __launch_bounds__(256) void att_dot_full(const float* __restrict__ feat,
                                                    const float* __restrict__ u,
                                                    float* __restrict__ outv, int rows) {
  int idx = blockIdx.x * 256 + threadIdx.x;
  if (idx >= rows * 4) return;
  int v = idx >> 2, h = idx & 3;
  const float4* fp = (const float4*)(feat + (size_t)v * 128);
  const float4* up = (const float4*)(u + h * 128);
  float s = 0.f;
#pragma unroll
  for (int q = 0; q < 32; ++q) {
    float4 a = up[q], f = fp[q];
    s += a.x * f.x + a.y * f.y + a.z * f.z + a.w * f.w;
  }
  outv[idx] = s;
}

// ealpha[i,h] = exp(leakyrelu(ai[n,h] + aj[e,h]))
__global__ __launch_bounds__(256) void entry_exp(const int* __restrict__ node_idx,
                                                 const int* __restrict__ edge_idx,
                                                 const float* __restrict__ ai,
                                                 const float* __restrict__ aj,
                                                 float* __restrict__ ealpha, int nnz) {
  int i = blockIdx.x * 256 + threadIdx.x;
  if (i >= nnz) return;
  int n = node_idx[i], e = edge_idx[i];
  float4 av = *(const float4*)&ai[(size_t)n * 4];
  float4 bv = *(const float4*)&aj[(size_t)e * 4];
  float v0 = av.x + bv.x, v1 = av.y + bv.y, v2 = av.z + bv.z, v3 = av.w + bv.w;
  v0 = v0 > 0.f ? v0 : 0.2f * v0;
  v1 = v1 > 0.f ? v1 : 0.2f * v1;
  v2 = v2 > 0.f ? v2 : 0.2f * v2;
  v3 = v3 > 0.f ? v3 : 0.2f * v3;
  *(float4*)&ealpha[(size_t)i * 4] = make_float4(expf(v0), expf(v1), expf(v2), expf(v3));
}

// rden[v,h] = 1/(sum ealpha + 1e-16); also emits ealpha_n (node-sorted alphas)
__global__ __launch_bounds__(256) void node_denom(const unsigned* __restrict__ noff,
                                                  const unsigned* __restrict__ nperm,
                                                  const float* __restrict__ ealpha,
                                                  float* __restrict__ ealpha_n,
                                                  float* __restrict__ rden, int N) {
  int v = blockIdx.x * 256 + threadIdx.x;
  if (v >= N) return;
  unsigned s = noff[v], en = noff[v + 1];
  float x = 0.f, y = 0.f, z = 0.f, w = 0.f;
  unsigned j = s;
  for (; j + 2 <= en; j += 2) {
    float4 a = *(const float4*)&ealpha[(size_t)nperm[j] * 4];
    float4 b = *(const float4*)&ealpha[(size_t)nperm[j + 1] * 4];
    *(float4*)&ealpha_n[(size_t)j * 4] = a;
    *(float4*)&ealpha_n[(size_t)(j + 1) * 4] = b;
    x += a.x + b.x; y += a.y + b.y; z += a.z + b.z; w += a.w + b.w;
  }
  if (j < en) {
    float4 a = *(const float4*)&ealpha[(size_t)nperm[j] * 4];
    *(float4*)&ealpha_n[(size_t)j * 4] = a;
    x += a.x; y += a.y; z += a.z; w += a.w;
  }
  *(float4*)&rden[(size_t)v * 4] = make_float4(1.f / (x + 1e-16f), 1.f / (y + 1e-16f),
                                               1.f / (z + 1e-16f), 1.f / (w + 1e-16f));
}

#define ECH 256
// out_e[e,t] = Binv[e] * sum_i alpha_norm[i,h] * x1[node_i, t]
__global__ __launch_bounds__(128) void edge_aggregate1(const float* __restrict__ x1,
                                                       const float* __restrict__ ealpha,
                                                       const float* __restrict__ rden,
                                                       const float* __restrict__ binv,
                                                       const int* __restrict__ enid,
                                                       const unsigned* __restrict__ eoff,
                                                       const unsigned* __restrict__ eperm,
                                                       float* __restrict__ out_e) {
  __shared__ int nid[ECH];
  __shared__ float wal[ECH][4];
  int e = blockIdx.x, t = threadIdx.x, h = t >> 5;
  unsigned s = eoff[e], en = eoff[e + 1];
  float a0 = 0.f, a1 = 0.f, a2 = 0.f, a3 = 0.f;
  for (unsigned base = s; base < en; base += ECH) {
    int cnt = (int)min((unsigned)ECH, en - base);
    __syncthreads();
    for (int c = t; c < cnt; c += 128) {
      int n = enid[base + c];
      unsigned i = eperm[base + c];
      nid[c] = n;
      float4 ea = *(const float4*)&ealpha[(size_t)i * 4];
      float4 rd = *(const float4*)&rden[(size_t)n * 4];
      wal[c][0] = ea.x * rd.x; wal[c][1] = ea.y * rd.y;
      wal[c][2] = ea.z * rd.z; wal[c][3] = ea.w * rd.w;
    }
    __syncthreads();
    int c = 0;
    for (; c + 4 <= cnt; c += 4) {
      int n0 = nid[c], n1 = nid[c + 1], n2 = nid[c + 2], n3 = nid[c + 3];
      float w0 = wal[c][h], w1 = wal[c + 1][h], w2 = wal[c + 2][h], w3 = wal[c + 3][h];
      a0 += w0 * x1[(size_t)n0 * 128 + t];
      a1 += w1 * x1[(size_t)n1 * 128 + t];
      a2 += w2 * x1[(size_t)n2 * 128 + t];
      a3 += w3 * x1[(size_t)n3 * 128 + t];
    }
    for (; c < cnt; ++c) a0 += wal[c][h] * x1[(size_t)nid[c] * 128 + t];
  }
  out_e[(size_t)e * 128 + t] = binv[e] * (a0 + a1 + a2 + a3);
}

// h[v,t] = elu(Dinv[v]*rden[v,h] * sum_j ealpha_n[j,h]*out_e[neid[j],t] + bias1[t])
__global__ __launch_bounds__(128) void node_aggregate1(const float* __restrict__ out_e,
                                                       const float* __restrict__ ealpha_n,
                                                       const float* __restrict__ rden,
                                                       const float* __restrict__ dinv,
                                                       const float* __restrict__ bias1,
                                                       const int* __restrict__ neid,
                                                       const unsigned* __restrict__ noff,
                                                       float* __restrict__ hout) {
  int v = blockIdx.x, t = threadIdx.x, h = t >> 5;
  unsigned s = noff[v], en = noff[v + 1];
  float rd = dinv[v] * rden[v * 4 + h];
  float a0 = 0.f, a1 = 0.f, a2 = 0.f, a3 = 0.f;
  unsigned j = s;
  for (; j + 4 <= en; j += 4) {
    int e0 = neid[j], e1 = neid[j + 1], e2 = neid[j + 2], e3 = neid[j + 3];
    a0 += ealpha_n[(size_t)j * 4 + h] * out_e[(size_t)e0 * 128 + t];
    a1 += ealpha_n[(size_t)(j + 1) * 4 + h] * out_e[(size_t)e1 * 128 + t];
    a2 += ealpha_n[(size_t)(j + 2) * 4 + h] * out_e[(size_t)e2 * 128 + t];
    a3 += ealpha_n[(size_t)(j + 3) * 4 + h] * out_e[(size_t)e3 * 128 + t];
  }
  for (; j < en; ++j)
    a0 += ealpha_n[(size_t)j * 4 + h] * out_e[(size_t)neid[j] * 128 + t];
  float val = rd * (a0 + a1 + a2 + a3) + bias1[t];
  hout[(size_t)v * 128 + t] = val > 0.f ? val : expm1f(val);
}

// oe_pre[e,t] = Binv[e] * sum_i h[node_i, t]
__global__ __launch_bounds__(128) void edge_aggregate2(const float* __restrict__ hfeat,
                                                       const float* __restrict__ binv,
                                                       const int* __restrict__ enid,
                                                       const unsigned* __restrict__ eoff,
                                                       float* __restrict__ oe) {
  __shared__ int nid[ECH];
  int e = blockIdx.x, t = threadIdx.x;
  unsigned s = eoff[e], en = eoff[e + 1];
  float a0 = 0.f, a1 = 0.f, a2 = 0.f, a3 = 0.f;
  for (unsigned base = s; base < en; base += ECH) {
    int cnt = (int)min((unsigned)ECH, en - base);
    __syncthreads();
    for (int c = t; c < cnt; c += 128) nid[c] = enid[base + c];
    __syncthreads();
    int c = 0;
    for (; c + 4 <= cnt; c += 4) {
      int n0 = nid[c], n1 = nid[c + 1], n2 = nid[c + 2], n3 = nid[c + 3];
      a0 += hfeat[(size_t)n0 * 128 + t];
      a1 += hfeat[(size_t)n1 * 128 + t];
      a2 += hfeat[(size_t)n2 * 128 + t];
      a3 += hfeat[(size_t)n3 * 128 + t];
    }
    for (; c < cnt; ++c) a0 += hfeat[(size_t)nid[c] * 128 + t];
  }
  oe[(size_t)e * 128 + t] = binv[e] * (a0 + a1 + a2 + a3);
}

// out[v,t] = Dinv[v] * sum_j oe2[neid[j], t] + bias2[t]
__global__ __launch_bounds__(128) void node_aggregate2(const float* __restrict__ oe2,
                                                       const float* __restrict__ dinv,
                                                       const float* __restrict__ bias2,
                                                       const int* __restrict__ neid,
                                                       const unsigned* __restrict__ noff,
                                                       float* __restrict__ out) {
  int v = blockIdx.x, t = threadIdx.x;
  unsigned s = noff[v], en = noff[v + 1];
  float a0 = 0.f, a1 = 0.f, a2 = 0.f, a3 = 0.f;
  unsigned j = s;
  for (; j + 4 <= en; j += 4) {
    int e0 = neid[j], e1 = neid[j + 1], e2 = neid[j + 2], e3 = neid[j + 3];
    a0 += oe2[(size_t)e0 * 128 + t];
    a1 += oe2[(size_t)e1 * 128 + t];
    a2 += oe2[(size_t)e2 * 128 + t];
    a3 += oe2[(size_t)e3 * 128 + t];
  }
  for (; j < en; ++j) a0 += oe2[(size_t)neid[j] * 128 + t];
  out[(size_t)v * 128 + t] = dinv[v] * (a0 + a1 + a2 + a3) + bias2[t];
}

extern "C" void kernel_launch(void* const* d_in, const int* in_sizes, int n_in,
                              void* d_out, int out_size, void* d_ws, size_t ws_size,
                              hipStream_t stream) {
  (void)n_in; (void)out_size; (void)ws_size;
  const float* x      = (const float*)d_in[0];
  const float* hea    = (const float*)d_in[1];
  const float* lin1W  = (const float*)d_in[2];
  const float* helinW = (const float*)d_in[3];
  const float* att1   = (const float*)d_in[4];
  const float* bias1  = (const float*)d_in[5];
  const float* lin2W  = (const float*)d_in[6];
  const float* bias2  = (const float*)d_in[7];
  const int* node_idx = (const int*)d_in[8];
  const int* edge_idx = (const int*)d_in[9];
  float* out = (float*)d_out;

  const int N   = in_sizes[0] / 128;
  const int M   = in_sizes[1] / 128;
  const int NNZ = in_sizes[8];
  const int NBE = (M + 63) >> E_SHIFT;
  const int NBN = (N + 127) >> N_SHIFT;

  char* base = (char*)d_ws;
  size_t off = 0;
  auto alloc = [&](size_t bytes) -> char* {
    char* p = base + off;
    off = (off + bytes + 255) & ~(size_t)255;
    return p;
  };
  float* x1    = (float*)alloc((size_t)N * 128 * 4);  // x1; later oe2 (M rows)
  float* hbuf  = (float*)alloc((size_t)N * 128 * 4);  // h
  float* heoe  = (float*)alloc((size_t)M * 128 * 4);  // out_e -> oe_pre
  float* ai    = (float*)alloc((size_t)N * 4 * 4);
  float* aj    = (float*)alloc((size_t)M * 4 * 4);
  float* u     = (float*)alloc(512 * 4);
  float* dinv  = (float*)alloc((size_t)N * 4);
  float* binv  = (float*)alloc((size_t)M * 4);
  float* rden  = (float*)alloc((size_t)N * 4 * 4);
  char* zstart = base + off;                           // ---- zeroed region ----
  unsigned* cnt_n = (unsigned*)alloc((size_t)N * 4);
  unsigned* cnt_e = (unsigned*)alloc((size_t)M * 4);
  size_t zbytes = (size_t)((base + off) - zstart);     // ---- end zero region ----
  float* ealpha   = (float*)alloc((size_t)NNZ * 4 * 4);
  u64* tmp_e      = (u64*)alloc((size_t)NNZ * 8);      // dead after sort_edge
  u64* tmp_n      = (u64*)alloc((size_t)NNZ * 8);      // dead after sort_node
  float* ealpha_n = (float*)tmp_e;                     // alias: 16B*NNZ = tmp_e+tmp_n
  unsigned* noff  = (unsigned*)alloc((size_t)(N + 1) * 4);
  unsigned* eoff  = (unsigned*)alloc((size_t)(M + 1) * 4);
  unsigned* bcur_e = (unsigned*)alloc((size_t)NBE * 4);
  unsigned* bcur_n = (unsigned*)alloc((size_t)NBN * 4);
  unsigned* nperm = (unsigned*)alloc((size_t)NNZ * 4);
  unsigned* eperm = (unsigned*)alloc((size_t)NNZ * 4);
  int* enid       = (int*)alloc((size_t)NNZ * 4);
  int* neid       = (int*)alloc((size_t)NNZ * 4);
  unsigned* bsum  = (unsigned*)alloc(1024 * 4);
  unsigned* boff  = (unsigned*)alloc(1024 * 4);

  hipMemsetAsync(zstart, 0, zbytes, stream);

  const int g_nnz = (NNZ + 255) / 256;
  count_deg<<<g_nnz, 256, 0, stream>>>(node_idx, edge_idx, cnt_n, cnt_e, NNZ);

  const int nbE = (M + 1 + 1023) / 1024;
  const int nbN = (N + 1 + 1023) / 1024;
  scan_pass1<<<nbE, 1024, 0, stream>>>(cnt_e, bsum, M);
  scan_pass2<<<1, 1024, 0, stream>>>(bsum, boff, nbE);
  scan_pass3<<<nbE, 1024, 0, stream>>>(cnt_e, boff, eoff, M);
  scan_pass1<<<nbN, 1024, 0, stream>>>(cnt_n, bsum, N);
  scan_pass2<<<1, 1024, 0, stream>>>(bsum, boff, nbN);
  scan_pass3<<<nbN, 1024, 0, stream>>>(cnt_n, boff, noff, N);

  make_inv<<<(N + 255) / 256, 256, 0, stream>>>(cnt_n, dinv, N);
  make_inv<<<(M + 255) / 256, 256, 0, stream>>>(cnt_e, binv, M);
  init_bcur<<<(max(NBE, NBN) + 255) / 256, 256, 0, stream>>>(eoff, noff, bcur_e, bcur_n,
                                                             NBE, NBN, M, N);
  partition<<<g_nnz, 256, 0, stream>>>(node_idx, edge_idx, bcur_e, bcur_n, tmp_e, tmp_n, NNZ);
  sort_edge<<<NBE, 256, 0, stream>>>(tmp_e, eoff, M, eperm, enid);
  sort_node<<<NBN, 256, 0, stream>>>(tmp_n, noff, N, nperm, neid);

  make_u<<<2, 256, 0, stream>>>(helinW, att1, u);
  gemm128<<<(N + GM - 1) / GM, 256, 0, stream>>>(x, lin1W, x1, N);
  att_dot<<<(N * 4 + 255) / 256, 256, 0, stream>>>(x1, att1, ai, N);
  att_dot_full<<<(M * 4 + 255) / 256, 256, 0, stream>>>(hea, u, aj, M);
  entry_exp<<<g_nnz, 256, 0, stream>>>(node_idx, edge_idx, ai, aj, ealpha, NNZ);
  node_denom<<<(N + 255) / 256, 256, 0, stream>>>(noff, nperm, ealpha, ealpha_n, rden, N);

  edge_aggregate1<<<M, 128, 0, stream>>>(x1, ealpha, rden, binv, enid, eoff, eperm, heoe);
  node_aggregate1<<<N, 128, 0, stream>>>(heoe, ealpha_n, rden, dinv, bias1, neid, noff, hbuf);

  edge_aggregate2<<<M, 128, 0, stream>>>(hbuf, binv, enid, eoff, heoe);
  gemm128<<<(M + GM - 1) / GM, 256, 0, stream>>>(heoe, lin2W, x1, M);  // oe2 into x1 buf
  node_aggregate2<<<N, 128, 0, stream>>>(x1, dinv, bias2, neid, noff, out);
}

// Round 4
// 643.657 us; speedup vs baseline: 1.6057x; 1.6057x over previous
//
#include <hip/hip_runtime.h>
#include <cstdint>

typedef unsigned long long u64;

// ---------------------------------------------------------------------------
// HCHA (hypergraph conv with attention), f32.
// N=100000 nodes, M=20000 hyperedges, NNZ=1e6, C=128, HEADS=4, FH=32.
// CSR build: block-local multi-split partition (LDS histogram + one global
// atomic per block x bucket) -> per-bucket LDS counting sort, coalesced out.
// Packing assumes i < 2^20 (NNZ=1e6), e < 2^15 (M=20000), n < 2^17 (N=1e5).
// ---------------------------------------------------------------------------

#define E_SHIFT 6
#define N_SHIFT 7
#define EB_CAP 4096
#define NB_CAP 2048
#define PCHUNK 4096
#define NBE_CAP 320   // >= ceil(M/64)  = 313
#define NBN_CAP 800   // >= ceil(N/128) = 782

__global__ __launch_bounds__(256) void count_deg(const int* __restrict__ node_idx,
                                                 const int* __restrict__ edge_idx,
                                                 unsigned* __restrict__ cnt_n,
                                                 unsigned* __restrict__ cnt_e, int nnz) {
  int i = blockIdx.x * 256 + threadIdx.x;
  if (i < nnz) {
    atomicAdd(&cnt_n[node_idx[i]], 1u);
    atomicAdd(&cnt_e[edge_idx[i]], 1u);
  }
}

__device__ __forceinline__ unsigned wave_incl_scan(unsigned x) {
#pragma unroll
  for (int s = 1; s < 64; s <<= 1) {
    unsigned t = __shfl_up(x, s, 64);
    if ((int)(threadIdx.x & 63) >= s) x += t;
  }
  return x;
}

__global__ __launch_bounds__(1024) void scan_pass1(const unsigned* __restrict__ cnt,
                                                   unsigned* __restrict__ bsum, int L) {
  int i = blockIdx.x * 1024 + threadIdx.x;
  unsigned v = (i < L) ? cnt[i] : 0u;
  unsigned incl = wave_incl_scan(v);
  __shared__ unsigned wsum[16];
  int lane = threadIdx.x & 63, wid = threadIdx.x >> 6;
  if (lane == 63) wsum[wid] = incl;
  __syncthreads();
  if (threadIdx.x == 0) {
    unsigned t = 0;
#pragma unroll
    for (int w = 0; w < 16; ++w) t += wsum[w];
    bsum[blockIdx.x] = t;
  }
}

__global__ __launch_bounds__(1024) void scan_pass2(const unsigned* __restrict__ bsum,
                                                   unsigned* __restrict__ boff, int nb) {
  int i = threadIdx.x;
  unsigned v = (i < nb) ? bsum[i] : 0u;
  unsigned incl = wave_incl_scan(v);
  __shared__ unsigned wsum[16];
  int lane = threadIdx.x & 63, wid = threadIdx.x >> 6;
  if (lane == 63) wsum[wid] = incl;
  __syncthreads();
  unsigned add = 0;
  for (int w = 0; w < wid; ++w) add += wsum[w];
  if (i < nb) boff[i] = add + incl - v;  // exclusive
}

__global__ __launch_bounds__(1024) void scan_pass3(const unsigned* __restrict__ cnt,
                                                   const unsigned* __restrict__ boff,
                                                   unsigned* __restrict__ off, int L) {
  int i = blockIdx.x * 1024 + threadIdx.x;
  unsigned v = (i < L) ? cnt[i] : 0u;
  unsigned incl = wave_incl_scan(v);
  __shared__ unsigned wsum[16];
  int lane = threadIdx.x & 63, wid = threadIdx.x >> 6;
  if (lane == 63) wsum[wid] = incl;
  __syncthreads();
  unsigned add = boff[blockIdx.x];
  for (int w = 0; w < wid; ++w) add += wsum[w];
  unsigned excl = add + incl - v;
  if (i < L) off[i] = excl;
  if (i == L) off[L] = excl;  // total
}

__global__ __launch_bounds__(256) void make_inv(const unsigned* __restrict__ cnt,
                                                float* __restrict__ inv, int L) {
  int i = blockIdx.x * 256 + threadIdx.x;
  if (i < L) inv[i] = cnt[i] ? 1.f / (float)cnt[i] : 0.f;
}

__global__ __launch_bounds__(256) void init_bcur(const unsigned* __restrict__ eoff,
                                                 const unsigned* __restrict__ noff,
                                                 unsigned* __restrict__ bcur_e,
                                                 unsigned* __restrict__ bcur_n,
                                                 int nbe, int nbn, int M_, int N_) {
  int i = blockIdx.x * 256 + threadIdx.x;
  if (i < nbe) bcur_e[i] = eoff[min(i << E_SHIFT, M_)];
  if (i < nbn) bcur_n[i] = noff[min(i << N_SHIFT, N_)];
}

// pass B: block-local multi-split. LDS histogram -> one global atomic per
// (block,bucket) to reserve ranges -> LDS-cursor scatter of packed payloads.
__global__ __launch_bounds__(256) void partition2(const int* __restrict__ node_idx,
                                                  const int* __restrict__ edge_idx,
                                                  unsigned* __restrict__ bcur_e,
                                                  unsigned* __restrict__ bcur_n,
                                                  u64* __restrict__ tmp_e,
                                                  u64* __restrict__ tmp_n, int nnz) {
  __shared__ unsigned he[NBE_CAP];
  __shared__ unsigned hn[NBN_CAP];
  const int t = threadIdx.x;
  const int base = blockIdx.x * PCHUNK;
  const int cnt = min(PCHUNK, nnz - base);

  for (int b = t; b < NBE_CAP; b += 256) he[b] = 0;
  for (int b = t; b < NBN_CAP; b += 256) hn[b] = 0;
  __syncthreads();

  for (int idx = t; idx < cnt; idx += 256) {
    unsigned e = (unsigned)edge_idx[base + idx];
    unsigned n = (unsigned)node_idx[base + idx];
    atomicAdd(&he[e >> E_SHIFT], 1u);
    atomicAdd(&hn[n >> N_SHIFT], 1u);
  }
  __syncthreads();

  for (int b = t; b < NBE_CAP; b += 256) {
    unsigned c = he[b];
    he[b] = c ? atomicAdd(&bcur_e[b], c) : 0u;   // bucket range base -> cursor
  }
  for (int b = t; b < NBN_CAP; b += 256) {
    unsigned c = hn[b];
    hn[b] = c ? atomicAdd(&bcur_n[b], c) : 0u;
  }
  __syncthreads();

  for (int idx = t; idx < cnt; idx += 256) {
    unsigned i = (unsigned)(base + idx);
    unsigned e = (unsigned)edge_idx[base + idx];
    unsigned n = (unsigned)node_idx[base + idx];
    unsigned pe = atomicAdd(&he[e >> E_SHIFT], 1u);
    tmp_e[pe] = ((u64)(e & 63u) << 37) | ((u64)n << 20) | i;
    unsigned pn = atomicAdd(&hn[n >> N_SHIFT], 1u);
    tmp_n[pn] = ((u64)(n & 127u) << 35) | ((u64)e << 20) | i;
  }
}

// pass C (edges): per-bucket LDS counting sort; coalesced eperm + enid writes
__global__ __launch_bounds__(256) void sort_edge(const u64* __restrict__ tmp,
                                                 const unsigned* __restrict__ eoff,
                                                 int M_, unsigned* __restrict__ eperm,
                                                 int* __restrict__ enid) {
  __shared__ unsigned cur[64];
  __shared__ u64 sbuf[EB_CAP];
  int b = blockIdx.x, t = threadIdx.x;
  int e0 = b << E_SHIFT;
  unsigned base = eoff[min(e0, M_)];
  unsigned end  = eoff[min(e0 + 64, M_)];
  if (t < 64) cur[t] = eoff[min(e0 + t, M_)] - base;
  __syncthreads();
  int cnt = (int)(end - base);
  for (int idx = t; idx < cnt; idx += 256) {
    u64 p = tmp[base + idx];
    unsigned key = (unsigned)(p >> 37) & 63u;
    unsigned pos = atomicAdd(&cur[key], 1u);
    if (pos < EB_CAP) {
      sbuf[pos] = p;
    } else {  // overflow fallback (statistically never): direct global write
      eperm[base + pos] = (unsigned)(p & 0xFFFFFu);
      enid[base + pos]  = (int)((p >> 20) & 0x1FFFFu);
    }
  }
  __syncthreads();
  int lim = min(cnt, EB_CAP);
  for (int idx = t; idx < lim; idx += 256) {
    u64 p = sbuf[idx];
    eperm[base + idx] = (unsigned)(p & 0xFFFFFu);
    enid[base + idx]  = (int)((p >> 20) & 0x1FFFFu);
  }
}

// pass C (nodes): coalesced nperm + neid writes
__global__ __launch_bounds__(256) void sort_node(const u64* __restrict__ tmp,
                                                 const unsigned* __restrict__ noff,
                                                 int N_, unsigned* __restrict__ nperm,
                                                 int* __restrict__ neid) {
  __shared__ unsigned cur[128];
  __shared__ u64 sbuf[NB_CAP];
  int b = blockIdx.x, t = threadIdx.x;
  int n0 = b << N_SHIFT;
  unsigned base = noff[min(n0, N_)];
  unsigned end  = noff[min(n0 + 128, N_)];
  if (t < 128) cur[t] = noff[min(n0 + t, N_)] - base;
  __syncthreads();
  int cnt = (int)(end - base);
  for (int idx = t; idx < cnt; idx += 256) {
    u64 p = tmp[base + idx];
    unsigned key = (unsigned)(p >> 35) & 127u;
    unsigned pos = atomicAdd(&cur[key], 1u);
    if (pos < NB_CAP) {
      sbuf[pos] = p;
    } else {
      nperm[base + pos] = (unsigned)(p & 0xFFFFFu);
      neid[base + pos]  = (int)((p >> 20) & 0x7FFFu);
    }
  }
  __syncthreads();
  int lim = min(cnt, NB_CAP);
  for (int idx = t; idx < lim; idx += 256) {
    u64 p = sbuf[idx];
    nperm[base + idx] = (unsigned)(p & 0xFFFFFu);
    neid[base + idx]  = (int)((p >> 20) & 0x7FFFu);
  }
}

// C[r,o] = sum_k A[r,k] * W[o,k];  A: rows x 128, W: 128 x 128 (row-major)
#define GM 32
__global__ __launch_bounds__(256) void gemm128(const float* __restrict__ A,
                                               const float* __restrict__ W,
                                               float* __restrict__ C, int rows) {
  __shared__ __align__(16) float Ast[128 * 36];  // Ast[k][r], r-pad to 36
  __shared__ __align__(16) float Wt[64 * 132];   // Wt[k][o], k half-tile
  const int tid = threadIdx.x;
  const int row0 = blockIdx.x * GM;

  for (int idx = tid; idx < GM * 128; idx += 256) {
    int r = idx >> 7, k = idx & 127;
    int gr = row0 + r;
    Ast[k * 36 + r] = (gr < rows) ? A[(size_t)gr * 128 + k] : 0.f;
  }

  const int tr = tid >> 5, tc = tid & 31;
  const int r0 = tr * 4, c0 = tc * 4;
  float acc[4][4] = {{0.f}};

  for (int kh = 0; kh < 2; ++kh) {
    __syncthreads();
    for (int idx = tid; idx < 128 * 64; idx += 256) {
      int o = idx >> 6, k = idx & 63;
      Wt[k * 132 + o] = W[o * 128 + kh * 64 + k];
    }
    __syncthreads();
#pragma unroll 8
    for (int k = 0; k < 64; ++k) {
      const int kk = kh * 64 + k;
      float4 a = *(const float4*)&Ast[kk * 36 + r0];
      float4 b = *(const float4*)&Wt[k * 132 + c0];
      acc[0][0] += a.x * b.x; acc[0][1] += a.x * b.y; acc[0][2] += a.x * b.z; acc[0][3] += a.x * b.w;
      acc[1][0] += a.y * b.x; acc[1][1] += a.y * b.y; acc[1][2] += a.y * b.z; acc[1][3] += a.y * b.w;
      acc[2][0] += a.z * b.x; acc[2][1] += a.z * b.y; acc[2][2] += a.z * b.z; acc[2][3] += a.z * b.w;
      acc[3][0] += a.w * b.x; acc[3][1] += a.w * b.y; acc[3][2] += a.w * b.z; acc[3][3] += a.w * b.w;
    }
  }
#pragma unroll
  for (int i = 0; i < 4; ++i) {
    int gr = row0 + r0 + i;
    if (gr < rows)
      *(float4*)&C[(size_t)gr * 128 + c0] = make_float4(acc[i][0], acc[i][1], acc[i][2], acc[i][3]);
  }
}

// ai[v,h] = sum_f feat[v, h*32+f] * att[h*64 + f]
__global__ __launch_bounds__(256) void att_dot(const float* __restrict__ feat,
                                               const float* __restrict__ att,
                                               float* __restrict__ outv, int rows) {
  int idx = blockIdx.x * 256 + threadIdx.x;
  if (idx >= rows * 4) return;
  int v = idx >> 2, h = idx & 3;
  const float4* fp = (const float4*)(feat + (size_t)v * 128 + h * 32);
  const float4* ap = (const float4*)(att + h * 64);
  float s = 0.f;
#pragma unroll
  for (int q = 0; q < 8; ++q) {
    float4 a = ap[q], f = fp[q];
    s += a.x * f.x + a.y * f.y + a.z * f.z + a.w * f.w;
  }
  outv[idx] = s;
}

// u[h,k] = sum_f att1[h*64+32+f] * W_he[(h*32+f)*128 + k]
__global__ __launch_bounds__(256) void make_u(const float* __restrict__ W_he,
                                              const float* __restrict__ att1,
                                              float* __restrict__ u) {
  int idx = blockIdx.x * 256 + threadIdx.x;
  if (idx >= 512) return;
  int h = idx >> 7, k = idx & 127;
  float s = 0.f;
#pragma unroll
  for (int f = 0; f < 32; ++f)
    s += att1[h * 64 + 32 + f] * W_he[(size_t)(h * 32 + f) * 128 + k];
  u[h * 128 + k] = s;
}

// aj[e,h] = hea[e,:] . u[h,:]
__global__ __launch_bounds__(256) void att_dot_full(const float* __restrict__ feat,
                                                    const float* __restrict__ u,
                                                    float* __restrict__ outv, int rows) {
  int idx = blockIdx.x * 256 + threadIdx.x;
  if (idx >= rows * 4) return;
  int v = idx >> 2, h = idx & 3;
  const float4* fp = (const float4*)(feat + (size_t)v * 128);
  const float4* up = (const float4*)(u + h * 128);
  float s = 0.f;
#pragma unroll
  for (int q = 0; q < 32; ++q) {
    float4 a = up[q], f = fp[q];
    s += a.x * f.x + a.y * f.y + a.z * f.z + a.w * f.w;
  }
  outv[idx] = s;
}

// ealpha[i,h] = exp(leakyrelu(ai[n,h] + aj[e,h]))
__global__ __launch_bounds__(256) void entry_exp(const int* __restrict__ node_idx,
                                                 const int* __restrict__ edge_idx,
                                                 const float* __restrict__ ai,
                                                 const float* __restrict__ aj,
                                                 float* __restrict__ ealpha, int nnz) {
  int i = blockIdx.x * 256 + threadIdx.x;
  if (i >= nnz) return;
  int n = node_idx[i], e = edge_idx[i];
  float4 av = *(const float4*)&ai[(size_t)n * 4];
  float4 bv = *(const float4*)&aj[(size_t)e * 4];
  float v0 = av.x + bv.x, v1 = av.y + bv.y, v2 = av.z + bv.z, v3 = av.w + bv.w;
  v0 = v0 > 0.f ? v0 : 0.2f * v0;
  v1 = v1 > 0.f ? v1 : 0.2f * v1;
  v2 = v2 > 0.f ? v2 : 0.2f * v2;
  v3 = v3 > 0.f ? v3 : 0.2f * v3;
  *(float4*)&ealpha[(size_t)i * 4] = make_float4(expf(v0), expf(v1), expf(v2), expf(v3));
}

// rden[v,h] = 1/(sum ealpha + 1e-16); also emits ealpha_n (node-sorted alphas)
__global__ __launch_bounds__(256) void node_denom(const unsigned* __restrict__ noff,
                                                  const unsigned* __restrict__ nperm,
                                                  const float* __restrict__ ealpha,
                                                  float* __restrict__ ealpha_n,
                                                  float* __restrict__ rden, int N) {
  int v = blockIdx.x * 256 + threadIdx.x;
  if (v >= N) return;
  unsigned s = noff[v], en = noff[v + 1];
  float x = 0.f, y = 0.f, z = 0.f, w = 0.f;
  unsigned j = s;
  for (; j + 2 <= en; j += 2) {
    float4 a = *(const float4*)&ealpha[(size_t)nperm[j] * 4];
    float4 b = *(const float4*)&ealpha[(size_t)nperm[j + 1] * 4];
    *(float4*)&ealpha_n[(size_t)j * 4] = a;
    *(float4*)&ealpha_n[(size_t)(j + 1) * 4] = b;
    x += a.x + b.x; y += a.y + b.y; z += a.z + b.z; w += a.w + b.w;
  }
  if (j < en) {
    float4 a = *(const float4*)&ealpha[(size_t)nperm[j] * 4];
    *(float4*)&ealpha_n[(size_t)j * 4] = a;
    x += a.x; y += a.y; z += a.z; w += a.w;
  }
  *(float4*)&rden[(size_t)v * 4] = make_float4(1.f / (x + 1e-16f), 1.f / (y + 1e-16f),
                                               1.f / (z + 1e-16f), 1.f / (w + 1e-16f));
}

#define ECH 256
// out_e[e,t] = Binv[e] * sum_i alpha_norm[i,h] * x1[node_i, t]
__global__ __launch_bounds__(128) void edge_aggregate1(const float* __restrict__ x1,
                                                       const float* __restrict__ ealpha,
                                                       const float* __restrict__ rden,
                                                       const float* __restrict__ binv,
                                                       const int* __restrict__ enid,
                                                       const unsigned* __restrict__ eoff,
                                                       const unsigned* __restrict__ eperm,
                                                       float* __restrict__ out_e) {
  __shared__ int nid[ECH];
  __shared__ float wal[ECH][4];
  int e = blockIdx.x, t = threadIdx.x, h = t >> 5;
  unsigned s = eoff[e], en = eoff[e + 1];
  float a0 = 0.f, a1 = 0.f, a2 = 0.f, a3 = 0.f;
  for (unsigned base = s; base < en; base += ECH) {
    int cnt = (int)min((unsigned)ECH, en - base);
    __syncthreads();
    for (int c = t; c < cnt; c += 128) {
      int n = enid[base + c];
      unsigned i = eperm[base + c];
      nid[c] = n;
      float4 ea = *(const float4*)&ealpha[(size_t)i * 4];
      float4 rd = *(const float4*)&rden[(size_t)n * 4];
      wal[c][0] = ea.x * rd.x; wal[c][1] = ea.y * rd.y;
      wal[c][2] = ea.z * rd.z; wal[c][3] = ea.w * rd.w;
    }
    __syncthreads();
    int c = 0;
    for (; c + 4 <= cnt; c += 4) {
      int n0 = nid[c], n1 = nid[c + 1], n2 = nid[c + 2], n3 = nid[c + 3];
      float w0 = wal[c][h], w1 = wal[c + 1][h], w2 = wal[c + 2][h], w3 = wal[c + 3][h];
      a0 += w0 * x1[(size_t)n0 * 128 + t];
      a1 += w1 * x1[(size_t)n1 * 128 + t];
      a2 += w2 * x1[(size_t)n2 * 128 + t];
      a3 += w3 * x1[(size_t)n3 * 128 + t];
    }
    for (; c < cnt; ++c) a0 += wal[c][h] * x1[(size_t)nid[c] * 128 + t];
  }
  out_e[(size_t)e * 128 + t] = binv[e] * (a0 + a1 + a2 + a3);
}

// h[v,t] = elu(Dinv[v]*rden[v,h] * sum_j ealpha_n[j,h]*out_e[neid[j],t] + bias1[t])
__global__ __launch_bounds__(128) void node_aggregate1(const float* __restrict__ out_e,
                                                       const float* __restrict__ ealpha_n,
                                                       const float* __restrict__ rden,
                                                       const float* __restrict__ dinv,
                                                       const float* __restrict__ bias1,
                                                       const int* __restrict__ neid,
                                                       const unsigned* __restrict__ noff,
                                                       float* __restrict__ hout) {
  int v = blockIdx.x, t = threadIdx.x, h = t >> 5;
  unsigned s = noff[v], en = noff[v + 1];
  float rd = dinv[v] * rden[v * 4 + h];
  float a0 = 0.f, a1 = 0.f, a2 = 0.f, a3 = 0.f;
  unsigned j = s;
  for (; j + 4 <= en; j += 4) {
    int e0 = neid[j], e1 = neid[j + 1], e2 = neid[j + 2], e3 = neid[j + 3];
    a0 += ealpha_n[(size_t)j * 4 + h] * out_e[(size_t)e0 * 128 + t];
    a1 += ealpha_n[(size_t)(j + 1) * 4 + h] * out_e[(size_t)e1 * 128 + t];
    a2 += ealpha_n[(size_t)(j + 2) * 4 + h] * out_e[(size_t)e2 * 128 + t];
    a3 += ealpha_n[(size_t)(j + 3) * 4 + h] * out_e[(size_t)e3 * 128 + t];
  }
  for (; j < en; ++j)
    a0 += ealpha_n[(size_t)j * 4 + h] * out_e[(size_t)neid[j] * 128 + t];
  float val = rd * (a0 + a1 + a2 + a3) + bias1[t];
  hout[(size_t)v * 128 + t] = val > 0.f ? val : expm1f(val);
}

// oe_pre[e,t] = Binv[e] * sum_i h[node_i, t]
__global__ __launch_bounds__(128) void edge_aggregate2(const float* __restrict__ hfeat,
                                                       const float* __restrict__ binv,
                                                       const int* __restrict__ enid,
                                                       const unsigned* __restrict__ eoff,
                                                       float* __restrict__ oe) {
  __shared__ int nid[ECH];
  int e = blockIdx.x, t = threadIdx.x;
  unsigned s = eoff[e], en = eoff[e + 1];
  float a0 = 0.f, a1 = 0.f, a2 = 0.f, a3 = 0.f;
  for (unsigned base = s; base < en; base += ECH) {
    int cnt = (int)min((unsigned)ECH, en - base);
    __syncthreads();
    for (int c = t; c < cnt; c += 128) nid[c] = enid[base + c];
    __syncthreads();
    int c = 0;
    for (; c + 4 <= cnt; c += 4) {
      int n0 = nid[c], n1 = nid[c + 1], n2 = nid[c + 2], n3 = nid[c + 3];
      a0 += hfeat[(size_t)n0 * 128 + t];
      a1 += hfeat[(size_t)n1 * 128 + t];
      a2 += hfeat[(size_t)n2 * 128 + t];
      a3 += hfeat[(size_t)n3 * 128 + t];
    }
    for (; c < cnt; ++c) a0 += hfeat[(size_t)nid[c] * 128 + t];
  }
  oe[(size_t)e * 128 + t] = binv[e] * (a0 + a1 + a2 + a3);
}

// out[v,t] = Dinv[v] * sum_j oe2[neid[j], t] + bias2[t]
__global__ __launch_bounds__(128) void node_aggregate2(const float* __restrict__ oe2,
                                                       const float* __restrict__ dinv,
                                                       const float* __restrict__ bias2,
                                                       const int* __restrict__ neid,
                                                       const unsigned* __restrict__ noff,
                                                       float* __restrict__ out) {
  int v = blockIdx.x, t = threadIdx.x;
  unsigned s = noff[v], en = noff[v + 1];
  float a0 = 0.f, a1 = 0.f, a2 = 0.f, a3 = 0.f;
  unsigned j = s;
  for (; j + 4 <= en; j += 4) {
    int e0 = neid[j], e1 = neid[j + 1], e2 = neid[j + 2], e3 = neid[j + 3];
    a0 += oe2[(size_t)e0 * 128 + t];
    a1 += oe2[(size_t)e1 * 128 + t];
    a2 += oe2[(size_t)e2 * 128 + t];
    a3 += oe2[(size_t)e3 * 128 + t];
  }
  for (; j < en; ++j) a0 += oe2[(size_t)neid[j] * 128 + t];
  out[(size_t)v * 128 + t] = dinv[v] * (a0 + a1 + a2 + a3) + bias2[t];
}

extern "C" void kernel_launch(void* const* d_in, const int* in_sizes, int n_in,
                              void* d_out, int out_size, void* d_ws, size_t ws_size,
                              hipStream_t stream) {
  (void)n_in; (void)out_size; (void)ws_size;
  const float* x      = (const float*)d_in[0];
  const float* hea    = (const float*)d_in[1];
  const float* lin1W  = (const float*)d_in[2];
  const float* helinW = (const float*)d_in[3];
  const float* att1   = (const float*)d_in[4];
  const float* bias1  = (const float*)d_in[5];
  const float* lin2W  = (const float*)d_in[6];
  const float* bias2  = (const float*)d_in[7];
  const int* node_idx = (const int*)d_in[8];
  const int* edge_idx = (const int*)d_in[9];
  float* out = (float*)d_out;

  const int N   = in_sizes[0] / 128;
  const int M   = in_sizes[1] / 128;
  const int NNZ = in_sizes[8];
  const int NBE = (M + 63) >> E_SHIFT;
  const int NBN = (N + 127) >> N_SHIFT;

  char* base = (char*)d_ws;
  size_t off = 0;
  auto alloc = [&](size_t bytes) -> char* {
    char* p = base + off;
    off = (off + bytes + 255) & ~(size_t)255;
    return p;
  };
  float* x1    = (float*)alloc((size_t)N * 128 * 4);  // x1; later oe2 (M rows)
  float* hbuf  = (float*)alloc((size_t)N * 128 * 4);  // h
  float* heoe  = (float*)alloc((size_t)M * 128 * 4);  // out_e -> oe_pre
  float* ai    = (float*)alloc((size_t)N * 4 * 4);
  float* aj    = (float*)alloc((size_t)M * 4 * 4);
  float* u     = (float*)alloc(512 * 4);
  float* dinv  = (float*)alloc((size_t)N * 4);
  float* binv  = (float*)alloc((size_t)M * 4);
  float* rden  = (float*)alloc((size_t)N * 4 * 4);
  char* zstart = base + off;                           // ---- zeroed region ----
  unsigned* cnt_n = (unsigned*)alloc((size_t)N * 4);
  unsigned* cnt_e = (unsigned*)alloc((size_t)M * 4);
  size_t zbytes = (size_t)((base + off) - zstart);     // ---- end zero region ----
  float* ealpha   = (float*)alloc((size_t)NNZ * 4 * 4);
  u64* tmp_e      = (u64*)alloc((size_t)NNZ * 8);      // dead after sort_edge
  u64* tmp_n      = (u64*)alloc((size_t)NNZ * 8);      // dead after sort_node
  float* ealpha_n = (float*)tmp_e;                     // alias: 16B*NNZ = tmp_e+tmp_n
  unsigned* noff  = (unsigned*)alloc((size_t)(N + 1) * 4);
  unsigned* eoff  = (unsigned*)alloc((size_t)(M + 1) * 4);
  unsigned* bcur_e = (unsigned*)alloc((size_t)NBE * 4);
  unsigned* bcur_n = (unsigned*)alloc((size_t)NBN * 4);
  unsigned* nperm = (unsigned*)alloc((size_t)NNZ * 4);
  unsigned* eperm = (unsigned*)alloc((size_t)NNZ * 4);
  int* enid       = (int*)alloc((size_t)NNZ * 4);
  int* neid       = (int*)alloc((size_t)NNZ * 4);
  unsigned* bsum  = (unsigned*)alloc(1024 * 4);
  unsigned* boff  = (unsigned*)alloc(1024 * 4);

  hipMemsetAsync(zstart, 0, zbytes, stream);

  const int g_nnz = (NNZ + 255) / 256;
  count_deg<<<g_nnz, 256, 0, stream>>>(node_idx, edge_idx, cnt_n, cnt_e, NNZ);

  const int nbE = (M + 1 + 1023) / 1024;
  const int nbN = (N + 1 + 1023) / 1024;
  scan_pass1<<<nbE, 1024, 0, stream>>>(cnt_e, bsum, M);
  scan_pass2<<<1, 1024, 0, stream>>>(bsum, boff, nbE);
  scan_pass3<<<nbE, 1024, 0, stream>>>(cnt_e, boff, eoff, M);
  scan_pass1<<<nbN, 1024, 0, stream>>>(cnt_n, bsum, N);
  scan_pass2<<<1, 1024, 0, stream>>>(bsum, boff, nbN);
  scan_pass3<<<nbN, 1024, 0, stream>>>(cnt_n, boff, noff, N);

  make_inv<<<(N + 255) / 256, 256, 0, stream>>>(cnt_n, dinv, N);
  make_inv<<<(M + 255) / 256, 256, 0, stream>>>(cnt_e, binv, M);
  init_bcur<<<(max(NBE, NBN) + 255) / 256, 256, 0, stream>>>(eoff, noff, bcur_e, bcur_n,
                                                             NBE, NBN, M, N);
  partition2<<<(NNZ + PCHUNK - 1) / PCHUNK, 256, 0, stream>>>(node_idx, edge_idx, bcur_e,
                                                              bcur_n, tmp_e, tmp_n, NNZ);
  sort_edge<<<NBE, 256, 0, stream>>>(tmp_e, eoff, M, eperm, enid);
  sort_node<<<NBN, 256, 0, stream>>>(tmp_n, noff, N, nperm, neid);

  make_u<<<2, 256, 0, stream>>>(helinW, att1, u);
  gemm128<<<(N + GM - 1) / GM, 256, 0, stream>>>(x, lin1W, x1, N);
  att_dot<<<(N * 4 + 255) / 256, 256, 0, stream>>>(x1, att1, ai, N);
  att_dot_full<<<(M * 4 + 255) / 256, 256, 0, stream>>>(hea, u, aj, M);
  entry_exp<<<g_nnz, 256, 0, stream>>>(node_idx, edge_idx, ai, aj, ealpha, NNZ);
  node_denom<<<(N + 255) / 256, 256, 0, stream>>>(noff, nperm, ealpha, ealpha_n, rden, N);

  edge_aggregate1<<<M, 128, 0, stream>>>(x1, ealpha, rden, binv, enid, eoff, eperm, heoe);
  node_aggregate1<<<N, 128, 0, stream>>>(heoe, ealpha_n, rden, dinv, bias1, neid, noff, hbuf);

  edge_aggregate2<<<M, 128, 0, stream>>>(hbuf, binv, enid, eoff, heoe);
  gemm128<<<(M + GM - 1) / GM, 256, 0, stream>>>(heoe, lin2W, x1, M);  // oe2 into x1 buf
  node_aggregate2<<<N, 128, 0, stream>>>(x1, dinv, bias2, neid, noff, out);
}

// Round 5
// 613.725 us; speedup vs baseline: 1.6840x; 1.0488x over previous
//
#include <hip/hip_runtime.h>
#include <cstdint>

// ---------------------------------------------------------------------------
// HCHA (hypergraph conv with attention), f32.
// N=100000 nodes, M=20000 hyperedges, NNZ=1e6, C=128, HEADS=4, FH=32.
// CSR build: block-local multi-split partition (u32 payloads) -> per-bucket
// LDS counting sort which ALSO evaluates exp(leakyrelu(ai+aj)) and emits
// edge-ordered / node-ordered alpha streams (no entry-order alpha buffer,
// no perm arrays, all downstream alpha reads sequential).
// Packing: e < 2^15 (M=20000), n < 2^17 (N=1e5).
// ---------------------------------------------------------------------------

#define E_SHIFT 6
#define N_SHIFT 7
#define EB_CAP 4096
#define NB_CAP 2048
#define PCHUNK 4096
#define NBE_CAP 320   // >= ceil(M/64)  = 313
#define NBN_CAP 800   // >= ceil(N/128) = 782

__global__ __launch_bounds__(256) void count_deg(const int* __restrict__ node_idx,
                                                 const int* __restrict__ edge_idx,
                                                 unsigned* __restrict__ cnt_n,
                                                 unsigned* __restrict__ cnt_e, int nnz) {
  int i = blockIdx.x * 256 + threadIdx.x;
  if (i < nnz) {
    atomicAdd(&cnt_n[node_idx[i]], 1u);
    atomicAdd(&cnt_e[edge_idx[i]], 1u);
  }
}

__device__ __forceinline__ unsigned wave_incl_scan(unsigned x) {
#pragma unroll
  for (int s = 1; s < 64; s <<= 1) {
    unsigned t = __shfl_up(x, s, 64);
    if ((int)(threadIdx.x & 63) >= s) x += t;
  }
  return x;
}

__global__ __launch_bounds__(1024) void scan_pass1(const unsigned* __restrict__ cnt,
                                                   unsigned* __restrict__ bsum, int L) {
  int i = blockIdx.x * 1024 + threadIdx.x;
  unsigned v = (i < L) ? cnt[i] : 0u;
  unsigned incl = wave_incl_scan(v);
  __shared__ unsigned wsum[16];
  int lane = threadIdx.x & 63, wid = threadIdx.x >> 6;
  if (lane == 63) wsum[wid] = incl;
  __syncthreads();
  if (threadIdx.x == 0) {
    unsigned t = 0;
#pragma unroll
    for (int w = 0; w < 16; ++w) t += wsum[w];
    bsum[blockIdx.x] = t;
  }
}

__global__ __launch_bounds__(1024) void scan_pass2(const unsigned* __restrict__ bsum,
                                                   unsigned* __restrict__ boff, int nb) {
  int i = threadIdx.x;
  unsigned v = (i < nb) ? bsum[i] : 0u;
  unsigned incl = wave_incl_scan(v);
  __shared__ unsigned wsum[16];
  int lane = threadIdx.x & 63, wid = threadIdx.x >> 6;
  if (lane == 63) wsum[wid] = incl;
  __syncthreads();
  unsigned add = 0;
  for (int w = 0; w < wid; ++w) add += wsum[w];
  if (i < nb) boff[i] = add + incl - v;  // exclusive
}

__global__ __launch_bounds__(1024) void scan_pass3(const unsigned* __restrict__ cnt,
                                                   const unsigned* __restrict__ boff,
                                                   unsigned* __restrict__ off, int L) {
  int i = blockIdx.x * 1024 + threadIdx.x;
  unsigned v = (i < L) ? cnt[i] : 0u;
  unsigned incl = wave_incl_scan(v);
  __shared__ unsigned wsum[16];
  int lane = threadIdx.x & 63, wid = threadIdx.x >> 6;
  if (lane == 63) wsum[wid] = incl;
  __syncthreads();
  unsigned add = boff[blockIdx.x];
  for (int w = 0; w < wid; ++w) add += wsum[w];
  unsigned excl = add + incl - v;
  if (i < L) off[i] = excl;
  if (i == L) off[L] = excl;  // total
}

__global__ __launch_bounds__(256) void make_inv(const unsigned* __restrict__ cnt,
                                                float* __restrict__ inv, int L) {
  int i = blockIdx.x * 256 + threadIdx.x;
  if (i < L) inv[i] = cnt[i] ? 1.f / (float)cnt[i] : 0.f;
}

__global__ __launch_bounds__(256) void init_bcur(const unsigned* __restrict__ eoff,
                                                 const unsigned* __restrict__ noff,
                                                 unsigned* __restrict__ bcur_e,
                                                 unsigned* __restrict__ bcur_n,
                                                 int nbe, int nbn, int M_, int N_) {
  int i = blockIdx.x * 256 + threadIdx.x;
  if (i < nbe) bcur_e[i] = eoff[min(i << E_SHIFT, M_)];
  if (i < nbn) bcur_n[i] = noff[min(i << N_SHIFT, N_)];
}

// pass B: block-local multi-split. LDS histogram -> one global atomic per
// (block,bucket) to reserve ranges -> LDS-cursor scatter of u32 payloads.
__global__ __launch_bounds__(256) void partition2(const int* __restrict__ node_idx,
                                                  const int* __restrict__ edge_idx,
                                                  unsigned* __restrict__ bcur_e,
                                                  unsigned* __restrict__ bcur_n,
                                                  unsigned* __restrict__ tmp_e,
                                                  unsigned* __restrict__ tmp_n, int nnz) {
  __shared__ unsigned he[NBE_CAP];
  __shared__ unsigned hn[NBN_CAP];
  const int t = threadIdx.x;
  const int base = blockIdx.x * PCHUNK;
  const int cnt = min(PCHUNK, nnz - base);

  for (int b = t; b < NBE_CAP; b += 256) he[b] = 0;
  for (int b = t; b < NBN_CAP; b += 256) hn[b] = 0;
  __syncthreads();

  for (int idx = t; idx < cnt; idx += 256) {
    unsigned e = (unsigned)edge_idx[base + idx];
    unsigned n = (unsigned)node_idx[base + idx];
    atomicAdd(&he[e >> E_SHIFT], 1u);
    atomicAdd(&hn[n >> N_SHIFT], 1u);
  }
  __syncthreads();

  for (int b = t; b < NBE_CAP; b += 256) {
    unsigned c = he[b];
    he[b] = c ? atomicAdd(&bcur_e[b], c) : 0u;   // bucket range base -> cursor
  }
  for (int b = t; b < NBN_CAP; b += 256) {
    unsigned c = hn[b];
    hn[b] = c ? atomicAdd(&bcur_n[b], c) : 0u;
  }
  __syncthreads();

  for (int idx = t; idx < cnt; idx += 256) {
    unsigned e = (unsigned)edge_idx[base + idx];
    unsigned n = (unsigned)node_idx[base + idx];
    unsigned pe = atomicAdd(&he[e >> E_SHIFT], 1u);
    tmp_e[pe] = ((e & 63u) << 17) | n;
    unsigned pn = atomicAdd(&hn[n >> N_SHIFT], 1u);
    tmp_n[pn] = ((n & 127u) << 15) | e;
  }
}

__device__ __forceinline__ float4 alpha4(const float* __restrict__ ai,
                                         const float* __restrict__ aj,
                                         unsigned n, unsigned e) {
  float4 av = *(const float4*)&ai[(size_t)n * 4];
  float4 bv = *(const float4*)&aj[(size_t)e * 4];
  float v0 = av.x + bv.x, v1 = av.y + bv.y, v2 = av.z + bv.z, v3 = av.w + bv.w;
  v0 = v0 > 0.f ? v0 : 0.2f * v0;
  v1 = v1 > 0.f ? v1 : 0.2f * v1;
  v2 = v2 > 0.f ? v2 : 0.2f * v2;
  v3 = v3 > 0.f ? v3 : 0.2f * v3;
  return make_float4(expf(v0), expf(v1), expf(v2), expf(v3));
}

// pass C (edges): per-bucket LDS counting sort; coalesced writes of
// edge-ordered node ids + exp(leakyrelu(ai+aj)) stream.
__global__ __launch_bounds__(256) void sort_edge_exp(const unsigned* __restrict__ tmp,
                                                     const unsigned* __restrict__ eoff,
                                                     int M_,
                                                     const float* __restrict__ ai,
                                                     const float* __restrict__ aj,
                                                     float* __restrict__ ealpha_e,
                                                     int* __restrict__ enid) {
  __shared__ unsigned cur[64];
  __shared__ unsigned sbuf[EB_CAP];
  int b = blockIdx.x, t = threadIdx.x;
  int e0 = b << E_SHIFT;
  unsigned base = eoff[min(e0, M_)];
  unsigned end  = eoff[min(e0 + 64, M_)];
  if (t < 64) cur[t] = eoff[min(e0 + t, M_)] - base;
  __syncthreads();
  int cnt = (int)(end - base);
  for (int idx = t; idx < cnt; idx += 256) {
    unsigned p = tmp[base + idx];
    unsigned key = p >> 17;
    unsigned pos = atomicAdd(&cur[key], 1u);
    if (pos < EB_CAP) {
      sbuf[pos] = p;
    } else {  // overflow fallback (statistically never)
      unsigned n = p & 0x1FFFFu;
      *(float4*)&ealpha_e[(size_t)(base + pos) * 4] = alpha4(ai, aj, n, e0 + key);
      enid[base + pos] = (int)n;
    }
  }
  __syncthreads();
  int lim = min(cnt, EB_CAP);
  for (int idx = t; idx < lim; idx += 256) {
    unsigned p = sbuf[idx];
    unsigned key = p >> 17, n = p & 0x1FFFFu;
    *(float4*)&ealpha_e[(size_t)(base + idx) * 4] = alpha4(ai, aj, n, e0 + key);
    enid[base + idx] = (int)n;
  }
}

// pass C (nodes): coalesced node-ordered edge ids + alpha stream.
__global__ __launch_bounds__(256) void sort_node_exp(const unsigned* __restrict__ tmp,
                                                     const unsigned* __restrict__ noff,
                                                     int N_,
                                                     const float* __restrict__ ai,
                                                     const float* __restrict__ aj,
                                                     float* __restrict__ ealpha_n,
                                                     int* __restrict__ neid) {
  __shared__ unsigned cur[128];
  __shared__ unsigned sbuf[NB_CAP];
  int b = blockIdx.x, t = threadIdx.x;
  int n0 = b << N_SHIFT;
  unsigned base = noff[min(n0, N_)];
  unsigned end  = noff[min(n0 + 128, N_)];
  if (t < 128) cur[t] = noff[min(n0 + t, N_)] - base;
  __syncthreads();
  int cnt = (int)(end - base);
  for (int idx = t; idx < cnt; idx += 256) {
    unsigned p = tmp[base + idx];
    unsigned key = p >> 15;
    unsigned pos = atomicAdd(&cur[key], 1u);
    if (pos < NB_CAP) {
      sbuf[pos] = p;
    } else {
      unsigned e = p & 0x7FFFu;
      *(float4*)&ealpha_n[(size_t)(base + pos) * 4] = alpha4(ai, aj, n0 + key, e);
      neid[base + pos] = (int)e;
    }
  }
  __syncthreads();
  int lim = min(cnt, NB_CAP);
  for (int idx = t; idx < lim; idx += 256) {
    unsigned p = sbuf[idx];
    unsigned key = p >> 15, e = p & 0x7FFFu;
    *(float4*)&ealpha_n[(size_t)(base + idx) * 4] = alpha4(ai, aj, n0 + key, e);
    neid[base + idx] = (int)e;
  }
}

// rden[v,h] = 1/(sum_{j in node range} ealpha_n[j,h] + 1e-16), sequential read
__global__ __launch_bounds__(256) void node_denom2(const unsigned* __restrict__ noff,
                                                   const float* __restrict__ ealpha_n,
                                                   float* __restrict__ rden, int N) {
  int v = blockIdx.x * 256 + threadIdx.x;
  if (v >= N) return;
  unsigned s = noff[v], en = noff[v + 1];
  float x = 0.f, y = 0.f, z = 0.f, w = 0.f;
  for (unsigned j = s; j < en; ++j) {
    float4 a = *(const float4*)&ealpha_n[(size_t)j * 4];
    x += a.x; y += a.y; z += a.z; w += a.w;
  }
  *(float4*)&rden[(size_t)v * 4] = make_float4(1.f / (x + 1e-16f), 1.f / (y + 1e-16f),
                                               1.f / (z + 1e-16f), 1.f / (w + 1e-16f));
}

// C[r,o] = sum_k A[r,k] * W[o,k];  A: rows x 128, W: 128 x 128 (row-major)
#define GM 32
__global__ __launch_bounds__(256) void gemm128(const float* __restrict__ A,
                                               const float* __restrict__ W,
                                               float* __restrict__ C, int rows) {
  __shared__ __align__(16) float Ast[128 * 36];  // Ast[k][r], r-pad to 36
  __shared__ __align__(16) float Wt[64 * 132];   // Wt[k][o], k half-tile
  const int tid = threadIdx.x;
  const int row0 = blockIdx.x * GM;

  for (int idx = tid; idx < GM * 128; idx += 256) {
    int r = idx >> 7, k = idx & 127;
    int gr = row0 + r;
    Ast[k * 36 + r] = (gr < rows) ? A[(size_t)gr * 128 + k] : 0.f;
  }

  const int tr = tid >> 5, tc = tid & 31;
  const int r0 = tr * 4, c0 = tc * 4;
  float acc[4][4] = {{0.f}};

  for (int kh = 0; kh < 2; ++kh) {
    __syncthreads();
    for (int idx = tid; idx < 128 * 64; idx += 256) {
      int o = idx >> 6, k = idx & 63;
      Wt[k * 132 + o] = W[o * 128 + kh * 64 + k];
    }
    __syncthreads();
#pragma unroll 8
    for (int k = 0; k < 64; ++k) {
      const int kk = kh * 64 + k;
      float4 a = *(const float4*)&Ast[kk * 36 + r0];
      float4 b = *(const float4*)&Wt[k * 132 + c0];
      acc[0][0] += a.x * b.x; acc[0][1] += a.x * b.y; acc[0][2] += a.x * b.z; acc[0][3] += a.x * b.w;
      acc[1][0] += a.y * b.x; acc[1][1] += a.y * b.y; acc[1][2] += a.y * b.z; acc[1][3] += a.y * b.w;
      acc[2][0] += a.z * b.x; acc[2][1] += a.z * b.y; acc[2][2] += a.z * b.z; acc[2][3] += a.z * b.w;
      acc[3][0] += a.w * b.x; acc[3][1] += a.w * b.y; acc[3][2] += a.w * b.z; acc[3][3] += a.w * b.w;
    }
  }
#pragma unroll
  for (int i = 0; i < 4; ++i) {
    int gr = row0 + r0 + i;
    if (gr < rows)
      *(float4*)&C[(size_t)gr * 128 + c0] = make_float4(acc[i][0], acc[i][1], acc[i][2], acc[i][3]);
  }
}

// ai[v,h] = sum_f feat[v, h*32+f] * att[h*64 + f]
__global__ __launch_bounds__(256) void att_dot(const float* __restrict__ feat,
                                               const float* __restrict__ att,
                                               float* __restrict__ outv, int rows) {
  int idx = blockIdx.x * 256 + threadIdx.x;
  if (idx >= rows * 4) return;
  int v = idx >> 2, h = idx & 3;
  const float4* fp = (const float4*)(feat + (size_t)v * 128 + h * 32);
  const float4* ap = (const float4*)(att + h * 64);
  float s = 0.f;
#pragma unroll
  for (int q = 0; q < 8; ++q) {
    float4 a = ap[q], f = fp[q];
    s += a.x * f.x + a.y * f.y + a.z * f.z + a.w * f.w;
  }
  outv[idx] = s;
}

// u[h,k] = sum_f att1[h*64+32+f] * W_he[(h*32+f)*128 + k]
__global__ __launch_bounds__(256) void make_u(const float* __restrict__ W_he,
                                              const float* __restrict__ att1,
                                              float* __restrict__ u) {
  int idx = blockIdx.x * 256 + threadIdx.x;
  if (idx >= 512) return;
  int h = idx >> 7, k = idx & 127;
  float s = 0.f;
#pragma unroll
  for (int f = 0; f < 32; ++f)
    s += att1[h * 64 + 32 + f] * W_he[(size_t)(h * 32 + f) * 128 + k];
  u[h * 128 + k] = s;
}

// aj[e,h] = hea[e,:] . u[h,:]
__global__ __launch_bounds__(256) void att_dot_full(const float* __restrict__ feat,
                                                    const float* __restrict__ u,
                                                    float* __restrict__ outv, int rows) {
  int idx = blockIdx.x * 256 + threadIdx.x;
  if (idx >= rows * 4) return;
  int v = idx >> 2, h = idx & 3;
  const float4* fp = (const float4*)(feat + (size_t)v * 128);
  const float4* up = (const float4*)(u + h * 128);
  float s = 0.f;
#pragma unroll
  for (int q = 0; q < 32; ++q) {
    float4 a = up[q], f = fp[q];
    s += a.x * f.x + a.y * f.y + a.z * f.z + a.w * f.w;
  }
  outv[idx] = s;
}

#define ECH 256
// out_e[e,t] = Binv[e] * sum_i alpha_norm[i,h] * x1[node_i, t]
__global__ __launch_bounds__(128) void edge_aggregate1(const float* __restrict__ x1,
                                                       const float* __restrict__ ealpha_e,
                                                       const float* __restrict__ rden,
                                                       const float* __restrict__ binv,
                                                       const int* __restrict__ enid,
                                                       const unsigned* __restrict__ eoff,
                                                       float* __restrict__ out_e) {
  __shared__ int nid[ECH];
  __shared__ float wal[ECH][4];
  int e = blockIdx.x, t = threadIdx.x, h = t >> 5;
  unsigned s = eoff[e], en = eoff[e + 1];
  float a0 = 0.f, a1 = 0.f, a2 = 0.f, a3 = 0.f;
  float a4 = 0.f, a5 = 0.f, a6 = 0.f, a7 = 0.f;
  for (unsigned base = s; base < en; base += ECH) {
    int cnt = (int)min((unsigned)ECH, en - base);
    __syncthreads();
    for (int c = t; c < cnt; c += 128) {
      int n = enid[base + c];
      nid[c] = n;
      float4 ea = *(const float4*)&ealpha_e[(size_t)(base + c) * 4];
      float4 rd = *(const float4*)&rden[(size_t)n * 4];
      wal[c][0] = ea.x * rd.x; wal[c][1] = ea.y * rd.y;
      wal[c][2] = ea.z * rd.z; wal[c][3] = ea.w * rd.w;
    }
    __syncthreads();
    int c = 0;
    for (; c + 8 <= cnt; c += 8) {
      a0 += wal[c + 0][h] * x1[(size_t)nid[c + 0] * 128 + t];
      a1 += wal[c + 1][h] * x1[(size_t)nid[c + 1] * 128 + t];
      a2 += wal[c + 2][h] * x1[(size_t)nid[c + 2] * 128 + t];
      a3 += wal[c + 3][h] * x1[(size_t)nid[c + 3] * 128 + t];
      a4 += wal[c + 4][h] * x1[(size_t)nid[c + 4] * 128 + t];
      a5 += wal[c + 5][h] * x1[(size_t)nid[c + 5] * 128 + t];
      a6 += wal[c + 6][h] * x1[(size_t)nid[c + 6] * 128 + t];
      a7 += wal[c + 7][h] * x1[(size_t)nid[c + 7] * 128 + t];
    }
    for (; c < cnt; ++c) a0 += wal[c][h] * x1[(size_t)nid[c] * 128 + t];
  }
  out_e[(size_t)e * 128 + t] = binv[e] * (((a0 + a1) + (a2 + a3)) + ((a4 + a5) + (a6 + a7)));
}

// h[v,t] = elu(Dinv[v]*rden[v,h] * sum_j ealpha_n[j,h]*out_e[neid[j],t] + bias1[t])
__global__ __launch_bounds__(128) void node_aggregate1(const float* __restrict__ out_e,
                                                       const float* __restrict__ ealpha_n,
                                                       const float* __restrict__ rden,
                                                       const float* __restrict__ dinv,
                                                       const float* __restrict__ bias1,
                                                       const int* __restrict__ neid,
                                                       const unsigned* __restrict__ noff,
                                                       float* __restrict__ hout) {
  int v = blockIdx.x, t = threadIdx.x, h = t >> 5;
  unsigned s = noff[v], en = noff[v + 1];
  float rd = dinv[v] * rden[v * 4 + h];
  float a0 = 0.f, a1 = 0.f, a2 = 0.f, a3 = 0.f;
  unsigned j = s;
  for (; j + 4 <= en; j += 4) {
    int e0 = neid[j], e1 = neid[j + 1], e2 = neid[j + 2], e3 = neid[j + 3];
    a0 += ealpha_n[(size_t)j * 4 + h] * out_e[(size_t)e0 * 128 + t];
    a1 += ealpha_n[(size_t)(j + 1) * 4 + h] * out_e[(size_t)e1 * 128 + t];
    a2 += ealpha_n[(size_t)(j + 2) * 4 + h] * out_e[(size_t)e2 * 128 + t];
    a3 += ealpha_n[(size_t)(j + 3) * 4 + h] * out_e[(size_t)e3 * 128 + t];
  }
  for (; j < en; ++j)
    a0 += ealpha_n[(size_t)j * 4 + h] * out_e[(size_t)neid[j] * 128 + t];
  float val = rd * (a0 + a1 + a2 + a3) + bias1[t];
  hout[(size_t)v * 128 + t] = val > 0.f ? val : expm1f(val);
}

// oe_pre[e,t] = Binv[e] * sum_i h[node_i, t]
__global__ __launch_bounds__(128) void edge_aggregate2(const float* __restrict__ hfeat,
                                                       const float* __restrict__ binv,
                                                       const int* __restrict__ enid,
                                                       const unsigned* __restrict__ eoff,
                                                       float* __restrict__ oe) {
  __shared__ int nid[ECH];
  int e = blockIdx.x, t = threadIdx.x;
  unsigned s = eoff[e], en = eoff[e + 1];
  float a0 = 0.f, a1 = 0.f, a2 = 0.f, a3 = 0.f;
  float a4 = 0.f, a5 = 0.f, a6 = 0.f, a7 = 0.f;
  for (unsigned base = s; base < en; base += ECH) {
    int cnt = (int)min((unsigned)ECH, en - base);
    __syncthreads();
    for (int c = t; c < cnt; c += 128) nid[c] = enid[base + c];
    __syncthreads();
    int c = 0;
    for (; c + 8 <= cnt; c += 8) {
      a0 += hfeat[(size_t)nid[c + 0] * 128 + t];
      a1 += hfeat[(size_t)nid[c + 1] * 128 + t];
      a2 += hfeat[(size_t)nid[c + 2] * 128 + t];
      a3 += hfeat[(size_t)nid[c + 3] * 128 + t];
      a4 += hfeat[(size_t)nid[c + 4] * 128 + t];
      a5 += hfeat[(size_t)nid[c + 5] * 128 + t];
      a6 += hfeat[(size_t)nid[c + 6] * 128 + t];
      a7 += hfeat[(size_t)nid[c + 7] * 128 + t];
    }
    for (; c < cnt; ++c) a0 += hfeat[(size_t)nid[c] * 128 + t];
  }
  oe[(size_t)e * 128 + t] = binv[e] * (((a0 + a1) + (a2 + a3)) + ((a4 + a5) + (a6 + a7)));
}

// out[v,t] = Dinv[v] * sum_j oe2[neid[j], t] + bias2[t]
__global__ __launch_bounds__(128) void node_aggregate2(const float* __restrict__ oe2,
                                                       const float* __restrict__ dinv,
                                                       const float* __restrict__ bias2,
                                                       const int* __restrict__ neid,
                                                       const unsigned* __restrict__ noff,
                                                       float* __restrict__ out) {
  int v = blockIdx.x, t = threadIdx.x;
  unsigned s = noff[v], en = noff[v + 1];
  float a0 = 0.f, a1 = 0.f, a2 = 0.f, a3 = 0.f;
  unsigned j = s;
  for (; j + 4 <= en; j += 4) {
    int e0 = neid[j], e1 = neid[j + 1], e2 = neid[j + 2], e3 = neid[j + 3];
    a0 += oe2[(size_t)e0 * 128 + t];
    a1 += oe2[(size_t)e1 * 128 + t];
    a2 += oe2[(size_t)e2 * 128 + t];
    a3 += oe2[(size_t)e3 * 128 + t];
  }
  for (; j < en; ++j) a0 += oe2[(size_t)neid[j] * 128 + t];
  out[(size_t)v * 128 + t] = dinv[v] * (a0 + a1 + a2 + a3) + bias2[t];
}

extern "C" void kernel_launch(void* const* d_in, const int* in_sizes, int n_in,
                              void* d_out, int out_size, void* d_ws, size_t ws_size,
                              hipStream_t stream) {
  (void)n_in; (void)out_size; (void)ws_size;
  const float* x      = (const float*)d_in[0];
  const float* hea    = (const float*)d_in[1];
  const float* lin1W  = (const float*)d_in[2];
  const float* helinW = (const float*)d_in[3];
  const float* att1   = (const float*)d_in[4];
  const float* bias1  = (const float*)d_in[5];
  const float* lin2W  = (const float*)d_in[6];
  const float* bias2  = (const float*)d_in[7];
  const int* node_idx = (const int*)d_in[8];
  const int* edge_idx = (const int*)d_in[9];
  float* out = (float*)d_out;

  const int N   = in_sizes[0] / 128;
  const int M   = in_sizes[1] / 128;
  const int NNZ = in_sizes[8];
  const int NBE = (M + 63) >> E_SHIFT;
  const int NBN = (N + 127) >> N_SHIFT;

  char* base = (char*)d_ws;
  size_t off = 0;
  auto alloc = [&](size_t bytes) -> char* {
    char* p = base + off;
    off = (off + bytes + 255) & ~(size_t)255;
    return p;
  };
  float* x1    = (float*)alloc((size_t)N * 128 * 4);  // x1; later oe2 (M rows)
  float* hbuf  = (float*)alloc((size_t)N * 128 * 4);  // h
  float* heoe  = (float*)alloc((size_t)M * 128 * 4);  // out_e -> oe_pre
  float* ai    = (float*)alloc((size_t)N * 4 * 4);
  float* aj    = (float*)alloc((size_t)M * 4 * 4);
  float* u     = (float*)alloc(512 * 4);
  float* dinv  = (float*)alloc((size_t)N * 4);
  float* binv  = (float*)alloc((size_t)M * 4);
  float* rden  = (float*)alloc((size_t)N * 4 * 4);
  char* zstart = base + off;                           // ---- zeroed region ----
  unsigned* cnt_n = (unsigned*)alloc((size_t)N * 4);
  unsigned* cnt_e = (unsigned*)alloc((size_t)M * 4);
  size_t zbytes = (size_t)((base + off) - zstart);     // ---- end zero region ----
  float* ealpha_e = (float*)alloc((size_t)NNZ * 4 * 4);
  float* ealpha_n = (float*)alloc((size_t)NNZ * 4 * 4);
  unsigned* tmp_e = (unsigned*)alloc((size_t)NNZ * 4);
  unsigned* tmp_n = (unsigned*)alloc((size_t)NNZ * 4);
  unsigned* noff  = (unsigned*)alloc((size_t)(N + 1) * 4);
  unsigned* eoff  = (unsigned*)alloc((size_t)(M + 1) * 4);
  unsigned* bcur_e = (unsigned*)alloc((size_t)NBE * 4);
  unsigned* bcur_n = (unsigned*)alloc((size_t)NBN * 4);
  int* enid       = (int*)alloc((size_t)NNZ * 4);
  int* neid       = (int*)alloc((size_t)NNZ * 4);
  unsigned* bsum  = (unsigned*)alloc(1024 * 4);
  unsigned* boff  = (unsigned*)alloc(1024 * 4);

  hipMemsetAsync(zstart, 0, zbytes, stream);

  const int g_nnz = (NNZ + 255) / 256;
  count_deg<<<g_nnz, 256, 0, stream>>>(node_idx, edge_idx, cnt_n, cnt_e, NNZ);

  const int nbE = (M + 1 + 1023) / 1024;
  const int nbN = (N + 1 + 1023) / 1024;
  scan_pass1<<<nbE, 1024, 0, stream>>>(cnt_e, bsum, M);
  scan_pass2<<<1, 1024, 0, stream>>>(bsum, boff, nbE);
  scan_pass3<<<nbE, 1024, 0, stream>>>(cnt_e, boff, eoff, M);
  scan_pass1<<<nbN, 1024, 0, stream>>>(cnt_n, bsum, N);
  scan_pass2<<<1, 1024, 0, stream>>>(bsum, boff, nbN);
  scan_pass3<<<nbN, 1024, 0, stream>>>(cnt_n, boff, noff, N);

  make_inv<<<(N + 255) / 256, 256, 0, stream>>>(cnt_n, dinv, N);
  make_inv<<<(M + 255) / 256, 256, 0, stream>>>(cnt_e, binv, M);
  init_bcur<<<(max(NBE, NBN) + 255) / 256, 256, 0, stream>>>(eoff, noff, bcur_e, bcur_n,
                                                             NBE, NBN, M, N);
  partition2<<<(NNZ + PCHUNK - 1) / PCHUNK, 256, 0, stream>>>(node_idx, edge_idx, bcur_e,
                                                              bcur_n, tmp_e, tmp_n, NNZ);

  gemm128<<<(N + GM - 1) / GM, 256, 0, stream>>>(x, lin1W, x1, N);
  att_dot<<<(N * 4 + 255) / 256, 256, 0, stream>>>(x1, att1, ai, N);
  make_u<<<2, 256, 0, stream>>>(helinW, att1, u);
  att_dot_full<<<(M * 4 + 255) / 256, 256, 0, stream>>>(hea, u, aj, M);

  sort_edge_exp<<<NBE, 256, 0, stream>>>(tmp_e, eoff, M, ai, aj, ealpha_e, enid);
  sort_node_exp<<<NBN, 256, 0, stream>>>(tmp_n, noff, N, ai, aj, ealpha_n, neid);
  node_denom2<<<(N + 255) / 256, 256, 0, stream>>>(noff, ealpha_n, rden, N);

  edge_aggregate1<<<M, 128, 0, stream>>>(x1, ealpha_e, rden, binv, enid, eoff, heoe);
  node_aggregate1<<<N, 128, 0, stream>>>(heoe, ealpha_n, rden, dinv, bias1, neid, noff, hbuf);

  edge_aggregate2<<<M, 128, 0, stream>>>(hbuf, binv, enid, eoff, heoe);
  gemm128<<<(M + GM - 1) / GM, 256, 0, stream>>>(heoe, lin2W, x1, M);  // oe2 into x1 buf
  node_aggregate2<<<N, 128, 0, stream>>>(x1, dinv, bias2, neid, noff, out);
}

// Round 6
// 599.023 us; speedup vs baseline: 1.7254x; 1.0245x over previous
//
#include <hip/hip_runtime.h>
#include <cstdint>

// ---------------------------------------------------------------------------
// HCHA (hypergraph conv with attention), f32.
// N=100000 nodes, M=20000 hyperedges, NNZ=1e6, C=128, HEADS=4, FH=32.
// CSR build: block-local multi-split partition (u32 payloads) -> per-bucket
// LDS counting sort which ALSO evaluates exp(leakyrelu(ai+aj)) and emits
// edge-ordered / node-ordered alpha streams.
// GEMM: A-tile transposed in LDS (broadcast b128 reads), W^T pre-transposed
// to global (L2-resident, wave-uniform row reads), ai head-dot fused into
// the layer-1 GEMM epilogue.
// ---------------------------------------------------------------------------

#define E_SHIFT 6
#define N_SHIFT 7
#define EB_CAP 4096
#define NB_CAP 2048
#define PCHUNK 4096
#define NBE_CAP 320   // >= ceil(M/64)  = 313
#define NBN_CAP 800   // >= ceil(N/128) = 782

__global__ __launch_bounds__(256) void count_deg(const int* __restrict__ node_idx,
                                                 const int* __restrict__ edge_idx,
                                                 unsigned* __restrict__ cnt_n,
                                                 unsigned* __restrict__ cnt_e, int nnz) {
  int i = blockIdx.x * 256 + threadIdx.x;
  if (i < nnz) {
    atomicAdd(&cnt_n[node_idx[i]], 1u);
    atomicAdd(&cnt_e[edge_idx[i]], 1u);
  }
}

__device__ __forceinline__ unsigned wave_incl_scan(unsigned x) {
#pragma unroll
  for (int s = 1; s < 64; s <<= 1) {
    unsigned t = __shfl_up(x, s, 64);
    if ((int)(threadIdx.x & 63) >= s) x += t;
  }
  return x;
}

__global__ __launch_bounds__(1024) void scan_pass1(const unsigned* __restrict__ cnt,
                                                   unsigned* __restrict__ bsum, int L) {
  int i = blockIdx.x * 1024 + threadIdx.x;
  unsigned v = (i < L) ? cnt[i] : 0u;
  unsigned incl = wave_incl_scan(v);
  __shared__ unsigned wsum[16];
  int lane = threadIdx.x & 63, wid = threadIdx.x >> 6;
  if (lane == 63) wsum[wid] = incl;
  __syncthreads();
  if (threadIdx.x == 0) {
    unsigned t = 0;
#pragma unroll
    for (int w = 0; w < 16; ++w) t += wsum[w];
    bsum[blockIdx.x] = t;
  }
}

__global__ __launch_bounds__(1024) void scan_pass2(const unsigned* __restrict__ bsum,
                                                   unsigned* __restrict__ boff, int nb) {
  int i = threadIdx.x;
  unsigned v = (i < nb) ? bsum[i] : 0u;
  unsigned incl = wave_incl_scan(v);
  __shared__ unsigned wsum[16];
  int lane = threadIdx.x & 63, wid = threadIdx.x >> 6;
  if (lane == 63) wsum[wid] = incl;
  __syncthreads();
  unsigned add = 0;
  for (int w = 0; w < wid; ++w) add += wsum[w];
  if (i < nb) boff[i] = add + incl - v;  // exclusive
}

__global__ __launch_bounds__(1024) void scan_pass3(const unsigned* __restrict__ cnt,
                                                   const unsigned* __restrict__ boff,
                                                   unsigned* __restrict__ off, int L) {
  int i = blockIdx.x * 1024 + threadIdx.x;
  unsigned v = (i < L) ? cnt[i] : 0u;
  unsigned incl = wave_incl_scan(v);
  __shared__ unsigned wsum[16];
  int lane = threadIdx.x & 63, wid = threadIdx.x >> 6;
  if (lane == 63) wsum[wid] = incl;
  __syncthreads();
  unsigned add = boff[blockIdx.x];
  for (int w = 0; w < wid; ++w) add += wsum[w];
  unsigned excl = add + incl - v;
  if (i < L) off[i] = excl;
  if (i == L) off[L] = excl;  // total
}

__global__ __launch_bounds__(256) void make_inv(const unsigned* __restrict__ cnt,
                                                float* __restrict__ inv, int L) {
  int i = blockIdx.x * 256 + threadIdx.x;
  if (i < L) inv[i] = cnt[i] ? 1.f / (float)cnt[i] : 0.f;
}

__global__ __launch_bounds__(256) void init_bcur(const unsigned* __restrict__ eoff,
                                                 const unsigned* __restrict__ noff,
                                                 unsigned* __restrict__ bcur_e,
                                                 unsigned* __restrict__ bcur_n,
                                                 int nbe, int nbn, int M_, int N_) {
  int i = blockIdx.x * 256 + threadIdx.x;
  if (i < nbe) bcur_e[i] = eoff[min(i << E_SHIFT, M_)];
  if (i < nbn) bcur_n[i] = noff[min(i << N_SHIFT, N_)];
}

// pass B: block-local multi-split. LDS histogram -> one global atomic per
// (block,bucket) to reserve ranges -> LDS-cursor scatter of u32 payloads.
__global__ __launch_bounds__(256) void partition2(const int* __restrict__ node_idx,
                                                  const int* __restrict__ edge_idx,
                                                  unsigned* __restrict__ bcur_e,
                                                  unsigned* __restrict__ bcur_n,
                                                  unsigned* __restrict__ tmp_e,
                                                  unsigned* __restrict__ tmp_n, int nnz) {
  __shared__ unsigned he[NBE_CAP];
  __shared__ unsigned hn[NBN_CAP];
  const int t = threadIdx.x;
  const int base = blockIdx.x * PCHUNK;
  const int cnt = min(PCHUNK, nnz - base);

  for (int b = t; b < NBE_CAP; b += 256) he[b] = 0;
  for (int b = t; b < NBN_CAP; b += 256) hn[b] = 0;
  __syncthreads();

  for (int idx = t; idx < cnt; idx += 256) {
    unsigned e = (unsigned)edge_idx[base + idx];
    unsigned n = (unsigned)node_idx[base + idx];
    atomicAdd(&he[e >> E_SHIFT], 1u);
    atomicAdd(&hn[n >> N_SHIFT], 1u);
  }
  __syncthreads();

  for (int b = t; b < NBE_CAP; b += 256) {
    unsigned c = he[b];
    he[b] = c ? atomicAdd(&bcur_e[b], c) : 0u;   // bucket range base -> cursor
  }
  for (int b = t; b < NBN_CAP; b += 256) {
    unsigned c = hn[b];
    hn[b] = c ? atomicAdd(&bcur_n[b], c) : 0u;
  }
  __syncthreads();

  for (int idx = t; idx < cnt; idx += 256) {
    unsigned e = (unsigned)edge_idx[base + idx];
    unsigned n = (unsigned)node_idx[base + idx];
    unsigned pe = atomicAdd(&he[e >> E_SHIFT], 1u);
    tmp_e[pe] = ((e & 63u) << 17) | n;
    unsigned pn = atomicAdd(&hn[n >> N_SHIFT], 1u);
    tmp_n[pn] = ((n & 127u) << 15) | e;
  }
}

__device__ __forceinline__ float4 alpha4(const float* __restrict__ ai,
                                         const float* __restrict__ aj,
                                         unsigned n, unsigned e) {
  float4 av = *(const float4*)&ai[(size_t)n * 4];
  float4 bv = *(const float4*)&aj[(size_t)e * 4];
  float v0 = av.x + bv.x, v1 = av.y + bv.y, v2 = av.z + bv.z, v3 = av.w + bv.w;
  v0 = v0 > 0.f ? v0 : 0.2f * v0;
  v1 = v1 > 0.f ? v1 : 0.2f * v1;
  v2 = v2 > 0.f ? v2 : 0.2f * v2;
  v3 = v3 > 0.f ? v3 : 0.2f * v3;
  return make_float4(expf(v0), expf(v1), expf(v2), expf(v3));
}

// pass C (edges): per-bucket LDS counting sort; coalesced writes of
// edge-ordered node ids + exp(leakyrelu(ai+aj)) stream.
__global__ __launch_bounds__(256) void sort_edge_exp(const unsigned* __restrict__ tmp,
                                                     const unsigned* __restrict__ eoff,
                                                     int M_,
                                                     const float* __restrict__ ai,
                                                     const float* __restrict__ aj,
                                                     float* __restrict__ ealpha_e,
                                                     int* __restrict__ enid) {
  __shared__ unsigned cur[64];
  __shared__ unsigned sbuf[EB_CAP];
  int b = blockIdx.x, t = threadIdx.x;
  int e0 = b << E_SHIFT;
  unsigned base = eoff[min(e0, M_)];
  unsigned end  = eoff[min(e0 + 64, M_)];
  if (t < 64) cur[t] = eoff[min(e0 + t, M_)] - base;
  __syncthreads();
  int cnt = (int)(end - base);
  for (int idx = t; idx < cnt; idx += 256) {
    unsigned p = tmp[base + idx];
    unsigned key = p >> 17;
    unsigned pos = atomicAdd(&cur[key], 1u);
    if (pos < EB_CAP) {
      sbuf[pos] = p;
    } else {  // overflow fallback (statistically never)
      unsigned n = p & 0x1FFFFu;
      *(float4*)&ealpha_e[(size_t)(base + pos) * 4] = alpha4(ai, aj, n, e0 + key);
      enid[base + pos] = (int)n;
    }
  }
  __syncthreads();
  int lim = min(cnt, EB_CAP);
  for (int idx = t; idx < lim; idx += 256) {
    unsigned p = sbuf[idx];
    unsigned key = p >> 17, n = p & 0x1FFFFu;
    *(float4*)&ealpha_e[(size_t)(base + idx) * 4] = alpha4(ai, aj, n, e0 + key);
    enid[base + idx] = (int)n;
  }
}

// pass C (nodes): coalesced node-ordered edge ids + alpha stream.
__global__ __launch_bounds__(256) void sort_node_exp(const unsigned* __restrict__ tmp,
                                                     const unsigned* __restrict__ noff,
                                                     int N_,
                                                     const float* __restrict__ ai,
                                                     const float* __restrict__ aj,
                                                     float* __restrict__ ealpha_n,
                                                     int* __restrict__ neid) {
  __shared__ unsigned cur[128];
  __shared__ unsigned sbuf[NB_CAP];
  int b = blockIdx.x, t = threadIdx.x;
  int n0 = b << N_SHIFT;
  unsigned base = noff[min(n0, N_)];
  unsigned end  = noff[min(n0 + 128, N_)];
  if (t < 128) cur[t] = noff[min(n0 + t, N_)] - base;
  __syncthreads();
  int cnt = (int)(end - base);
  for (int idx = t; idx < cnt; idx += 256) {
    unsigned p = tmp[base + idx];
    unsigned key = p >> 15;
    unsigned pos = atomicAdd(&cur[key], 1u);
    if (pos < NB_CAP) {
      sbuf[pos] = p;
    } else {
      unsigned e = p & 0x7FFFu;
      *(float4*)&ealpha_n[(size_t)(base + pos) * 4] = alpha4(ai, aj, n0 + key, e);
      neid[base + pos] = (int)e;
    }
  }
  __syncthreads();
  int lim = min(cnt, NB_CAP);
  for (int idx = t; idx < lim; idx += 256) {
    unsigned p = sbuf[idx];
    unsigned key = p >> 15, e = p & 0x7FFFu;
    *(float4*)&ealpha_n[(size_t)(base + idx) * 4] = alpha4(ai, aj, n0 + key, e);
    neid[base + idx] = (int)e;
  }
}

// rden[v,h] = 1/(sum_{j in node range} ealpha_n[j,h] + 1e-16), sequential read
__global__ __launch_bounds__(256) void node_denom2(const unsigned* __restrict__ noff,
                                                   const float* __restrict__ ealpha_n,
                                                   float* __restrict__ rden, int N) {
  int v = blockIdx.x * 256 + threadIdx.x;
  if (v >= N) return;
  unsigned s = noff[v], en = noff[v + 1];
  float x = 0.f, y = 0.f, z = 0.f, w = 0.f;
  for (unsigned j = s; j < en; ++j) {
    float4 a = *(const float4*)&ealpha_n[(size_t)j * 4];
    x += a.x; y += a.y; z += a.z; w += a.w;
  }
  *(float4*)&rden[(size_t)v * 4] = make_float4(1.f / (x + 1e-16f), 1.f / (y + 1e-16f),
                                               1.f / (z + 1e-16f), 1.f / (w + 1e-16f));
}

// WT[k*128+o] = W[o*128+k]   (one-time 64KB transpose)
__global__ __launch_bounds__(256) void wtrans(const float* __restrict__ W,
                                              float* __restrict__ WT) {
  int idx = blockIdx.x * 256 + threadIdx.x;
  if (idx >= 128 * 128) return;
  int k = idx >> 7, o = idx & 127;
  WT[idx] = W[o * 128 + k];
}

// C[r,o] = sum_k A[r,k] * WT[k,o]; A rows x 128, WT 128x128 (pre-transposed).
// Optional fused head-dot epilogue: aiout[r,h] = sum_f C[r,h*32+f]*att[h*64+f].
#define GM 64
__global__ __launch_bounds__(256) void gemm128t(const float* __restrict__ A,
                                                const float* __restrict__ WT,
                                                float* __restrict__ C, int rows,
                                                const float* __restrict__ att,
                                                float* __restrict__ aiout) {
  __shared__ __align__(16) float Ast[128 * 68];  // Ast[k][r], r-pad to 68
  const int tid = threadIdx.x;
  const int row0 = blockIdx.x * GM;

  for (int idx = tid; idx < GM * 128; idx += 256) {
    int r = idx >> 7, k = idx & 127;
    int gr = row0 + r;
    Ast[k * 68 + r] = (gr < rows) ? A[(size_t)gr * 128 + k] : 0.f;
  }
  __syncthreads();

  const int tr = tid >> 5, tc = tid & 31;
  const int r0 = tr * 8, c0 = tc * 4;
  float acc[8][4] = {{0.f}};

#pragma unroll 4
  for (int k = 0; k < 128; ++k) {
    float4 b  = *(const float4*)&WT[k * 128 + c0];
    float4 a0 = *(const float4*)&Ast[k * 68 + r0];
    float4 a1 = *(const float4*)&Ast[k * 68 + r0 + 4];
    acc[0][0] += a0.x * b.x; acc[0][1] += a0.x * b.y; acc[0][2] += a0.x * b.z; acc[0][3] += a0.x * b.w;
    acc[1][0] += a0.y * b.x; acc[1][1] += a0.y * b.y; acc[1][2] += a0.y * b.z; acc[1][3] += a0.y * b.w;
    acc[2][0] += a0.z * b.x; acc[2][1] += a0.z * b.y; acc[2][2] += a0.z * b.z; acc[2][3] += a0.z * b.w;
    acc[3][0] += a0.w * b.x; acc[3][1] += a0.w * b.y; acc[3][2] += a0.w * b.z; acc[3][3] += a0.w * b.w;
    acc[4][0] += a1.x * b.x; acc[4][1] += a1.x * b.y; acc[4][2] += a1.x * b.z; acc[4][3] += a1.x * b.w;
    acc[5][0] += a1.y * b.x; acc[5][1] += a1.y * b.y; acc[5][2] += a1.y * b.z; acc[5][3] += a1.y * b.w;
    acc[6][0] += a1.z * b.x; acc[6][1] += a1.z * b.y; acc[6][2] += a1.z * b.z; acc[6][3] += a1.z * b.w;
    acc[7][0] += a1.w * b.x; acc[7][1] += a1.w * b.y; acc[7][2] += a1.w * b.z; acc[7][3] += a1.w * b.w;
  }

#pragma unroll
  for (int i = 0; i < 8; ++i) {
    int gr = row0 + r0 + i;
    if (gr < rows)
      *(float4*)&C[(size_t)gr * 128 + c0] = make_float4(acc[i][0], acc[i][1], acc[i][2], acc[i][3]);
  }

  if (att) {  // fused ai head-dot: cols c0..c0+3 all in head h = tc>>3
    int h = tc >> 3;
    float4 w = *(const float4*)&att[h * 64 + (c0 & 31)];
#pragma unroll
    for (int i = 0; i < 8; ++i) {
      float p = acc[i][0] * w.x + acc[i][1] * w.y + acc[i][2] * w.z + acc[i][3] * w.w;
      p += __shfl_xor(p, 1);
      p += __shfl_xor(p, 2);
      p += __shfl_xor(p, 4);
      if ((tc & 7) == 0) {
        int gr = row0 + r0 + i;
        if (gr < rows) aiout[(size_t)gr * 4 + h] = p;
      }
    }
  }
}

// u[h,k] = sum_f att1[h*64+32+f] * W_he[(h*32+f)*128 + k]
__global__ __launch_bounds__(256) void make_u(const float* __restrict__ W_he,
                                              const float* __restrict__ att1,
                                              float* __restrict__ u) {
  int idx = blockIdx.x * 256 + threadIdx.x;
  if (idx >= 512) return;
  int h = idx >> 7, k = idx & 127;
  float s = 0.f;
#pragma unroll
  for (int f = 0; f < 32; ++f)
    s += att1[h * 64 + 32 + f] * W_he[(size_t)(h * 32 + f) * 128 + k];
  u[h * 128 + k] = s;
}

// aj[e,h] = hea[e,:] . u[h,:]
__global__ __launch_bounds__(256) void att_dot_full(const float* __restrict__ feat,
                                                    const float* __restrict__ u,
                                                    float* __restrict__ outv, int rows) {
  int idx = blockIdx.x * 256 + threadIdx.x;
  if (idx >= rows * 4) return;
  int v = idx >> 2, h = idx & 3;
  const float4* fp = (const float4*)(feat + (size_t)v * 128);
  const float4* up = (const float4*)(u + h * 128);
  float s = 0.f;
#pragma unroll
  for (int q = 0; q < 32; ++q) {
    float4 a = up[q], f = fp[q];
    s += a.x * f.x + a.y * f.y + a.z * f.z + a.w * f.w;
  }
  outv[idx] = s;
}

#define ECH 256
// out_e[e,t] = Binv[e] * sum_i alpha_norm[i,h] * x1[node_i, t]
__global__ __launch_bounds__(128) void edge_aggregate1(const float* __restrict__ x1,
                                                       const float* __restrict__ ealpha_e,
                                                       const float* __restrict__ rden,
                                                       const float* __restrict__ binv,
                                                       const int* __restrict__ enid,
                                                       const unsigned* __restrict__ eoff,
                                                       float* __restrict__ out_e) {
  __shared__ int nid[ECH];
  __shared__ float wal[ECH][4];
  int e = blockIdx.x, t = threadIdx.x, h = t >> 5;
  unsigned s = eoff[e], en = eoff[e + 1];
  float a0 = 0.f, a1 = 0.f, a2 = 0.f, a3 = 0.f;
  float a4 = 0.f, a5 = 0.f, a6 = 0.f, a7 = 0.f;
  for (unsigned base = s; base < en; base += ECH) {
    int cnt = (int)min((unsigned)ECH, en - base);
    __syncthreads();
    for (int c = t; c < cnt; c += 128) {
      int n = enid[base + c];
      nid[c] = n;
      float4 ea = *(const float4*)&ealpha_e[(size_t)(base + c) * 4];
      float4 rd = *(const float4*)&rden[(size_t)n * 4];
      wal[c][0] = ea.x * rd.x; wal[c][1] = ea.y * rd.y;
      wal[c][2] = ea.z * rd.z; wal[c][3] = ea.w * rd.w;
    }
    __syncthreads();
    int c = 0;
    for (; c + 8 <= cnt; c += 8) {
      a0 += wal[c + 0][h] * x1[(size_t)nid[c + 0] * 128 + t];
      a1 += wal[c + 1][h] * x1[(size_t)nid[c + 1] * 128 + t];
      a2 += wal[c + 2][h] * x1[(size_t)nid[c + 2] * 128 + t];
      a3 += wal[c + 3][h] * x1[(size_t)nid[c + 3] * 128 + t];
      a4 += wal[c + 4][h] * x1[(size_t)nid[c + 4] * 128 + t];
      a5 += wal[c + 5][h] * x1[(size_t)nid[c + 5] * 128 + t];
      a6 += wal[c + 6][h] * x1[(size_t)nid[c + 6] * 128 + t];
      a7 += wal[c + 7][h] * x1[(size_t)nid[c + 7] * 128 + t];
    }
    for (; c < cnt; ++c) a0 += wal[c][h] * x1[(size_t)nid[c] * 128 + t];
  }
  out_e[(size_t)e * 128 + t] = binv[e] * (((a0 + a1) + (a2 + a3)) + ((a4 + a5) + (a6 + a7)));
}

// h[v,t] = elu(Dinv[v]*rden[v,h] * sum_j ealpha_n[j,h]*out_e[neid[j],t] + bias1[t])
__global__ __launch_bounds__(128) void node_aggregate1(const float* __restrict__ out_e,
                                                       const float* __restrict__ ealpha_n,
                                                       const float* __restrict__ rden,
                                                       const float* __restrict__ dinv,
                                                       const float* __restrict__ bias1,
                                                       const int* __restrict__ neid,
                                                       const unsigned* __restrict__ noff,
                                                       float* __restrict__ hout) {
  int v = blockIdx.x, t = threadIdx.x, h = t >> 5;
  unsigned s = noff[v], en = noff[v + 1];
  float rd = dinv[v] * rden[v * 4 + h];
  float a0 = 0.f, a1 = 0.f, a2 = 0.f, a3 = 0.f;
  unsigned j = s;
  for (; j + 4 <= en; j += 4) {
    int e0 = neid[j], e1 = neid[j + 1], e2 = neid[j + 2], e3 = neid[j + 3];
    a0 += ealpha_n[(size_t)j * 4 + h] * out_e[(size_t)e0 * 128 + t];
    a1 += ealpha_n[(size_t)(j + 1) * 4 + h] * out_e[(size_t)e1 * 128 + t];
    a2 += ealpha_n[(size_t)(j + 2) * 4 + h] * out_e[(size_t)e2 * 128 + t];
    a3 += ealpha_n[(size_t)(j + 3) * 4 + h] * out_e[(size_t)e3 * 128 + t];
  }
  for (; j < en; ++j)
    a0 += ealpha_n[(size_t)j * 4 + h] * out_e[(size_t)neid[j] * 128 + t];
  float val = rd * (a0 + a1 + a2 + a3) + bias1[t];
  hout[(size_t)v * 128 + t] = val > 0.f ? val : expm1f(val);
}

// oe_pre[e,t] = Binv[e] * sum_i h[node_i, t]
__global__ __launch_bounds__(128) void edge_aggregate2(const float* __restrict__ hfeat,
                                                       const float* __restrict__ binv,
                                                       const int* __restrict__ enid,
                                                       const unsigned* __restrict__ eoff,
                                                       float* __restrict__ oe) {
  __shared__ int nid[ECH];
  int e = blockIdx.x, t = threadIdx.x;
  unsigned s = eoff[e], en = eoff[e + 1];
  float a0 = 0.f, a1 = 0.f, a2 = 0.f, a3 = 0.f;
  float a4 = 0.f, a5 = 0.f, a6 = 0.f, a7 = 0.f;
  for (unsigned base = s; base < en; base += ECH) {
    int cnt = (int)min((unsigned)ECH, en - base);
    __syncthreads();
    for (int c = t; c < cnt; c += 128) nid[c] = enid[base + c];
    __syncthreads();
    int c = 0;
    for (; c + 8 <= cnt; c += 8) {
      a0 += hfeat[(size_t)nid[c + 0] * 128 + t];
      a1 += hfeat[(size_t)nid[c + 1] * 128 + t];
      a2 += hfeat[(size_t)nid[c + 2] * 128 + t];
      a3 += hfeat[(size_t)nid[c + 3] * 128 + t];
      a4 += hfeat[(size_t)nid[c + 4] * 128 + t];
      a5 += hfeat[(size_t)nid[c + 5] * 128 + t];
      a6 += hfeat[(size_t)nid[c + 6] * 128 + t];
      a7 += hfeat[(size_t)nid[c + 7] * 128 + t];
    }
    for (; c < cnt; ++c) a0 += hfeat[(size_t)nid[c] * 128 + t];
  }
  oe[(size_t)e * 128 + t] = binv[e] * (((a0 + a1) + (a2 + a3)) + ((a4 + a5) + (a6 + a7)));
}

// out[v,t] = Dinv[v] * sum_j oe2[neid[j], t] + bias2[t]
__global__ __launch_bounds__(128) void node_aggregate2(const float* __restrict__ oe2,
                                                       const float* __restrict__ dinv,
                                                       const float* __restrict__ bias2,
                                                       const int* __restrict__ neid,
                                                       const unsigned* __restrict__ noff,
                                                       float* __restrict__ out) {
  int v = blockIdx.x, t = threadIdx.x;
  unsigned s = noff[v], en = noff[v + 1];
  float a0 = 0.f, a1 = 0.f, a2 = 0.f, a3 = 0.f;
  unsigned j = s;
  for (; j + 4 <= en; j += 4) {
    int e0 = neid[j], e1 = neid[j + 1], e2 = neid[j + 2], e3 = neid[j + 3];
    a0 += oe2[(size_t)e0 * 128 + t];
    a1 += oe2[(size_t)e1 * 128 + t];
    a2 += oe2[(size_t)e2 * 128 + t];
    a3 += oe2[(size_t)e3 * 128 + t];
  }
  for (; j < en; ++j) a0 += oe2[(size_t)neid[j] * 128 + t];
  out[(size_t)v * 128 + t] = dinv[v] * (a0 + a1 + a2 + a3) + bias2[t];
}

extern "C" void kernel_launch(void* const* d_in, const int* in_sizes, int n_in,
                              void* d_out, int out_size, void* d_ws, size_t ws_size,
                              hipStream_t stream) {
  (void)n_in; (void)out_size; (void)ws_size;
  const float* x      = (const float*)d_in[0];
  const float* hea    = (const float*)d_in[1];
  const float* lin1W  = (const float*)d_in[2];
  const float* helinW = (const float*)d_in[3];
  const float* att1   = (const float*)d_in[4];
  const float* bias1  = (const float*)d_in[5];
  const float* lin2W  = (const float*)d_in[6];
  const float* bias2  = (const float*)d_in[7];
  const int* node_idx = (const int*)d_in[8];
  const int* edge_idx = (const int*)d_in[9];
  float* out = (float*)d_out;

  const int N   = in_sizes[0] / 128;
  const int M   = in_sizes[1] / 128;
  const int NNZ = in_sizes[8];
  const int NBE = (M + 63) >> E_SHIFT;
  const int NBN = (N + 127) >> N_SHIFT;

  char* base = (char*)d_ws;
  size_t off = 0;
  auto alloc = [&](size_t bytes) -> char* {
    char* p = base + off;
    off = (off + bytes + 255) & ~(size_t)255;
    return p;
  };
  float* x1    = (float*)alloc((size_t)N * 128 * 4);  // x1; later oe2 (M rows)
  float* hbuf  = (float*)alloc((size_t)N * 128 * 4);  // h
  float* heoe  = (float*)alloc((size_t)M * 128 * 4);  // out_e -> oe_pre
  float* ai    = (float*)alloc((size_t)N * 4 * 4);
  float* aj    = (float*)alloc((size_t)M * 4 * 4);
  float* u     = (float*)alloc(512 * 4);
  float* WT1   = (float*)alloc(128 * 128 * 4);
  float* WT2   = (float*)alloc(128 * 128 * 4);
  float* dinv  = (float*)alloc((size_t)N * 4);
  float* binv  = (float*)alloc((size_t)M * 4);
  float* rden  = (float*)alloc((size_t)N * 4 * 4);
  char* zstart = base + off;                           // ---- zeroed region ----
  unsigned* cnt_n = (unsigned*)alloc((size_t)N * 4);
  unsigned* cnt_e = (unsigned*)alloc((size_t)M * 4);
  size_t zbytes = (size_t)((base + off) - zstart);     // ---- end zero region ----
  float* ealpha_e = (float*)alloc((size_t)NNZ * 4 * 4);
  float* ealpha_n = (float*)alloc((size_t)NNZ * 4 * 4);
  unsigned* tmp_e = (unsigned*)alloc((size_t)NNZ * 4);
  unsigned* tmp_n = (unsigned*)alloc((size_t)NNZ * 4);
  unsigned* noff  = (unsigned*)alloc((size_t)(N + 1) * 4);
  unsigned* eoff  = (unsigned*)alloc((size_t)(M + 1) * 4);
  unsigned* bcur_e = (unsigned*)alloc((size_t)NBE * 4);
  unsigned* bcur_n = (unsigned*)alloc((size_t)NBN * 4);
  int* enid       = (int*)alloc((size_t)NNZ * 4);
  int* neid       = (int*)alloc((size_t)NNZ * 4);
  unsigned* bsum  = (unsigned*)alloc(1024 * 4);
  unsigned* boff  = (unsigned*)alloc(1024 * 4);

  hipMemsetAsync(zstart, 0, zbytes, stream);

  const int g_nnz = (NNZ + 255) / 256;
  count_deg<<<g_nnz, 256, 0, stream>>>(node_idx, edge_idx, cnt_n, cnt_e, NNZ);

  const int nbE = (M + 1 + 1023) / 1024;
  const int nbN = (N + 1 + 1023) / 1024;
  scan_pass1<<<nbE, 1024, 0, stream>>>(cnt_e, bsum, M);
  scan_pass2<<<1, 1024, 0, stream>>>(bsum, boff, nbE);
  scan_pass3<<<nbE, 1024, 0, stream>>>(cnt_e, boff, eoff, M);
  scan_pass1<<<nbN, 1024, 0, stream>>>(cnt_n, bsum, N);
  scan_pass2<<<1, 1024, 0, stream>>>(bsum, boff, nbN);
  scan_pass3<<<nbN, 1024, 0, stream>>>(cnt_n, boff, noff, N);

  make_inv<<<(N + 255) / 256, 256, 0, stream>>>(cnt_n, dinv, N);
  make_inv<<<(M + 255) / 256, 256, 0, stream>>>(cnt_e, binv, M);
  init_bcur<<<(max(NBE, NBN) + 255) / 256, 256, 0, stream>>>(eoff, noff, bcur_e, bcur_n,
                                                             NBE, NBN, M, N);
  partition2<<<(NNZ + PCHUNK - 1) / PCHUNK, 256, 0, stream>>>(node_idx, edge_idx, bcur_e,
                                                              bcur_n, tmp_e, tmp_n, NNZ);

  wtrans<<<64, 256, 0, stream>>>(lin1W, WT1);
  wtrans<<<64, 256, 0, stream>>>(lin2W, WT2);
  gemm128t<<<(N + GM - 1) / GM, 256, 0, stream>>>(x, WT1, x1, N, att1, ai);
  make_u<<<2, 256, 0, stream>>>(helinW, att1, u);
  att_dot_full<<<(M * 4 + 255) / 256, 256, 0, stream>>>(hea, u, aj, M);

  sort_edge_exp<<<NBE, 256, 0, stream>>>(tmp_e, eoff, M, ai, aj, ealpha_e, enid);
  sort_node_exp<<<NBN, 256, 0, stream>>>(tmp_n, noff, N, ai, aj, ealpha_n, neid);
  node_denom2<<<(N + 255) / 256, 256, 0, stream>>>(noff, ealpha_n, rden, N);

  edge_aggregate1<<<M, 128, 0, stream>>>(x1, ealpha_e, rden, binv, enid, eoff, heoe);
  node_aggregate1<<<N, 128, 0, stream>>>(heoe, ealpha_n, rden, dinv, bias1, neid, noff, hbuf);

  edge_aggregate2<<<M, 128, 0, stream>>>(hbuf, binv, enid, eoff, heoe);
  gemm128t<<<(M + GM - 1) / GM, 256, 0, stream>>>(heoe, WT2, x1, M, nullptr, nullptr);
  node_aggregate2<<<N, 128, 0, stream>>>(x1, dinv, bias2, neid, noff, out);
}

// Round 7
// 521.859 us; speedup vs baseline: 1.9805x; 1.1479x over previous
//
#include <hip/hip_runtime.h>
#include <cstdint>

// ---------------------------------------------------------------------------
// HCHA (hypergraph conv with attention), f32.
// N=100000 nodes, M=20000 hyperedges, NNZ=1e6, C=128, HEADS=4, FH=32.
// CSR build: bucket_count (per-block LDS hist -> global bucket totals, no
// per-id atomics anywhere) -> 1-block scan of ~1100 bucket totals ->
// block-local multi-split partition -> per-bucket LDS counting sort which
// computes per-id counts/offsets LOCALLY (emits eoff/noff/binv/dinv) and
// evaluates exp(leakyrelu(ai+aj)) into edge-/node-ordered alpha streams.
// GEMM: A-tile transposed in LDS (broadcast b128 reads), W^T pre-transposed
// to global, ai head-dot fused into the layer-1 GEMM epilogue.
// Packing: e < 2^15 (M=20000), n < 2^17 (N=1e5).
// ---------------------------------------------------------------------------

#define E_SHIFT 6
#define N_SHIFT 7
#define EB_CAP 4096
#define NB_CAP 2048
#define PCHUNK 4096
#define NBE_CAP 320   // >= ceil(M/64)  = 313
#define NBN_CAP 800   // >= ceil(N/128) = 782

__device__ __forceinline__ unsigned wave_incl_scan(unsigned x) {
#pragma unroll
  for (int s = 1; s < 64; s <<= 1) {
    unsigned t = __shfl_up(x, s, 64);
    if ((int)(threadIdx.x & 63) >= s) x += t;
  }
  return x;
}

// pass A: per-block LDS bucket histogram -> one global atomicAdd per
// (block,bucket). No per-id atomics.
__global__ __launch_bounds__(256) void bucket_count(const int* __restrict__ node_idx,
                                                    const int* __restrict__ edge_idx,
                                                    unsigned* __restrict__ bcnt_e,
                                                    unsigned* __restrict__ bcnt_n, int nnz) {
  __shared__ unsigned he[NBE_CAP];
  __shared__ unsigned hn[NBN_CAP];
  const int t = threadIdx.x;
  const int base = blockIdx.x * PCHUNK;
  const int cnt = min(PCHUNK, nnz - base);
  for (int b = t; b < NBE_CAP; b += 256) he[b] = 0;
  for (int b = t; b < NBN_CAP; b += 256) hn[b] = 0;
  __syncthreads();
  for (int idx = t; idx < cnt; idx += 256) {
    unsigned e = (unsigned)edge_idx[base + idx];
    unsigned n = (unsigned)node_idx[base + idx];
    atomicAdd(&he[e >> E_SHIFT], 1u);
    atomicAdd(&hn[n >> N_SHIFT], 1u);
  }
  __syncthreads();
  for (int b = t; b < NBE_CAP; b += 256) if (he[b]) atomicAdd(&bcnt_e[b], he[b]);
  for (int b = t; b < NBN_CAP; b += 256) if (hn[b]) atomicAdd(&bcnt_n[b], hn[b]);
}

// single block: exclusive-scan bucket totals -> bucket bases + cursors;
// also writes eoff[M]=noff[N]=NNZ.
__global__ __launch_bounds__(1024) void bucket_scan(const unsigned* __restrict__ bcnt_e,
                                                    const unsigned* __restrict__ bcnt_n,
                                                    unsigned* __restrict__ bbase_e,
                                                    unsigned* __restrict__ bcur_e,
                                                    unsigned* __restrict__ bbase_n,
                                                    unsigned* __restrict__ bcur_n,
                                                    unsigned* __restrict__ eoff,
                                                    unsigned* __restrict__ noff,
                                                    int nbe, int nbn, int M_, int N_, int nnz) {
  __shared__ unsigned wsum[16];
  const int i = threadIdx.x;
  const int lane = i & 63, wid = i >> 6;
  {
    unsigned v = (i < nbe) ? bcnt_e[i] : 0u;
    unsigned incl = wave_incl_scan(v);
    if (lane == 63) wsum[wid] = incl;
    __syncthreads();
    unsigned add = 0;
    for (int w = 0; w < wid; ++w) add += wsum[w];
    unsigned excl = add + incl - v;
    if (i <= nbe) bbase_e[i] = excl;
    if (i < nbe) bcur_e[i] = excl;
    __syncthreads();
  }
  {
    unsigned v = (i < nbn) ? bcnt_n[i] : 0u;
    unsigned incl = wave_incl_scan(v);
    if (lane == 63) wsum[wid] = incl;
    __syncthreads();
    unsigned add = 0;
    for (int w = 0; w < wid; ++w) add += wsum[w];
    unsigned excl = add + incl - v;
    if (i <= nbn) bbase_n[i] = excl;
    if (i < nbn) bcur_n[i] = excl;
  }
  if (i == 0) { eoff[M_] = (unsigned)nnz; noff[N_] = (unsigned)nnz; }
}

// pass B: block-local multi-split. LDS histogram -> one global atomic per
// (block,bucket) to reserve ranges -> LDS-cursor scatter of u32 payloads.
__global__ __launch_bounds__(256) void partition2(const int* __restrict__ node_idx,
                                                  const int* __restrict__ edge_idx,
                                                  unsigned* __restrict__ bcur_e,
                                                  unsigned* __restrict__ bcur_n,
                                                  unsigned* __restrict__ tmp_e,
                                                  unsigned* __restrict__ tmp_n, int nnz) {
  __shared__ unsigned he[NBE_CAP];
  __shared__ unsigned hn[NBN_CAP];
  const int t = threadIdx.x;
  const int base = blockIdx.x * PCHUNK;
  const int cnt = min(PCHUNK, nnz - base);

  for (int b = t; b < NBE_CAP; b += 256) he[b] = 0;
  for (int b = t; b < NBN_CAP; b += 256) hn[b] = 0;
  __syncthreads();

  for (int idx = t; idx < cnt; idx += 256) {
    unsigned e = (unsigned)edge_idx[base + idx];
    unsigned n = (unsigned)node_idx[base + idx];
    atomicAdd(&he[e >> E_SHIFT], 1u);
    atomicAdd(&hn[n >> N_SHIFT], 1u);
  }
  __syncthreads();

  for (int b = t; b < NBE_CAP; b += 256) {
    unsigned c = he[b];
    he[b] = c ? atomicAdd(&bcur_e[b], c) : 0u;   // bucket range base -> cursor
  }
  for (int b = t; b < NBN_CAP; b += 256) {
    unsigned c = hn[b];
    hn[b] = c ? atomicAdd(&bcur_n[b], c) : 0u;
  }
  __syncthreads();

  for (int idx = t; idx < cnt; idx += 256) {
    unsigned e = (unsigned)edge_idx[base + idx];
    unsigned n = (unsigned)node_idx[base + idx];
    unsigned pe = atomicAdd(&he[e >> E_SHIFT], 1u);
    tmp_e[pe] = ((e & 63u) << 17) | n;
    unsigned pn = atomicAdd(&hn[n >> N_SHIFT], 1u);
    tmp_n[pn] = ((n & 127u) << 15) | e;
  }
}

__device__ __forceinline__ float4 alpha4(const float* __restrict__ ai,
                                         const float* __restrict__ aj,
                                         unsigned n, unsigned e) {
  float4 av = *(const float4*)&ai[(size_t)n * 4];
  float4 bv = *(const float4*)&aj[(size_t)e * 4];
  float v0 = av.x + bv.x, v1 = av.y + bv.y, v2 = av.z + bv.z, v3 = av.w + bv.w;
  v0 = v0 > 0.f ? v0 : 0.2f * v0;
  v1 = v1 > 0.f ? v1 : 0.2f * v1;
  v2 = v2 > 0.f ? v2 : 0.2f * v2;
  v3 = v3 > 0.f ? v3 : 0.2f * v3;
  return make_float4(expf(v0), expf(v1), expf(v2), expf(v3));
}

// pass C (edges): per-bucket LDS counting sort. Computes per-edge counts
// locally (LDS hist + wave scan), emits eoff/binv, then coalesced
// edge-ordered node ids + exp(leakyrelu(ai+aj)) stream.
__global__ __launch_bounds__(256) void sort_edge_exp(const unsigned* __restrict__ tmp,
                                                     const unsigned* __restrict__ bbase,
                                                     int M_,
                                                     const float* __restrict__ ai,
                                                     const float* __restrict__ aj,
                                                     float* __restrict__ ealpha_e,
                                                     int* __restrict__ enid,
                                                     unsigned* __restrict__ eoff,
                                                     float* __restrict__ binv) {
  __shared__ unsigned cur[64];
  __shared__ unsigned sbuf[EB_CAP];
  int b = blockIdx.x, t = threadIdx.x;
  int e0 = b << E_SHIFT;
  unsigned base = bbase[b];
  int cnt = (int)(bbase[b + 1] - base);
  if (t < 64) cur[t] = 0;
  __syncthreads();
  for (int idx = t; idx < cnt; idx += 256) {
    unsigned key = tmp[base + idx] >> 17;
    atomicAdd(&cur[key], 1u);
  }
  __syncthreads();
  {  // local exclusive scan of 64 counts (wave 0 relevant)
    unsigned c = (t < 64) ? cur[t] : 0u;
    unsigned incl = wave_incl_scan(c);
    unsigned excl = incl - c;
    if (t < 64) {
      int e = e0 + t;
      if (e < M_) {
        eoff[e] = base + excl;
        binv[e] = c ? 1.f / (float)c : 0.f;
      }
      cur[t] = excl;  // becomes the placement cursor
    }
  }
  __syncthreads();
  for (int idx = t; idx < cnt; idx += 256) {
    unsigned p = tmp[base + idx];
    unsigned key = p >> 17;
    unsigned pos = atomicAdd(&cur[key], 1u);
    if (pos < EB_CAP) {
      sbuf[pos] = p;
    } else {  // overflow fallback (statistically never): pos is final slot
      unsigned n = p & 0x1FFFFu;
      *(float4*)&ealpha_e[(size_t)(base + pos) * 4] = alpha4(ai, aj, n, e0 + key);
      enid[base + pos] = (int)n;
    }
  }
  __syncthreads();
  int lim = min(cnt, EB_CAP);
  for (int idx = t; idx < lim; idx += 256) {
    unsigned p = sbuf[idx];
    unsigned key = p >> 17, n = p & 0x1FFFFu;
    *(float4*)&ealpha_e[(size_t)(base + idx) * 4] = alpha4(ai, aj, n, e0 + key);
    enid[base + idx] = (int)n;
  }
}

// pass C (nodes): per-bucket sort; emits noff/dinv + node-ordered edge ids
// and alpha stream.
__global__ __launch_bounds__(256) void sort_node_exp(const unsigned* __restrict__ tmp,
                                                     const unsigned* __restrict__ bbase,
                                                     int N_,
                                                     const float* __restrict__ ai,
                                                     const float* __restrict__ aj,
                                                     float* __restrict__ ealpha_n,
                                                     int* __restrict__ neid,
                                                     unsigned* __restrict__ noff,
                                                     float* __restrict__ dinv) {
  __shared__ unsigned cur[128];
  __shared__ unsigned sbuf[NB_CAP];
  __shared__ unsigned wtot;
  int b = blockIdx.x, t = threadIdx.x;
  int n0 = b << N_SHIFT;
  unsigned base = bbase[b];
  int cnt = (int)(bbase[b + 1] - base);
  if (t < 128) cur[t] = 0;
  __syncthreads();
  for (int idx = t; idx < cnt; idx += 256) {
    unsigned key = tmp[base + idx] >> 15;
    atomicAdd(&cur[key], 1u);
  }
  __syncthreads();
  {  // exclusive scan of 128 counts across waves 0..1
    unsigned c = (t < 128) ? cur[t] : 0u;
    unsigned incl = wave_incl_scan(c);
    if (t == 63) wtot = incl;
    __syncthreads();
    unsigned excl = incl - c + ((t >= 64 && t < 128) ? wtot : 0u);
    if (t < 128) {
      int n = n0 + t;
      if (n < N_) {
        noff[n] = base + excl;
        dinv[n] = c ? 1.f / (float)c : 0.f;
      }
      cur[t] = excl;
    }
  }
  __syncthreads();
  for (int idx = t; idx < cnt; idx += 256) {
    unsigned p = tmp[base + idx];
    unsigned key = p >> 15;
    unsigned pos = atomicAdd(&cur[key], 1u);
    if (pos < NB_CAP) {
      sbuf[pos] = p;
    } else {
      unsigned e = p & 0x7FFFu;
      *(float4*)&ealpha_n[(size_t)(base + pos) * 4] = alpha4(ai, aj, n0 + key, e);
      neid[base + pos] = (int)e;
    }
  }
  __syncthreads();
  int lim = min(cnt, NB_CAP);
  for (int idx = t; idx < lim; idx += 256) {
    unsigned p = sbuf[idx];
    unsigned key = p >> 15, e = p & 0x7FFFu;
    *(float4*)&ealpha_n[(size_t)(base + idx) * 4] = alpha4(ai, aj, n0 + key, e);
    neid[base + idx] = (int)e;
  }
}

// rden[v,h] = 1/(sum_{j in node range} ealpha_n[j,h] + 1e-16), sequential read
__global__ __launch_bounds__(256) void node_denom2(const unsigned* __restrict__ noff,
                                                   const float* __restrict__ ealpha_n,
                                                   float* __restrict__ rden, int N) {
  int v = blockIdx.x * 256 + threadIdx.x;
  if (v >= N) return;
  unsigned s = noff[v], en = noff[v + 1];
  float x = 0.f, y = 0.f, z = 0.f, w = 0.f;
  for (unsigned j = s; j < en; ++j) {
    float4 a = *(const float4*)&ealpha_n[(size_t)j * 4];
    x += a.x; y += a.y; z += a.z; w += a.w;
  }
  *(float4*)&rden[(size_t)v * 4] = make_float4(1.f / (x + 1e-16f), 1.f / (y + 1e-16f),
                                               1.f / (z + 1e-16f), 1.f / (w + 1e-16f));
}

// WT[k*128+o] = W[o*128+k]   (one-time 64KB transpose)
__global__ __launch_bounds__(256) void wtrans(const float* __restrict__ W,
                                              float* __restrict__ WT) {
  int idx = blockIdx.x * 256 + threadIdx.x;
  if (idx >= 128 * 128) return;
  int k = idx >> 7, o = idx & 127;
  WT[idx] = W[o * 128 + k];
}

// C[r,o] = sum_k A[r,k] * WT[k,o]; A rows x 128, WT 128x128 (pre-transposed).
// Optional fused head-dot epilogue: aiout[r,h] = sum_f C[r,h*32+f]*att[h*64+f].
#define GM 64
__global__ __launch_bounds__(256) void gemm128t(const float* __restrict__ A,
                                                const float* __restrict__ WT,
                                                float* __restrict__ C, int rows,
                                                const float* __restrict__ att,
                                                float* __restrict__ aiout) {
  __shared__ __align__(16) float Ast[128 * 68];  // Ast[k][r], r-pad to 68
  const int tid = threadIdx.x;
  const int row0 = blockIdx.x * GM;

  for (int idx = tid; idx < GM * 128; idx += 256) {
    int r = idx >> 7, k = idx & 127;
    int gr = row0 + r;
    Ast[k * 68 + r] = (gr < rows) ? A[(size_t)gr * 128 + k] : 0.f;
  }
  __syncthreads();

  const int tr = tid >> 5, tc = tid & 31;
  const int r0 = tr * 8, c0 = tc * 4;
  float acc[8][4] = {{0.f}};

  float4 bnext = *(const float4*)&WT[c0];
#pragma unroll 8
  for (int k = 0; k < 128; ++k) {
    float4 b = bnext;
    if (k < 127) bnext = *(const float4*)&WT[(k + 1) * 128 + c0];
    float4 a0 = *(const float4*)&Ast[k * 68 + r0];
    float4 a1 = *(const float4*)&Ast[k * 68 + r0 + 4];
    acc[0][0] += a0.x * b.x; acc[0][1] += a0.x * b.y; acc[0][2] += a0.x * b.z; acc[0][3] += a0.x * b.w;
    acc[1][0] += a0.y * b.x; acc[1][1] += a0.y * b.y; acc[1][2] += a0.y * b.z; acc[1][3] += a0.y * b.w;
    acc[2][0] += a0.z * b.x; acc[2][1] += a0.z * b.y; acc[2][2] += a0.z * b.z; acc[2][3] += a0.z * b.w;
    acc[3][0] += a0.w * b.x; acc[3][1] += a0.w * b.y; acc[3][2] += a0.w * b.z; acc[3][3] += a0.w * b.w;
    acc[4][0] += a1.x * b.x; acc[4][1] += a1.x * b.y; acc[4][2] += a1.x * b.z; acc[4][3] += a1.x * b.w;
    acc[5][0] += a1.y * b.x; acc[5][1] += a1.y * b.y; acc[5][2] += a1.y * b.z; acc[5][3] += a1.y * b.w;
    acc[6][0] += a1.z * b.x; acc[6][1] += a1.z * b.y; acc[6][2] += a1.z * b.z; acc[6][3] += a1.z * b.w;
    acc[7][0] += a1.w * b.x; acc[7][1] += a1.w * b.y; acc[7][2] += a1.w * b.z; acc[7][3] += a1.w * b.w;
  }

#pragma unroll
  for (int i = 0; i < 8; ++i) {
    int gr = row0 + r0 + i;
    if (gr < rows)
      *(float4*)&C[(size_t)gr * 128 + c0] = make_float4(acc[i][0], acc[i][1], acc[i][2], acc[i][3]);
  }

  if (att) {  // fused ai head-dot: cols c0..c0+3 all in head h = tc>>3
    int h = tc >> 3;
    float4 w = *(const float4*)&att[h * 64 + (c0 & 31)];
#pragma unroll
    for (int i = 0; i < 8; ++i) {
      float p = acc[i][0] * w.x + acc[i][1] * w.y + acc[i][2] * w.z + acc[i][3] * w.w;
      p += __shfl_xor(p, 1);
      p += __shfl_xor(p, 2);
      p += __shfl_xor(p, 4);
      if ((tc & 7) == 0) {
        int gr = row0 + r0 + i;
        if (gr < rows) aiout[(size_t)gr * 4 + h] = p;
      }
    }
  }
}

// u[h,k] = sum_f att1[h*64+32+f] * W_he[(h*32+f)*128 + k]
__global__ __launch_bounds__(256) void make_u(const float* __restrict__ W_he,
                                              const float* __restrict__ att1,
                                              float* __restrict__ u) {
  int idx = blockIdx.x * 256 + threadIdx.x;
  if (idx >= 512) return;
  int h = idx >> 7, k = idx & 127;
  float s = 0.f;
#pragma unroll
  for (int f = 0; f < 32; ++f)
    s += att1[h * 64 + 32 + f] * W_he[(size_t)(h * 32 + f) * 128 + k];
  u[h * 128 + k] = s;
}

// aj[e,h] = hea[e,:] . u[h,:]
__global__ __launch_bounds__(256) void att_dot_full(const float* __restrict__ feat,
                                                    const float* __restrict__ u,
                                                    float* __restrict__ outv, int rows) {
  int idx = blockIdx.x * 256 + threadIdx.x;
  if (idx >= rows * 4) return;
  int v = idx >> 2, h = idx & 3;
  const float4* fp = (const float4*)(feat + (size_t)v * 128);
  const float4* up = (const float4*)(u + h * 128);
  float s = 0.f;
#pragma unroll
  for (int q = 0; q < 32; ++q) {
    float4 a = up[q], f = fp[q];
    s += a.x * f.x + a.y * f.y + a.z * f.z + a.w * f.w;
  }
  outv[idx] = s;
}

#define ECH 256
// out_e[e,t] = Binv[e] * sum_i alpha_norm[i,h] * x1[node_i, t]
__global__ __launch_bounds__(128) void edge_aggregate1(const float* __restrict__ x1,
                                                       const float* __restrict__ ealpha_e,
                                                       const float* __restrict__ rden,
                                                       const float* __restrict__ binv,
                                                       const int* __restrict__ enid,
                                                       const unsigned* __restrict__ eoff,
                                                       float* __restrict__ out_e) {
  __shared__ int nid[ECH];
  __shared__ float wal[ECH][4];
  int e = blockIdx.x, t = threadIdx.x, h = t >> 5;
  unsigned s = eoff[e], en = eoff[e + 1];
  float a0 = 0.f, a1 = 0.f, a2 = 0.f, a3 = 0.f;
  float a4 = 0.f, a5 = 0.f, a6 = 0.f, a7 = 0.f;
  for (unsigned base = s; base < en; base += ECH) {
    int cnt = (int)min((unsigned)ECH, en - base);
    __syncthreads();
    for (int c = t; c < cnt; c += 128) {
      int n = enid[base + c];
      nid[c] = n;
      float4 ea = *(const float4*)&ealpha_e[(size_t)(base + c) * 4];
      float4 rd = *(const float4*)&rden[(size_t)n * 4];
      wal[c][0] = ea.x * rd.x; wal[c][1] = ea.y * rd.y;
      wal[c][2] = ea.z * rd.z; wal[c][3] = ea.w * rd.w;
    }
    __syncthreads();
    int c = 0;
    for (; c + 8 <= cnt; c += 8) {
      a0 += wal[c + 0][h] * x1[(size_t)nid[c + 0] * 128 + t];
      a1 += wal[c + 1][h] * x1[(size_t)nid[c + 1] * 128 + t];
      a2 += wal[c + 2][h] * x1[(size_t)nid[c + 2] * 128 + t];
      a3 += wal[c + 3][h] * x1[(size_t)nid[c + 3] * 128 + t];
      a4 += wal[c + 4][h] * x1[(size_t)nid[c + 4] * 128 + t];
      a5 += wal[c + 5][h] * x1[(size_t)nid[c + 5] * 128 + t];
      a6 += wal[c + 6][h] * x1[(size_t)nid[c + 6] * 128 + t];
      a7 += wal[c + 7][h] * x1[(size_t)nid[c + 7] * 128 + t];
    }
    for (; c < cnt; ++c) a0 += wal[c][h] * x1[(size_t)nid[c] * 128 + t];
  }
  out_e[(size_t)e * 128 + t] = binv[e] * (((a0 + a1) + (a2 + a3)) + ((a4 + a5) + (a6 + a7)));
}

// h[v,t] = elu(Dinv[v]*rden[v,h] * sum_j ealpha_n[j,h]*out_e[neid[j],t] + bias1[t])
__global__ __launch_bounds__(128) void node_aggregate1(const float* __restrict__ out_e,
                                                       const float* __restrict__ ealpha_n,
                                                       const float* __restrict__ rden,
                                                       const float* __restrict__ dinv,
                                                       const float* __restrict__ bias1,
                                                       const int* __restrict__ neid,
                                                       const unsigned* __restrict__ noff,
                                                       float* __restrict__ hout) {
  int v = blockIdx.x, t = threadIdx.x, h = t >> 5;
  unsigned s = noff[v], en = noff[v + 1];
  float rd = dinv[v] * rden[v * 4 + h];
  float a0 = 0.f, a1 = 0.f, a2 = 0.f, a3 = 0.f;
  unsigned j = s;
  for (; j + 4 <= en; j += 4) {
    int e0 = neid[j], e1 = neid[j + 1], e2 = neid[j + 2], e3 = neid[j + 3];
    a0 += ealpha_n[(size_t)j * 4 + h] * out_e[(size_t)e0 * 128 + t];
    a1 += ealpha_n[(size_t)(j + 1) * 4 + h] * out_e[(size_t)e1 * 128 + t];
    a2 += ealpha_n[(size_t)(j + 2) * 4 + h] * out_e[(size_t)e2 * 128 + t];
    a3 += ealpha_n[(size_t)(j + 3) * 4 + h] * out_e[(size_t)e3 * 128 + t];
  }
  for (; j < en; ++j)
    a0 += ealpha_n[(size_t)j * 4 + h] * out_e[(size_t)neid[j] * 128 + t];
  float val = rd * (a0 + a1 + a2 + a3) + bias1[t];
  hout[(size_t)v * 128 + t] = val > 0.f ? val : expm1f(val);
}

// oe_pre[e,t] = Binv[e] * sum_i h[node_i, t]
__global__ __launch_bounds__(128) void edge_aggregate2(const float* __restrict__ hfeat,
                                                       const float* __restrict__ binv,
                                                       const int* __restrict__ enid,
                                                       const unsigned* __restrict__ eoff,
                                                       float* __restrict__ oe) {
  __shared__ int nid[ECH];
  int e = blockIdx.x, t = threadIdx.x;
  unsigned s = eoff[e], en = eoff[e + 1];
  float a0 = 0.f, a1 = 0.f, a2 = 0.f, a3 = 0.f;
  float a4 = 0.f, a5 = 0.f, a6 = 0.f, a7 = 0.f;
  for (unsigned base = s; base < en; base += ECH) {
    int cnt = (int)min((unsigned)ECH, en - base);
    __syncthreads();
    for (int c = t; c < cnt; c += 128) nid[c] = enid[base + c];
    __syncthreads();
    int c = 0;
    for (; c + 8 <= cnt; c += 8) {
      a0 += hfeat[(size_t)nid[c + 0] * 128 + t];
      a1 += hfeat[(size_t)nid[c + 1] * 128 + t];
      a2 += hfeat[(size_t)nid[c + 2] * 128 + t];
      a3 += hfeat[(size_t)nid[c + 3] * 128 + t];
      a4 += hfeat[(size_t)nid[c + 4] * 128 + t];
      a5 += hfeat[(size_t)nid[c + 5] * 128 + t];
      a6 += hfeat[(size_t)nid[c + 6] * 128 + t];
      a7 += hfeat[(size_t)nid[c + 7] * 128 + t];
    }
    for (; c < cnt; ++c) a0 += hfeat[(size_t)nid[c] * 128 + t];
  }
  oe[(size_t)e * 128 + t] = binv[e] * (((a0 + a1) + (a2 + a3)) + ((a4 + a5) + (a6 + a7)));
}

// out[v,t] = Dinv[v] * sum_j oe2[neid[j], t] + bias2[t]
__global__ __launch_bounds__(128) void node_aggregate2(const float* __restrict__ oe2,
                                                       const float* __restrict__ dinv,
                                                       const float* __restrict__ bias2,
                                                       const int* __restrict__ neid,
                                                       const unsigned* __restrict__ noff,
                                                       float* __restrict__ out) {
  int v = blockIdx.x, t = threadIdx.x;
  unsigned s = noff[v], en = noff[v + 1];
  float a0 = 0.f, a1 = 0.f, a2 = 0.f, a3 = 0.f;
  unsigned j = s;
  for (; j + 4 <= en; j += 4) {
    int e0 = neid[j], e1 = neid[j + 1], e2 = neid[j + 2], e3 = neid[j + 3];
    a0 += oe2[(size_t)e0 * 128 + t];
    a1 += oe2[(size_t)e1 * 128 + t];
    a2 += oe2[(size_t)e2 * 128 + t];
    a3 += oe2[(size_t)e3 * 128 + t];
  }
  for (; j < en; ++j) a0 += oe2[(size_t)neid[j] * 128 + t];
  out[(size_t)v * 128 + t] = dinv[v] * (a0 + a1 + a2 + a3) + bias2[t];
}

extern "C" void kernel_launch(void* const* d_in, const int* in_sizes, int n_in,
                              void* d_out, int out_size, void* d_ws, size_t ws_size,
                              hipStream_t stream) {
  (void)n_in; (void)out_size; (void)ws_size;
  const float* x      = (const float*)d_in[0];
  const float* hea    = (const float*)d_in[1];
  const float* lin1W  = (const float*)d_in[2];
  const float* helinW = (const float*)d_in[3];
  const float* att1   = (const float*)d_in[4];
  const float* bias1  = (const float*)d_in[5];
  const float* lin2W  = (const float*)d_in[6];
  const float* bias2  = (const float*)d_in[7];
  const int* node_idx = (const int*)d_in[8];
  const int* edge_idx = (const int*)d_in[9];
  float* out = (float*)d_out;

  const int N   = in_sizes[0] / 128;
  const int M   = in_sizes[1] / 128;
  const int NNZ = in_sizes[8];
  const int NBE = (M + 63) >> E_SHIFT;
  const int NBN = (N + 127) >> N_SHIFT;

  char* base = (char*)d_ws;
  size_t off = 0;
  auto alloc = [&](size_t bytes) -> char* {
    char* p = base + off;
    off = (off + bytes + 255) & ~(size_t)255;
    return p;
  };
  float* x1    = (float*)alloc((size_t)N * 128 * 4);  // x1; later oe2 (M rows)
  float* hbuf  = (float*)alloc((size_t)N * 128 * 4);  // h
  float* heoe  = (float*)alloc((size_t)M * 128 * 4);  // out_e -> oe_pre
  float* ai    = (float*)alloc((size_t)N * 4 * 4);
  float* aj    = (float*)alloc((size_t)M * 4 * 4);
  float* u     = (float*)alloc(512 * 4);
  float* WT1   = (float*)alloc(128 * 128 * 4);
  float* WT2   = (float*)alloc(128 * 128 * 4);
  float* dinv  = (float*)alloc((size_t)N * 4);
  float* binv  = (float*)alloc((size_t)M * 4);
  float* rden  = (float*)alloc((size_t)N * 4 * 4);
  char* zstart = base + off;                           // ---- zeroed region ----
  unsigned* bcnt_e = (unsigned*)alloc((size_t)NBE * 4);
  unsigned* bcnt_n = (unsigned*)alloc((size_t)NBN * 4);
  size_t zbytes = (size_t)((base + off) - zstart);     // ---- end zero region ----
  float* ealpha_e = (float*)alloc((size_t)NNZ * 4 * 4);
  float* ealpha_n = (float*)alloc((size_t)NNZ * 4 * 4);
  unsigned* tmp_e = (unsigned*)alloc((size_t)NNZ * 4);
  unsigned* tmp_n = (unsigned*)alloc((size_t)NNZ * 4);
  unsigned* noff  = (unsigned*)alloc((size_t)(N + 1) * 4);
  unsigned* eoff  = (unsigned*)alloc((size_t)(M + 1) * 4);
  unsigned* bbase_e = (unsigned*)alloc((size_t)(NBE + 1) * 4);
  unsigned* bbase_n = (unsigned*)alloc((size_t)(NBN + 1) * 4);
  unsigned* bcur_e = (unsigned*)alloc((size_t)NBE * 4);
  unsigned* bcur_n = (unsigned*)alloc((size_t)NBN * 4);
  int* enid       = (int*)alloc((size_t)NNZ * 4);
  int* neid       = (int*)alloc((size_t)NNZ * 4);

  hipMemsetAsync(zstart, 0, zbytes, stream);

  const int g_pchunk = (NNZ + PCHUNK - 1) / PCHUNK;
  bucket_count<<<g_pchunk, 256, 0, stream>>>(node_idx, edge_idx, bcnt_e, bcnt_n, NNZ);
  bucket_scan<<<1, 1024, 0, stream>>>(bcnt_e, bcnt_n, bbase_e, bcur_e, bbase_n, bcur_n,
                                      eoff, noff, NBE, NBN, M, N, NNZ);
  partition2<<<g_pchunk, 256, 0, stream>>>(node_idx, edge_idx, bcur_e, bcur_n,
                                           tmp_e, tmp_n, NNZ);

  wtrans<<<64, 256, 0, stream>>>(lin1W, WT1);
  wtrans<<<64, 256, 0, stream>>>(lin2W, WT2);
  gemm128t<<<(N + GM - 1) / GM, 256, 0, stream>>>(x, WT1, x1, N, att1, ai);
  make_u<<<2, 256, 0, stream>>>(helinW, att1, u);
  att_dot_full<<<(M * 4 + 255) / 256, 256, 0, stream>>>(hea, u, aj, M);

  sort_edge_exp<<<NBE, 256, 0, stream>>>(tmp_e, bbase_e, M, ai, aj, ealpha_e, enid,
                                         eoff, binv);
  sort_node_exp<<<NBN, 256, 0, stream>>>(tmp_n, bbase_n, N, ai, aj, ealpha_n, neid,
                                         noff, dinv);
  node_denom2<<<(N + 255) / 256, 256, 0, stream>>>(noff, ealpha_n, rden, N);

  edge_aggregate1<<<M, 128, 0, stream>>>(x1, ealpha_e, rden, binv, enid, eoff, heoe);
  node_aggregate1<<<N, 128, 0, stream>>>(heoe, ealpha_n, rden, dinv, bias1, neid, noff, hbuf);

  edge_aggregate2<<<M, 128, 0, stream>>>(hbuf, binv, enid, eoff, heoe);
  gemm128t<<<(M + GM - 1) / GM, 256, 0, stream>>>(heoe, WT2, x1, M, nullptr, nullptr);
  node_aggregate2<<<N, 128, 0, stream>>>(x1, dinv, bias2, neid, noff, out);
}

// Round 8
// 488.715 us; speedup vs baseline: 2.1148x; 1.0678x over previous
//
#include <hip/hip_runtime.h>
#include <cstdint>

// ---------------------------------------------------------------------------
// HCHA (hypergraph conv with attention), f32.
// N=100000 nodes, M=20000 hyperedges, NNZ=1e6, C=128, HEADS=4, FH=32.
// CSR build: bucket_count -> 1-block bucket_scan -> block-local multi-split
// partition -> per-bucket LDS counting sort (emits eoff/noff/binv/dinv and
// exp(leakyrelu(ai+aj)) in edge-/node-order).
// GEMM: A-tile row-major in LDS (coalesced conflict-free staging, broadcast
// b128 reads, k unrolled x4), W^T pre-transposed in global (L2-resident),
// ai head-dot fused into the layer-1 GEMM epilogue.
// Packing: e < 2^15 (M=20000), n < 2^17 (N=1e5).
// ---------------------------------------------------------------------------

#define E_SHIFT 6
#define N_SHIFT 7
#define EB_CAP 4096
#define NB_CAP 2048
#define PCHUNK 4096
#define NBE_CAP 320   // >= ceil(M/64)  = 313
#define NBN_CAP 800   // >= ceil(N/128) = 782

__device__ __forceinline__ unsigned wave_incl_scan(unsigned x) {
#pragma unroll
  for (int s = 1; s < 64; s <<= 1) {
    unsigned t = __shfl_up(x, s, 64);
    if ((int)(threadIdx.x & 63) >= s) x += t;
  }
  return x;
}

// pass A: per-block LDS bucket histogram -> one global atomicAdd per
// (block,bucket). No per-id atomics.
__global__ __launch_bounds__(256) void bucket_count(const int* __restrict__ node_idx,
                                                    const int* __restrict__ edge_idx,
                                                    unsigned* __restrict__ bcnt_e,
                                                    unsigned* __restrict__ bcnt_n, int nnz) {
  __shared__ unsigned he[NBE_CAP];
  __shared__ unsigned hn[NBN_CAP];
  const int t = threadIdx.x;
  const int base = blockIdx.x * PCHUNK;
  const int cnt = min(PCHUNK, nnz - base);
  for (int b = t; b < NBE_CAP; b += 256) he[b] = 0;
  for (int b = t; b < NBN_CAP; b += 256) hn[b] = 0;
  __syncthreads();
  for (int idx = t; idx < cnt; idx += 256) {
    unsigned e = (unsigned)edge_idx[base + idx];
    unsigned n = (unsigned)node_idx[base + idx];
    atomicAdd(&he[e >> E_SHIFT], 1u);
    atomicAdd(&hn[n >> N_SHIFT], 1u);
  }
  __syncthreads();
  for (int b = t; b < NBE_CAP; b += 256) if (he[b]) atomicAdd(&bcnt_e[b], he[b]);
  for (int b = t; b < NBN_CAP; b += 256) if (hn[b]) atomicAdd(&bcnt_n[b], hn[b]);
}

// single block: exclusive-scan bucket totals -> bucket bases + cursors;
// also writes eoff[M]=noff[N]=NNZ.
__global__ __launch_bounds__(1024) void bucket_scan(const unsigned* __restrict__ bcnt_e,
                                                    const unsigned* __restrict__ bcnt_n,
                                                    unsigned* __restrict__ bbase_e,
                                                    unsigned* __restrict__ bcur_e,
                                                    unsigned* __restrict__ bbase_n,
                                                    unsigned* __restrict__ bcur_n,
                                                    unsigned* __restrict__ eoff,
                                                    unsigned* __restrict__ noff,
                                                    int nbe, int nbn, int M_, int N_, int nnz) {
  __shared__ unsigned wsum[16];
  const int i = threadIdx.x;
  const int lane = i & 63, wid = i >> 6;
  {
    unsigned v = (i < nbe) ? bcnt_e[i] : 0u;
    unsigned incl = wave_incl_scan(v);
    if (lane == 63) wsum[wid] = incl;
    __syncthreads();
    unsigned add = 0;
    for (int w = 0; w < wid; ++w) add += wsum[w];
    unsigned excl = add + incl - v;
    if (i <= nbe) bbase_e[i] = excl;
    if (i < nbe) bcur_e[i] = excl;
    __syncthreads();
  }
  {
    unsigned v = (i < nbn) ? bcnt_n[i] : 0u;
    unsigned incl = wave_incl_scan(v);
    if (lane == 63) wsum[wid] = incl;
    __syncthreads();
    unsigned add = 0;
    for (int w = 0; w < wid; ++w) add += wsum[w];
    unsigned excl = add + incl - v;
    if (i <= nbn) bbase_n[i] = excl;
    if (i < nbn) bcur_n[i] = excl;
  }
  if (i == 0) { eoff[M_] = (unsigned)nnz; noff[N_] = (unsigned)nnz; }
}

// pass B: block-local multi-split. LDS histogram -> one global atomic per
// (block,bucket) to reserve ranges -> LDS-cursor scatter of u32 payloads.
__global__ __launch_bounds__(256) void partition2(const int* __restrict__ node_idx,
                                                  const int* __restrict__ edge_idx,
                                                  unsigned* __restrict__ bcur_e,
                                                  unsigned* __restrict__ bcur_n,
                                                  unsigned* __restrict__ tmp_e,
                                                  unsigned* __restrict__ tmp_n, int nnz) {
  __shared__ unsigned he[NBE_CAP];
  __shared__ unsigned hn[NBN_CAP];
  const int t = threadIdx.x;
  const int base = blockIdx.x * PCHUNK;
  const int cnt = min(PCHUNK, nnz - base);

  for (int b = t; b < NBE_CAP; b += 256) he[b] = 0;
  for (int b = t; b < NBN_CAP; b += 256) hn[b] = 0;
  __syncthreads();

  for (int idx = t; idx < cnt; idx += 256) {
    unsigned e = (unsigned)edge_idx[base + idx];
    unsigned n = (unsigned)node_idx[base + idx];
    atomicAdd(&he[e >> E_SHIFT], 1u);
    atomicAdd(&hn[n >> N_SHIFT], 1u);
  }
  __syncthreads();

  for (int b = t; b < NBE_CAP; b += 256) {
    unsigned c = he[b];
    he[b] = c ? atomicAdd(&bcur_e[b], c) : 0u;   // bucket range base -> cursor
  }
  for (int b = t; b < NBN_CAP; b += 256) {
    unsigned c = hn[b];
    hn[b] = c ? atomicAdd(&bcur_n[b], c) : 0u;
  }
  __syncthreads();

  for (int idx = t; idx < cnt; idx += 256) {
    unsigned e = (unsigned)edge_idx[base + idx];
    unsigned n = (unsigned)node_idx[base + idx];
    unsigned pe = atomicAdd(&he[e >> E_SHIFT], 1u);
    tmp_e[pe] = ((e & 63u) << 17) | n;
    unsigned pn = atomicAdd(&hn[n >> N_SHIFT], 1u);
    tmp_n[pn] = ((n & 127u) << 15) | e;
  }
}

__device__ __forceinline__ float4 alpha4(const float* __restrict__ ai,
                                         const float* __restrict__ aj,
                                         unsigned n, unsigned e) {
  float4 av = *(const float4*)&ai[(size_t)n * 4];
  float4 bv = *(const float4*)&aj[(size_t)e * 4];
  float v0 = av.x + bv.x, v1 = av.y + bv.y, v2 = av.z + bv.z, v3 = av.w + bv.w;
  v0 = v0 > 0.f ? v0 : 0.2f * v0;
  v1 = v1 > 0.f ? v1 : 0.2f * v1;
  v2 = v2 > 0.f ? v2 : 0.2f * v2;
  v3 = v3 > 0.f ? v3 : 0.2f * v3;
  return make_float4(expf(v0), expf(v1), expf(v2), expf(v3));
}

// pass C (edges): per-bucket LDS counting sort. Computes per-edge counts
// locally (LDS hist + wave scan), emits eoff/binv, then coalesced
// edge-ordered node ids + exp(leakyrelu(ai+aj)) stream.
__global__ __launch_bounds__(256) void sort_edge_exp(const unsigned* __restrict__ tmp,
                                                     const unsigned* __restrict__ bbase,
                                                     int M_,
                                                     const float* __restrict__ ai,
                                                     const float* __restrict__ aj,
                                                     float* __restrict__ ealpha_e,
                                                     int* __restrict__ enid,
                                                     unsigned* __restrict__ eoff,
                                                     float* __restrict__ binv) {
  __shared__ unsigned cur[64];
  __shared__ unsigned sbuf[EB_CAP];
  int b = blockIdx.x, t = threadIdx.x;
  int e0 = b << E_SHIFT;
  unsigned base = bbase[b];
  int cnt = (int)(bbase[b + 1] - base);
  if (t < 64) cur[t] = 0;
  __syncthreads();
  for (int idx = t; idx < cnt; idx += 256) {
    unsigned key = tmp[base + idx] >> 17;
    atomicAdd(&cur[key], 1u);
  }
  __syncthreads();
  {  // local exclusive scan of 64 counts (wave 0 relevant)
    unsigned c = (t < 64) ? cur[t] : 0u;
    unsigned incl = wave_incl_scan(c);
    unsigned excl = incl - c;
    if (t < 64) {
      int e = e0 + t;
      if (e < M_) {
        eoff[e] = base + excl;
        binv[e] = c ? 1.f / (float)c : 0.f;
      }
      cur[t] = excl;  // becomes the placement cursor
    }
  }
  __syncthreads();
  for (int idx = t; idx < cnt; idx += 256) {
    unsigned p = tmp[base + idx];
    unsigned key = p >> 17;
    unsigned pos = atomicAdd(&cur[key], 1u);
    if (pos < EB_CAP) {
      sbuf[pos] = p;
    } else {  // overflow fallback (statistically never): pos is final slot
      unsigned n = p & 0x1FFFFu;
      *(float4*)&ealpha_e[(size_t)(base + pos) * 4] = alpha4(ai, aj, n, e0 + key);
      enid[base + pos] = (int)n;
    }
  }
  __syncthreads();
  int lim = min(cnt, EB_CAP);
  for (int idx = t; idx < lim; idx += 256) {
    unsigned p = sbuf[idx];
    unsigned key = p >> 17, n = p & 0x1FFFFu;
    *(float4*)&ealpha_e[(size_t)(base + idx) * 4] = alpha4(ai, aj, n, e0 + key);
    enid[base + idx] = (int)n;
  }
}

// pass C (nodes): per-bucket sort; emits noff/dinv + node-ordered edge ids
// and alpha stream.
__global__ __launch_bounds__(256) void sort_node_exp(const unsigned* __restrict__ tmp,
                                                     const unsigned* __restrict__ bbase,
                                                     int N_,
                                                     const float* __restrict__ ai,
                                                     const float* __restrict__ aj,
                                                     float* __restrict__ ealpha_n,
                                                     int* __restrict__ neid,
                                                     unsigned* __restrict__ noff,
                                                     float* __restrict__ dinv) {
  __shared__ unsigned cur[128];
  __shared__ unsigned sbuf[NB_CAP];
  __shared__ unsigned wtot;
  int b = blockIdx.x, t = threadIdx.x;
  int n0 = b << N_SHIFT;
  unsigned base = bbase[b];
  int cnt = (int)(bbase[b + 1] - base);
  if (t < 128) cur[t] = 0;
  __syncthreads();
  for (int idx = t; idx < cnt; idx += 256) {
    unsigned key = tmp[base + idx] >> 15;
    atomicAdd(&cur[key], 1u);
  }
  __syncthreads();
  {  // exclusive scan of 128 counts across waves 0..1
    unsigned c = (t < 128) ? cur[t] : 0u;
    unsigned incl = wave_incl_scan(c);
    if (t == 63) wtot = incl;
    __syncthreads();
    unsigned excl = incl - c + ((t >= 64 && t < 128) ? wtot : 0u);
    if (t < 128) {
      int n = n0 + t;
      if (n < N_) {
        noff[n] = base + excl;
        dinv[n] = c ? 1.f / (float)c : 0.f;
      }
      cur[t] = excl;
    }
  }
  __syncthreads();
  for (int idx = t; idx < cnt; idx += 256) {
    unsigned p = tmp[base + idx];
    unsigned key = p >> 15;
    unsigned pos = atomicAdd(&cur[key], 1u);
    if (pos < NB_CAP) {
      sbuf[pos] = p;
    } else {
      unsigned e = p & 0x7FFFu;
      *(float4*)&ealpha_n[(size_t)(base + pos) * 4] = alpha4(ai, aj, n0 + key, e);
      neid[base + pos] = (int)e;
    }
  }
  __syncthreads();
  int lim = min(cnt, NB_CAP);
  for (int idx = t; idx < lim; idx += 256) {
    unsigned p = sbuf[idx];
    unsigned key = p >> 15, e = p & 0x7FFFu;
    *(float4*)&ealpha_n[(size_t)(base + idx) * 4] = alpha4(ai, aj, n0 + key, e);
    neid[base + idx] = (int)e;
  }
}

// rden[v,h] = 1/(sum_{j in node range} ealpha_n[j,h] + 1e-16), sequential read
__global__ __launch_bounds__(256) void node_denom2(const unsigned* __restrict__ noff,
                                                   const float* __restrict__ ealpha_n,
                                                   float* __restrict__ rden, int N) {
  int v = blockIdx.x * 256 + threadIdx.x;
  if (v >= N) return;
  unsigned s = noff[v], en = noff[v + 1];
  float x = 0.f, y = 0.f, z = 0.f, w = 0.f;
  for (unsigned j = s; j < en; ++j) {
    float4 a = *(const float4*)&ealpha_n[(size_t)j * 4];
    x += a.x; y += a.y; z += a.z; w += a.w;
  }
  *(float4*)&rden[(size_t)v * 4] = make_float4(1.f / (x + 1e-16f), 1.f / (y + 1e-16f),
                                               1.f / (z + 1e-16f), 1.f / (w + 1e-16f));
}

// WT[k*128+o] = W[o*128+k]   (one-time 64KB transpose)
__global__ __launch_bounds__(256) void wtrans(const float* __restrict__ W,
                                              float* __restrict__ WT) {
  int idx = blockIdx.x * 256 + threadIdx.x;
  if (idx >= 128 * 128) return;
  int k = idx >> 7, o = idx & 127;
  WT[idx] = W[o * 128 + k];
}

// C[r,o] = sum_k A[r,k] * WT[k,o]; A rows x 128, WT 128x128 (pre-transposed).
// A-tile row-major in LDS: staging coalesced & conflict-free; reads broadcast.
// Optional fused head-dot epilogue: aiout[r,h] = sum_f C[r,h*32+f]*att[h*64+f].
#define GM 64
__global__ __launch_bounds__(256) void gemm128t(const float* __restrict__ A,
                                                const float* __restrict__ WT,
                                                float* __restrict__ C, int rows,
                                                const float* __restrict__ att,
                                                float* __restrict__ aiout) {
  __shared__ __align__(16) float Ast[GM][132];  // row-major, pad 132
  const int tid = threadIdx.x;
  const int row0 = blockIdx.x * GM;

  for (int idx = tid; idx < GM * 32; idx += 256) {  // float4-granular staging
    int r = idx >> 5, kq = idx & 31;
    int gr = row0 + r;
    float4 v = (gr < rows) ? *(const float4*)&A[(size_t)gr * 128 + kq * 4]
                           : make_float4(0.f, 0.f, 0.f, 0.f);
    *(float4*)&Ast[r][kq * 4] = v;
  }
  __syncthreads();

  const int tr = tid >> 5, tc = tid & 31;
  const int r0 = tr * 8, c0 = tc * 4;
  float acc[8][4] = {{0.f}};

  for (int k = 0; k < 128; k += 4) {
    float4 b0 = *(const float4*)&WT[(k + 0) * 128 + c0];
    float4 b1 = *(const float4*)&WT[(k + 1) * 128 + c0];
    float4 b2 = *(const float4*)&WT[(k + 2) * 128 + c0];
    float4 b3 = *(const float4*)&WT[(k + 3) * 128 + c0];
#pragma unroll
    for (int i = 0; i < 8; ++i) {
      float4 a = *(const float4*)&Ast[r0 + i][k];  // broadcast read
      acc[i][0] += a.x * b0.x; acc[i][1] += a.x * b0.y; acc[i][2] += a.x * b0.z; acc[i][3] += a.x * b0.w;
      acc[i][0] += a.y * b1.x; acc[i][1] += a.y * b1.y; acc[i][2] += a.y * b1.z; acc[i][3] += a.y * b1.w;
      acc[i][0] += a.z * b2.x; acc[i][1] += a.z * b2.y; acc[i][2] += a.z * b2.z; acc[i][3] += a.z * b2.w;
      acc[i][0] += a.w * b3.x; acc[i][1] += a.w * b3.y; acc[i][2] += a.w * b3.z; acc[i][3] += a.w * b3.w;
    }
  }

#pragma unroll
  for (int i = 0; i < 8; ++i) {
    int gr = row0 + r0 + i;
    if (gr < rows)
      *(float4*)&C[(size_t)gr * 128 + c0] = make_float4(acc[i][0], acc[i][1], acc[i][2], acc[i][3]);
  }

  if (att) {  // fused ai head-dot: cols c0..c0+3 all in head h = tc>>3
    int h = tc >> 3;
    float4 w = *(const float4*)&att[h * 64 + (c0 & 31)];
#pragma unroll
    for (int i = 0; i < 8; ++i) {
      float p = acc[i][0] * w.x + acc[i][1] * w.y + acc[i][2] * w.z + acc[i][3] * w.w;
      p += __shfl_xor(p, 1);
      p += __shfl_xor(p, 2);
      p += __shfl_xor(p, 4);
      if ((tc & 7) == 0) {
        int gr = row0 + r0 + i;
        if (gr < rows) aiout[(size_t)gr * 4 + h] = p;
      }
    }
  }
}

// u[h,k] = sum_f att1[h*64+32+f] * W_he[(h*32+f)*128 + k]
__global__ __launch_bounds__(256) void make_u(const float* __restrict__ W_he,
                                              const float* __restrict__ att1,
                                              float* __restrict__ u) {
  int idx = blockIdx.x * 256 + threadIdx.x;
  if (idx >= 512) return;
  int h = idx >> 7, k = idx & 127;
  float s = 0.f;
#pragma unroll
  for (int f = 0; f < 32; ++f)
    s += att1[h * 64 + 32 + f] * W_he[(size_t)(h * 32 + f) * 128 + k];
  u[h * 128 + k] = s;
}

// aj[e,h] = hea[e,:] . u[h,:]
__global__ __launch_bounds__(256) void att_dot_full(const float* __restrict__ feat,
                                                    const float* __restrict__ u,
                                                    float* __restrict__ outv, int rows) {
  int idx = blockIdx.x * 256 + threadIdx.x;
  if (idx >= rows * 4) return;
  int v = idx >> 2, h = idx & 3;
  const float4* fp = (const float4*)(feat + (size_t)v * 128);
  const float4* up = (const float4*)(u + h * 128);
  float s = 0.f;
#pragma unroll
  for (int q = 0; q < 32; ++q) {
    float4 a = up[q], f = fp[q];
    s += a.x * f.x + a.y * f.y + a.z * f.z + a.w * f.w;
  }
  outv[idx] = s;
}

#define ECH 256
// out_e[e,t] = Binv[e] * sum_i alpha_norm[i,h] * x1[node_i, t]
__global__ __launch_bounds__(128) void edge_aggregate1(const float* __restrict__ x1,
                                                       const float* __restrict__ ealpha_e,
                                                       const float* __restrict__ rden,
                                                       const float* __restrict__ binv,
                                                       const int* __restrict__ enid,
                                                       const unsigned* __restrict__ eoff,
                                                       float* __restrict__ out_e) {
  __shared__ int nid[ECH];
  __shared__ float wal[ECH][4];
  int e = blockIdx.x, t = threadIdx.x, h = t >> 5;
  unsigned s = eoff[e], en = eoff[e + 1];
  float a0 = 0.f, a1 = 0.f, a2 = 0.f, a3 = 0.f;
  float a4 = 0.f, a5 = 0.f, a6 = 0.f, a7 = 0.f;
  for (unsigned base = s; base < en; base += ECH) {
    int cnt = (int)min((unsigned)ECH, en - base);
    __syncthreads();
    for (int c = t; c < cnt; c += 128) {
      int n = enid[base + c];
      nid[c] = n;
      float4 ea = *(const float4*)&ealpha_e[(size_t)(base + c) * 4];
      float4 rd = *(const float4*)&rden[(size_t)n * 4];
      wal[c][0] = ea.x * rd.x; wal[c][1] = ea.y * rd.y;
      wal[c][2] = ea.z * rd.z; wal[c][3] = ea.w * rd.w;
    }
    __syncthreads();
    int c = 0;
    for (; c + 8 <= cnt; c += 8) {
      a0 += wal[c + 0][h] * x1[(size_t)nid[c + 0] * 128 + t];
      a1 += wal[c + 1][h] * x1[(size_t)nid[c + 1] * 128 + t];
      a2 += wal[c + 2][h] * x1[(size_t)nid[c + 2] * 128 + t];
      a3 += wal[c + 3][h] * x1[(size_t)nid[c + 3] * 128 + t];
      a4 += wal[c + 4][h] * x1[(size_t)nid[c + 4] * 128 + t];
      a5 += wal[c + 5][h] * x1[(size_t)nid[c + 5] * 128 + t];
      a6 += wal[c + 6][h] * x1[(size_t)nid[c + 6] * 128 + t];
      a7 += wal[c + 7][h] * x1[(size_t)nid[c + 7] * 128 + t];
    }
    for (; c < cnt; ++c) a0 += wal[c][h] * x1[(size_t)nid[c] * 128 + t];
  }
  out_e[(size_t)e * 128 + t] = binv[e] * (((a0 + a1) + (a2 + a3)) + ((a4 + a5) + (a6 + a7)));
}

// h[v,t] = elu(Dinv[v]*rden[v,h] * sum_j ealpha_n[j,h]*out_e[neid[j],t] + bias1[t])
__global__ __launch_bounds__(128) void node_aggregate1(const float* __restrict__ out_e,
                                                       const float* __restrict__ ealpha_n,
                                                       const float* __restrict__ rden,
                                                       const float* __restrict__ dinv,
                                                       const float* __restrict__ bias1,
                                                       const int* __restrict__ neid,
                                                       const unsigned* __restrict__ noff,
                                                       float* __restrict__ hout) {
  int v = blockIdx.x, t = threadIdx.x, h = t >> 5;
  unsigned s = noff[v], en = noff[v + 1];
  float rd = dinv[v] * rden[v * 4 + h];
  float a0 = 0.f, a1 = 0.f, a2 = 0.f, a3 = 0.f;
  unsigned j = s;
  for (; j + 4 <= en; j += 4) {
    int e0 = neid[j], e1 = neid[j + 1], e2 = neid[j + 2], e3 = neid[j + 3];
    a0 += ealpha_n[(size_t)j * 4 + h] * out_e[(size_t)e0 * 128 + t];
    a1 += ealpha_n[(size_t)(j + 1) * 4 + h] * out_e[(size_t)e1 * 128 + t];
    a2 += ealpha_n[(size_t)(j + 2) * 4 + h] * out_e[(size_t)e2 * 128 + t];
    a3 += ealpha_n[(size_t)(j + 3) * 4 + h] * out_e[(size_t)e3 * 128 + t];
  }
  for (; j < en; ++j)
    a0 += ealpha_n[(size_t)j * 4 + h] * out_e[(size_t)neid[j] * 128 + t];
  float val = rd * (a0 + a1 + a2 + a3) + bias1[t];
  hout[(size_t)v * 128 + t] = val > 0.f ? val : expm1f(val);
}

// oe_pre[e,t] = Binv[e] * sum_i h[node_i, t]
__global__ __launch_bounds__(128) void edge_aggregate2(const float* __restrict__ hfeat,
                                                       const float* __restrict__ binv,
                                                       const int* __restrict__ enid,
                                                       const unsigned* __restrict__ eoff,
                                                       float* __restrict__ oe) {
  __shared__ int nid[ECH];
  int e = blockIdx.x, t = threadIdx.x;
  unsigned s = eoff[e], en = eoff[e + 1];
  float a0 = 0.f, a1 = 0.f, a2 = 0.f, a3 = 0.f;
  float a4 = 0.f, a5 = 0.f, a6 = 0.f, a7 = 0.f;
  for (unsigned base = s; base < en; base += ECH) {
    int cnt = (int)min((unsigned)ECH, en - base);
    __syncthreads();
    for (int c = t; c < cnt; c += 128) nid[c] = enid[base + c];
    __syncthreads();
    int c = 0;
    for (; c + 8 <= cnt; c += 8) {
      a0 += hfeat[(size_t)nid[c + 0] * 128 + t];
      a1 += hfeat[(size_t)nid[c + 1] * 128 + t];
      a2 += hfeat[(size_t)nid[c + 2] * 128 + t];
      a3 += hfeat[(size_t)nid[c + 3] * 128 + t];
      a4 += hfeat[(size_t)nid[c + 4] * 128 + t];
      a5 += hfeat[(size_t)nid[c + 5] * 128 + t];
      a6 += hfeat[(size_t)nid[c + 6] * 128 + t];
      a7 += hfeat[(size_t)nid[c + 7] * 128 + t];
    }
    for (; c < cnt; ++c) a0 += hfeat[(size_t)nid[c] * 128 + t];
  }
  oe[(size_t)e * 128 + t] = binv[e] * (((a0 + a1) + (a2 + a3)) + ((a4 + a5) + (a6 + a7)));
}

// out[v,t] = Dinv[v] * sum_j oe2[neid[j], t] + bias2[t]
__global__ __launch_bounds__(128) void node_aggregate2(const float* __restrict__ oe2,
                                                       const float* __restrict__ dinv,
                                                       const float* __restrict__ bias2,
                                                       const int* __restrict__ neid,
                                                       const unsigned* __restrict__ noff,
                                                       float* __restrict__ out) {
  int v = blockIdx.x, t = threadIdx.x;
  unsigned s = noff[v], en = noff[v + 1];
  float a0 = 0.f, a1 = 0.f, a2 = 0.f, a3 = 0.f;
  unsigned j = s;
  for (; j + 4 <= en; j += 4) {
    int e0 = neid[j], e1 = neid[j + 1], e2 = neid[j + 2], e3 = neid[j + 3];
    a0 += oe2[(size_t)e0 * 128 + t];
    a1 += oe2[(size_t)e1 * 128 + t];
    a2 += oe2[(size_t)e2 * 128 + t];
    a3 += oe2[(size_t)e3 * 128 + t];
  }
  for (; j < en; ++j) a0 += oe2[(size_t)neid[j] * 128 + t];
  out[(size_t)v * 128 + t] = dinv[v] * (a0 + a1 + a2 + a3) + bias2[t];
}

extern "C" void kernel_launch(void* const* d_in, const int* in_sizes, int n_in,
                              void* d_out, int out_size, void* d_ws, size_t ws_size,
                              hipStream_t stream) {
  (void)n_in; (void)out_size; (void)ws_size;
  const float* x      = (const float*)d_in[0];
  const float* hea    = (const float*)d_in[1];
  const float* lin1W  = (const float*)d_in[2];
  const float* helinW = (const float*)d_in[3];
  const float* att1   = (const float*)d_in[4];
  const float* bias1  = (const float*)d_in[5];
  const float* lin2W  = (const float*)d_in[6];
  const float* bias2  = (const float*)d_in[7];
  const int* node_idx = (const int*)d_in[8];
  const int* edge_idx = (const int*)d_in[9];
  float* out = (float*)d_out;

  const int N   = in_sizes[0] / 128;
  const int M   = in_sizes[1] / 128;
  const int NNZ = in_sizes[8];
  const int NBE = (M + 63) >> E_SHIFT;
  const int NBN = (N + 127) >> N_SHIFT;

  char* base = (char*)d_ws;
  size_t off = 0;
  auto alloc = [&](size_t bytes) -> char* {
    char* p = base + off;
    off = (off + bytes + 255) & ~(size_t)255;
    return p;
  };
  float* x1    = (float*)alloc((size_t)N * 128 * 4);  // x1; later oe2 (M rows)
  float* hbuf  = (float*)alloc((size_t)N * 128 * 4);  // h
  float* heoe  = (float*)alloc((size_t)M * 128 * 4);  // out_e -> oe_pre
  float* ai    = (float*)alloc((size_t)N * 4 * 4);
  float* aj    = (float*)alloc((size_t)M * 4 * 4);
  float* u     = (float*)alloc(512 * 4);
  float* WT1   = (float*)alloc(128 * 128 * 4);
  float* WT2   = (float*)alloc(128 * 128 * 4);
  float* dinv  = (float*)alloc((size_t)N * 4);
  float* binv  = (float*)alloc((size_t)M * 4);
  float* rden  = (float*)alloc((size_t)N * 4 * 4);
  char* zstart = base + off;                           // ---- zeroed region ----
  unsigned* bcnt_e = (unsigned*)alloc((size_t)NBE * 4);
  unsigned* bcnt_n = (unsigned*)alloc((size_t)NBN * 4);
  size_t zbytes = (size_t)((base + off) - zstart);     // ---- end zero region ----
  float* ealpha_e = (float*)alloc((size_t)NNZ * 4 * 4);
  float* ealpha_n = (float*)alloc((size_t)NNZ * 4 * 4);
  unsigned* tmp_e = (unsigned*)alloc((size_t)NNZ * 4);
  unsigned* tmp_n = (unsigned*)alloc((size_t)NNZ * 4);
  unsigned* noff  = (unsigned*)alloc((size_t)(N + 1) * 4);
  unsigned* eoff  = (unsigned*)alloc((size_t)(M + 1) * 4);
  unsigned* bbase_e = (unsigned*)alloc((size_t)(NBE + 1) * 4);
  unsigned* bbase_n = (unsigned*)alloc((size_t)(NBN + 1) * 4);
  unsigned* bcur_e = (unsigned*)alloc((size_t)NBE * 4);
  unsigned* bcur_n = (unsigned*)alloc((size_t)NBN * 4);
  int* enid       = (int*)alloc((size_t)NNZ * 4);
  int* neid       = (int*)alloc((size_t)NNZ * 4);

  hipMemsetAsync(zstart, 0, zbytes, stream);

  const int g_pchunk = (NNZ + PCHUNK - 1) / PCHUNK;
  bucket_count<<<g_pchunk, 256, 0, stream>>>(node_idx, edge_idx, bcnt_e, bcnt_n, NNZ);
  bucket_scan<<<1, 1024, 0, stream>>>(bcnt_e, bcnt_n, bbase_e, bcur_e, bbase_n, bcur_n,
                                      eoff, noff, NBE, NBN, M, N, NNZ);
  partition2<<<g_pchunk, 256, 0, stream>>>(node_idx, edge_idx, bcur_e, bcur_n,
                                           tmp_e, tmp_n, NNZ);

  wtrans<<<64, 256, 0, stream>>>(lin1W, WT1);
  wtrans<<<64, 256, 0, stream>>>(lin2W, WT2);
  gemm128t<<<(N + GM - 1) / GM, 256, 0, stream>>>(x, WT1, x1, N, att1, ai);
  make_u<<<2, 256, 0, stream>>>(helinW, att1, u);
  att_dot_full<<<(M * 4 + 255) / 256, 256, 0, stream>>>(hea, u, aj, M);

  sort_edge_exp<<<NBE, 256, 0, stream>>>(tmp_e, bbase_e, M, ai, aj, ealpha_e, enid,
                                         eoff, binv);
  sort_node_exp<<<NBN, 256, 0, stream>>>(tmp_n, bbase_n, N, ai, aj, ealpha_n, neid,
                                         noff, dinv);
  node_denom2<<<(N + 255) / 256, 256, 0, stream>>>(noff, ealpha_n, rden, N);

  edge_aggregate1<<<M, 128, 0, stream>>>(x1, ealpha_e, rden, binv, enid, eoff, heoe);
  node_aggregate1<<<N, 128, 0, stream>>>(heoe, ealpha_n, rden, dinv, bias1, neid, noff, hbuf);

  edge_aggregate2<<<M, 128, 0, stream>>>(hbuf, binv, enid, eoff, heoe);
  gemm128t<<<(M + GM - 1) / GM, 256, 0, stream>>>(heoe, WT2, x1, M, nullptr, nullptr);
  node_aggregate2<<<N, 128, 0, stream>>>(x1, dinv, bias2, neid, noff, out);
}

// Round 9
// 472.407 us; speedup vs baseline: 2.1878x; 1.0345x over previous
//
#include <hip/hip_runtime.h>
#include <cstdint>

// ---------------------------------------------------------------------------
// HCHA (hypergraph conv with attention), f32.
// N=100000 nodes, M=20000 hyperedges, NNZ=1e6, C=128, HEADS=4, FH=32.
// CSR build: bucket_count -> 1-block bucket_scan -> block-local multi-split
// partition -> per-bucket LDS counting sort (emits eoff/noff/binv/dinv).
// sort_node runs first so node_denom produces rden; sort_edge then emits
// PRE-NORMALIZED alpha (ealpha * rden[n] * Binv[e]) in edge order.
// Aggregations: float4 gathers, 4 quarters x 32 lanes per block, 4-deep
// unroll, LDS cross-quarter reduce (no per-chunk staging barriers).
// GEMM: A-tile row-major in LDS, W^T pre-transposed, ai head-dot fused.
// Packing: e < 2^15 (M=20000), n < 2^17 (N=1e5).
// ---------------------------------------------------------------------------

#define E_SHIFT 6
#define N_SHIFT 7
#define EB_CAP 4096
#define NB_CAP 2048
#define PCHUNK 4096
#define NBE_CAP 320   // >= ceil(M/64)  = 313
#define NBN_CAP 800   // >= ceil(N/128) = 782

__device__ __forceinline__ unsigned wave_incl_scan(unsigned x) {
#pragma unroll
  for (int s = 1; s < 64; s <<= 1) {
    unsigned t = __shfl_up(x, s, 64);
    if ((int)(threadIdx.x & 63) >= s) x += t;
  }
  return x;
}

// pass A: per-block LDS bucket histogram -> one global atomicAdd per
// (block,bucket). No per-id atomics.
__global__ __launch_bounds__(256) void bucket_count(const int* __restrict__ node_idx,
                                                    const int* __restrict__ edge_idx,
                                                    unsigned* __restrict__ bcnt_e,
                                                    unsigned* __restrict__ bcnt_n, int nnz) {
  __shared__ unsigned he[NBE_CAP];
  __shared__ unsigned hn[NBN_CAP];
  const int t = threadIdx.x;
  const int base = blockIdx.x * PCHUNK;
  const int cnt = min(PCHUNK, nnz - base);
  for (int b = t; b < NBE_CAP; b += 256) he[b] = 0;
  for (int b = t; b < NBN_CAP; b += 256) hn[b] = 0;
  __syncthreads();
  for (int idx = t; idx < cnt; idx += 256) {
    unsigned e = (unsigned)edge_idx[base + idx];
    unsigned n = (unsigned)node_idx[base + idx];
    atomicAdd(&he[e >> E_SHIFT], 1u);
    atomicAdd(&hn[n >> N_SHIFT], 1u);
  }
  __syncthreads();
  for (int b = t; b < NBE_CAP; b += 256) if (he[b]) atomicAdd(&bcnt_e[b], he[b]);
  for (int b = t; b < NBN_CAP; b += 256) if (hn[b]) atomicAdd(&bcnt_n[b], hn[b]);
}

// single block: exclusive-scan bucket totals -> bucket bases + cursors;
// also writes eoff[M]=noff[N]=NNZ.
__global__ __launch_bounds__(1024) void bucket_scan(const unsigned* __restrict__ bcnt_e,
                                                    const unsigned* __restrict__ bcnt_n,
                                                    unsigned* __restrict__ bbase_e,
                                                    unsigned* __restrict__ bcur_e,
                                                    unsigned* __restrict__ bbase_n,
                                                    unsigned* __restrict__ bcur_n,
                                                    unsigned* __restrict__ eoff,
                                                    unsigned* __restrict__ noff,
                                                    int nbe, int nbn, int M_, int N_, int nnz) {
  __shared__ unsigned wsum[16];
  const int i = threadIdx.x;
  const int lane = i & 63, wid = i >> 6;
  {
    unsigned v = (i < nbe) ? bcnt_e[i] : 0u;
    unsigned incl = wave_incl_scan(v);
    if (lane == 63) wsum[wid] = incl;
    __syncthreads();
    unsigned add = 0;
    for (int w = 0; w < wid; ++w) add += wsum[w];
    unsigned excl = add + incl - v;
    if (i <= nbe) bbase_e[i] = excl;
    if (i < nbe) bcur_e[i] = excl;
    __syncthreads();
  }
  {
    unsigned v = (i < nbn) ? bcnt_n[i] : 0u;
    unsigned incl = wave_incl_scan(v);
    if (lane == 63) wsum[wid] = incl;
    __syncthreads();
    unsigned add = 0;
    for (int w = 0; w < wid; ++w) add += wsum[w];
    unsigned excl = add + incl - v;
    if (i <= nbn) bbase_n[i] = excl;
    if (i < nbn) bcur_n[i] = excl;
  }
  if (i == 0) { eoff[M_] = (unsigned)nnz; noff[N_] = (unsigned)nnz; }
}

// pass B: block-local multi-split. LDS histogram -> one global atomic per
// (block,bucket) to reserve ranges -> LDS-cursor scatter of u32 payloads.
__global__ __launch_bounds__(256) void partition2(const int* __restrict__ node_idx,
                                                  const int* __restrict__ edge_idx,
                                                  unsigned* __restrict__ bcur_e,
                                                  unsigned* __restrict__ bcur_n,
                                                  unsigned* __restrict__ tmp_e,
                                                  unsigned* __restrict__ tmp_n, int nnz) {
  __shared__ unsigned he[NBE_CAP];
  __shared__ unsigned hn[NBN_CAP];
  const int t = threadIdx.x;
  const int base = blockIdx.x * PCHUNK;
  const int cnt = min(PCHUNK, nnz - base);

  for (int b = t; b < NBE_CAP; b += 256) he[b] = 0;
  for (int b = t; b < NBN_CAP; b += 256) hn[b] = 0;
  __syncthreads();

  for (int idx = t; idx < cnt; idx += 256) {
    unsigned e = (unsigned)edge_idx[base + idx];
    unsigned n = (unsigned)node_idx[base + idx];
    atomicAdd(&he[e >> E_SHIFT], 1u);
    atomicAdd(&hn[n >> N_SHIFT], 1u);
  }
  __syncthreads();

  for (int b = t; b < NBE_CAP; b += 256) {
    unsigned c = he[b];
    he[b] = c ? atomicAdd(&bcur_e[b], c) : 0u;   // bucket range base -> cursor
  }
  for (int b = t; b < NBN_CAP; b += 256) {
    unsigned c = hn[b];
    hn[b] = c ? atomicAdd(&bcur_n[b], c) : 0u;
  }
  __syncthreads();

  for (int idx = t; idx < cnt; idx += 256) {
    unsigned e = (unsigned)edge_idx[base + idx];
    unsigned n = (unsigned)node_idx[base + idx];
    unsigned pe = atomicAdd(&he[e >> E_SHIFT], 1u);
    tmp_e[pe] = ((e & 63u) << 17) | n;
    unsigned pn = atomicAdd(&hn[n >> N_SHIFT], 1u);
    tmp_n[pn] = ((n & 127u) << 15) | e;
  }
}

__device__ __forceinline__ float4 alpha4(const float* __restrict__ ai,
                                         const float* __restrict__ aj,
                                         unsigned n, unsigned e) {
  float4 av = *(const float4*)&ai[(size_t)n * 4];
  float4 bv = *(const float4*)&aj[(size_t)e * 4];
  float v0 = av.x + bv.x, v1 = av.y + bv.y, v2 = av.z + bv.z, v3 = av.w + bv.w;
  v0 = v0 > 0.f ? v0 : 0.2f * v0;
  v1 = v1 > 0.f ? v1 : 0.2f * v1;
  v2 = v2 > 0.f ? v2 : 0.2f * v2;
  v3 = v3 > 0.f ? v3 : 0.2f * v3;
  return make_float4(expf(v0), expf(v1), expf(v2), expf(v3));
}

// pass C (nodes): per-bucket sort; emits noff/dinv + node-ordered edge ids
// and RAW alpha stream (rden is derived from this afterwards).
__global__ __launch_bounds__(256) void sort_node_exp(const unsigned* __restrict__ tmp,
                                                     const unsigned* __restrict__ bbase,
                                                     int N_,
                                                     const float* __restrict__ ai,
                                                     const float* __restrict__ aj,
                                                     float* __restrict__ ealpha_n,
                                                     int* __restrict__ neid,
                                                     unsigned* __restrict__ noff,
                                                     float* __restrict__ dinv) {
  __shared__ unsigned cur[128];
  __shared__ unsigned sbuf[NB_CAP];
  __shared__ unsigned wtot;
  int b = blockIdx.x, t = threadIdx.x;
  int n0 = b << N_SHIFT;
  unsigned base = bbase[b];
  int cnt = (int)(bbase[b + 1] - base);
  if (t < 128) cur[t] = 0;
  __syncthreads();
  for (int idx = t; idx < cnt; idx += 256) {
    unsigned key = tmp[base + idx] >> 15;
    atomicAdd(&cur[key], 1u);
  }
  __syncthreads();
  {  // exclusive scan of 128 counts across waves 0..1
    unsigned c = (t < 128) ? cur[t] : 0u;
    unsigned incl = wave_incl_scan(c);
    if (t == 63) wtot = incl;
    __syncthreads();
    unsigned excl = incl - c + ((t >= 64 && t < 128) ? wtot : 0u);
    if (t < 128) {
      int n = n0 + t;
      if (n < N_) {
        noff[n] = base + excl;
        dinv[n] = c ? 1.f / (float)c : 0.f;
      }
      cur[t] = excl;
    }
  }
  __syncthreads();
  for (int idx = t; idx < cnt; idx += 256) {
    unsigned p = tmp[base + idx];
    unsigned key = p >> 15;
    unsigned pos = atomicAdd(&cur[key], 1u);
    if (pos < NB_CAP) {
      sbuf[pos] = p;
    } else {
      unsigned e = p & 0x7FFFu;
      *(float4*)&ealpha_n[(size_t)(base + pos) * 4] = alpha4(ai, aj, n0 + key, e);
      neid[base + pos] = (int)e;
    }
  }
  __syncthreads();
  int lim = min(cnt, NB_CAP);
  for (int idx = t; idx < lim; idx += 256) {
    unsigned p = sbuf[idx];
    unsigned key = p >> 15, e = p & 0x7FFFu;
    *(float4*)&ealpha_n[(size_t)(base + idx) * 4] = alpha4(ai, aj, n0 + key, e);
    neid[base + idx] = (int)e;
  }
}

// rden[v,h] = 1/(sum_{j in node range} ealpha_n[j,h] + 1e-16), sequential read
__global__ __launch_bounds__(256) void node_denom2(const unsigned* __restrict__ noff,
                                                   const float* __restrict__ ealpha_n,
                                                   float* __restrict__ rden, int N) {
  int v = blockIdx.x * 256 + threadIdx.x;
  if (v >= N) return;
  unsigned s = noff[v], en = noff[v + 1];
  float x = 0.f, y = 0.f, z = 0.f, w = 0.f;
  for (unsigned j = s; j < en; ++j) {
    float4 a = *(const float4*)&ealpha_n[(size_t)j * 4];
    x += a.x; y += a.y; z += a.z; w += a.w;
  }
  *(float4*)&rden[(size_t)v * 4] = make_float4(1.f / (x + 1e-16f), 1.f / (y + 1e-16f),
                                               1.f / (z + 1e-16f), 1.f / (w + 1e-16f));
}

// pass C (edges): per-bucket LDS counting sort; emits eoff/binv + coalesced
// edge-ordered node ids + PRE-NORMALIZED alpha (ealpha * rden[n] * binv[e]).
__global__ __launch_bounds__(256) void sort_edge_exp(const unsigned* __restrict__ tmp,
                                                     const unsigned* __restrict__ bbase,
                                                     int M_,
                                                     const float* __restrict__ ai,
                                                     const float* __restrict__ aj,
                                                     const float* __restrict__ rden,
                                                     float* __restrict__ alpha_e,
                                                     int* __restrict__ enid,
                                                     unsigned* __restrict__ eoff,
                                                     float* __restrict__ binv) {
  __shared__ unsigned cur[64];
  __shared__ float binv_s[64];
  __shared__ unsigned sbuf[EB_CAP];
  int b = blockIdx.x, t = threadIdx.x;
  int e0 = b << E_SHIFT;
  unsigned base = bbase[b];
  int cnt = (int)(bbase[b + 1] - base);
  if (t < 64) cur[t] = 0;
  __syncthreads();
  for (int idx = t; idx < cnt; idx += 256) {
    unsigned key = tmp[base + idx] >> 17;
    atomicAdd(&cur[key], 1u);
  }
  __syncthreads();
  {  // local exclusive scan of 64 counts (wave 0 relevant)
    unsigned c = (t < 64) ? cur[t] : 0u;
    unsigned incl = wave_incl_scan(c);
    unsigned excl = incl - c;
    if (t < 64) {
      float bv = c ? 1.f / (float)c : 0.f;
      binv_s[t] = bv;
      int e = e0 + t;
      if (e < M_) {
        eoff[e] = base + excl;
        binv[e] = bv;
      }
      cur[t] = excl;  // becomes the placement cursor
    }
  }
  __syncthreads();
  for (int idx = t; idx < cnt; idx += 256) {
    unsigned p = tmp[base + idx];
    unsigned key = p >> 17;
    unsigned pos = atomicAdd(&cur[key], 1u);
    if (pos < EB_CAP) {
      sbuf[pos] = p;
    } else {  // overflow fallback (statistically never): pos is final slot
      unsigned n = p & 0x1FFFFu;
      float4 al = alpha4(ai, aj, n, e0 + key);
      float4 rd = *(const float4*)&rden[(size_t)n * 4];
      float bv = binv_s[key];
      *(float4*)&alpha_e[(size_t)(base + pos) * 4] =
          make_float4(al.x * rd.x * bv, al.y * rd.y * bv, al.z * rd.z * bv, al.w * rd.w * bv);
      enid[base + pos] = (int)n;
    }
  }
  __syncthreads();
  int lim = min(cnt, EB_CAP);
  for (int idx = t; idx < lim; idx += 256) {
    unsigned p = sbuf[idx];
    unsigned key = p >> 17, n = p & 0x1FFFFu;
    float4 al = alpha4(ai, aj, n, e0 + key);
    float4 rd = *(const float4*)&rden[(size_t)n * 4];
    float bv = binv_s[key];
    *(float4*)&alpha_e[(size_t)(base + idx) * 4] =
        make_float4(al.x * rd.x * bv, al.y * rd.y * bv, al.z * rd.z * bv, al.w * rd.w * bv);
    enid[base + idx] = (int)n;
  }
}

// WT[k*128+o] = W[o*128+k]   (one-time 64KB transpose)
__global__ __launch_bounds__(256) void wtrans(const float* __restrict__ W,
                                              float* __restrict__ WT) {
  int idx = blockIdx.x * 256 + threadIdx.x;
  if (idx >= 128 * 128) return;
  int k = idx >> 7, o = idx & 127;
  WT[idx] = W[o * 128 + k];
}

// C[r,o] = sum_k A[r,k] * WT[k,o]; A rows x 128, WT 128x128 (pre-transposed).
// A-tile row-major in LDS: staging coalesced & conflict-free; reads broadcast.
// Optional fused head-dot epilogue: aiout[r,h] = sum_f C[r,h*32+f]*att[h*64+f].
#define GM 64
__global__ __launch_bounds__(256) void gemm128t(const float* __restrict__ A,
                                                const float* __restrict__ WT,
                                                float* __restrict__ C, int rows,
                                                const float* __restrict__ att,
                                                float* __restrict__ aiout) {
  __shared__ __align__(16) float Ast[GM][132];  // row-major, pad 132
  const int tid = threadIdx.x;
  const int row0 = blockIdx.x * GM;

  for (int idx = tid; idx < GM * 32; idx += 256) {  // float4-granular staging
    int r = idx >> 5, kq = idx & 31;
    int gr = row0 + r;
    float4 v = (gr < rows) ? *(const float4*)&A[(size_t)gr * 128 + kq * 4]
                           : make_float4(0.f, 0.f, 0.f, 0.f);
    *(float4*)&Ast[r][kq * 4] = v;
  }
  __syncthreads();

  const int tr = tid >> 5, tc = tid & 31;
  const int r0 = tr * 8, c0 = tc * 4;
  float acc[8][4] = {{0.f}};

  for (int k = 0; k < 128; k += 4) {
    float4 b0 = *(const float4*)&WT[(k + 0) * 128 + c0];
    float4 b1 = *(const float4*)&WT[(k + 1) * 128 + c0];
    float4 b2 = *(const float4*)&WT[(k + 2) * 128 + c0];
    float4 b3 = *(const float4*)&WT[(k + 3) * 128 + c0];
#pragma unroll
    for (int i = 0; i < 8; ++i) {
      float4 a = *(const float4*)&Ast[r0 + i][k];  // broadcast read
      acc[i][0] += a.x * b0.x; acc[i][1] += a.x * b0.y; acc[i][2] += a.x * b0.z; acc[i][3] += a.x * b0.w;
      acc[i][0] += a.y * b1.x; acc[i][1] += a.y * b1.y; acc[i][2] += a.y * b1.z; acc[i][3] += a.y * b1.w;
      acc[i][0] += a.z * b2.x; acc[i][1] += a.z * b2.y; acc[i][2] += a.z * b2.z; acc[i][3] += a.z * b2.w;
      acc[i][0] += a.w * b3.x; acc[i][1] += a.w * b3.y; acc[i][2] += a.w * b3.z; acc[i][3] += a.w * b3.w;
    }
  }

#pragma unroll
  for (int i = 0; i < 8; ++i) {
    int gr = row0 + r0 + i;
    if (gr < rows)
      *(float4*)&C[(size_t)gr * 128 + c0] = make_float4(acc[i][0], acc[i][1], acc[i][2], acc[i][3]);
  }

  if (att) {  // fused ai head-dot: cols c0..c0+3 all in head h = tc>>3
    int h = tc >> 3;
    float4 w = *(const float4*)&att[h * 64 + (c0 & 31)];
#pragma unroll
    for (int i = 0; i < 8; ++i) {
      float p = acc[i][0] * w.x + acc[i][1] * w.y + acc[i][2] * w.z + acc[i][3] * w.w;
      p += __shfl_xor(p, 1);
      p += __shfl_xor(p, 2);
      p += __shfl_xor(p, 4);
      if ((tc & 7) == 0) {
        int gr = row0 + r0 + i;
        if (gr < rows) aiout[(size_t)gr * 4 + h] = p;
      }
    }
  }
}

// u[h,k] = sum_f att1[h*64+32+f] * W_he[(h*32+f)*128 + k]
__global__ __launch_bounds__(256) void make_u(const float* __restrict__ W_he,
                                              const float* __restrict__ att1,
                                              float* __restrict__ u) {
  int idx = blockIdx.x * 256 + threadIdx.x;
  if (idx >= 512) return;
  int h = idx >> 7, k = idx & 127;
  float s = 0.f;
#pragma unroll
  for (int f = 0; f < 32; ++f)
    s += att1[h * 64 + 32 + f] * W_he[(size_t)(h * 32 + f) * 128 + k];
  u[h * 128 + k] = s;
}

// aj[e,h] = hea[e,:] . u[h,:]
__global__ __launch_bounds__(256) void att_dot_full(const float* __restrict__ feat,
                                                    const float* __restrict__ u,
                                                    float* __restrict__ outv, int rows) {
  int idx = blockIdx.x * 256 + threadIdx.x;
  if (idx >= rows * 4) return;
  int v = idx >> 2, h = idx & 3;
  const float4* fp = (const float4*)(feat + (size_t)v * 128);
  const float4* up = (const float4*)(u + h * 128);
  float s = 0.f;
#pragma unroll
  for (int q = 0; q < 32; ++q) {
    float4 a = up[q], f = fp[q];
    s += a.x * f.x + a.y * f.y + a.z * f.z + a.w * f.w;
  }
  outv[idx] = s;
}

// out_e[e,:] = sum_i alpha_pre[i,h] * x1[node_i,:]   (alpha pre-normalized)
// 4 quarters x 32 lanes; lane loads float4 (full 512B row per quarter).
__global__ __launch_bounds__(128) void edge_aggregate1(const float* __restrict__ x1,
                                                       const float* __restrict__ alpha_e,
                                                       const int* __restrict__ enid,
                                                       const unsigned* __restrict__ eoff,
                                                       float* __restrict__ out_e) {
  __shared__ float red[4][128];
  const int e = blockIdx.x, t = threadIdx.x;
  const int q = t >> 5, l = t & 31, hh = l >> 3;
  const unsigned s = eoff[e], en = eoff[e + 1];
  float4 A0 = make_float4(0.f, 0.f, 0.f, 0.f), A1 = A0, A2 = A0, A3 = A0;
  unsigned j = s + q;
  for (; j + 12 < en; j += 16) {
    int n0 = enid[j], n1 = enid[j + 4], n2 = enid[j + 8], n3 = enid[j + 12];
    float w0 = alpha_e[(size_t)j * 4 + hh];
    float w1 = alpha_e[(size_t)(j + 4) * 4 + hh];
    float w2 = alpha_e[(size_t)(j + 8) * 4 + hh];
    float w3 = alpha_e[(size_t)(j + 12) * 4 + hh];
    float4 a0 = *(const float4*)&x1[(size_t)n0 * 128 + l * 4];
    float4 a1 = *(const float4*)&x1[(size_t)n1 * 128 + l * 4];
    float4 a2 = *(const float4*)&x1[(size_t)n2 * 128 + l * 4];
    float4 a3 = *(const float4*)&x1[(size_t)n3 * 128 + l * 4];
    A0.x += w0 * a0.x; A0.y += w0 * a0.y; A0.z += w0 * a0.z; A0.w += w0 * a0.w;
    A1.x += w1 * a1.x; A1.y += w1 * a1.y; A1.z += w1 * a1.z; A1.w += w1 * a1.w;
    A2.x += w2 * a2.x; A2.y += w2 * a2.y; A2.z += w2 * a2.z; A2.w += w2 * a2.w;
    A3.x += w3 * a3.x; A3.y += w3 * a3.y; A3.z += w3 * a3.z; A3.w += w3 * a3.w;
  }
  for (; j < en; j += 4) {
    int n = enid[j];
    float w = alpha_e[(size_t)j * 4 + hh];
    float4 a = *(const float4*)&x1[(size_t)n * 128 + l * 4];
    A0.x += w * a.x; A0.y += w * a.y; A0.z += w * a.z; A0.w += w * a.w;
  }
  float4 A = make_float4((A0.x + A1.x) + (A2.x + A3.x), (A0.y + A1.y) + (A2.y + A3.y),
                         (A0.z + A1.z) + (A2.z + A3.z), (A0.w + A1.w) + (A2.w + A3.w));
  *(float4*)&red[q][l * 4] = A;
  __syncthreads();
  out_e[(size_t)e * 128 + t] = red[0][t] + red[1][t] + red[2][t] + red[3][t];
}

// h[v,:] = elu(Dinv[v]*rden[v,h] * sum_j ealpha_n[j,h]*out_e[neid[j],:] + bias1)
__global__ __launch_bounds__(128) void node_aggregate1(const float* __restrict__ out_e,
                                                       const float* __restrict__ ealpha_n,
                                                       const float* __restrict__ rden,
                                                       const float* __restrict__ dinv,
                                                       const float* __restrict__ bias1,
                                                       const int* __restrict__ neid,
                                                       const unsigned* __restrict__ noff,
                                                       float* __restrict__ hout) {
  __shared__ float red[4][128];
  const int v = blockIdx.x, t = threadIdx.x;
  const int q = t >> 5, l = t & 31, hh = l >> 3;
  const unsigned s = noff[v], en = noff[v + 1];
  float4 A0 = make_float4(0.f, 0.f, 0.f, 0.f), A1 = A0;
  unsigned j = s + q;
  for (; j + 4 < en; j += 8) {
    int e0 = neid[j], e1 = neid[j + 4];
    float w0 = ealpha_n[(size_t)j * 4 + hh];
    float w1 = ealpha_n[(size_t)(j + 4) * 4 + hh];
    float4 a0 = *(const float4*)&out_e[(size_t)e0 * 128 + l * 4];
    float4 a1 = *(const float4*)&out_e[(size_t)e1 * 128 + l * 4];
    A0.x += w0 * a0.x; A0.y += w0 * a0.y; A0.z += w0 * a0.z; A0.w += w0 * a0.w;
    A1.x += w1 * a1.x; A1.y += w1 * a1.y; A1.z += w1 * a1.z; A1.w += w1 * a1.w;
  }
  for (; j < en; j += 4) {
    int e0 = neid[j];
    float w = ealpha_n[(size_t)j * 4 + hh];
    float4 a = *(const float4*)&out_e[(size_t)e0 * 128 + l * 4];
    A0.x += w * a.x; A0.y += w * a.y; A0.z += w * a.z; A0.w += w * a.w;
  }
  float4 A = make_float4(A0.x + A1.x, A0.y + A1.y, A0.z + A1.z, A0.w + A1.w);
  *(float4*)&red[q][l * 4] = A;
  __syncthreads();
  float rd = dinv[v] * rden[(size_t)v * 4 + (t >> 5)];
  float val = rd * (red[0][t] + red[1][t] + red[2][t] + red[3][t]) + bias1[t];
  hout[(size_t)v * 128 + t] = val > 0.f ? val : expm1f(val);
}

// oe[e,:] = Binv[e] * sum_i h[node_i,:]
__global__ __launch_bounds__(128) void edge_aggregate2(const float* __restrict__ hfeat,
                                                       const float* __restrict__ binv,
                                                       const int* __restrict__ enid,
                                                       const unsigned* __restrict__ eoff,
                                                       float* __restrict__ oe) {
  __shared__ float red[4][128];
  const int e = blockIdx.x, t = threadIdx.x;
  const int q = t >> 5, l = t & 31;
  const unsigned s = eoff[e], en = eoff[e + 1];
  float4 A0 = make_float4(0.f, 0.f, 0.f, 0.f), A1 = A0, A2 = A0, A3 = A0;
  unsigned j = s + q;
  for (; j + 12 < en; j += 16) {
    int n0 = enid[j], n1 = enid[j + 4], n2 = enid[j + 8], n3 = enid[j + 12];
    float4 a0 = *(const float4*)&hfeat[(size_t)n0 * 128 + l * 4];
    float4 a1 = *(const float4*)&hfeat[(size_t)n1 * 128 + l * 4];
    float4 a2 = *(const float4*)&hfeat[(size_t)n2 * 128 + l * 4];
    float4 a3 = *(const float4*)&hfeat[(size_t)n3 * 128 + l * 4];
    A0.x += a0.x; A0.y += a0.y; A0.z += a0.z; A0.w += a0.w;
    A1.x += a1.x; A1.y += a1.y; A1.z += a1.z; A1.w += a1.w;
    A2.x += a2.x; A2.y += a2.y; A2.z += a2.z; A2.w += a2.w;
    A3.x += a3.x; A3.y += a3.y; A3.z += a3.z; A3.w += a3.w;
  }
  for (; j < en; j += 4) {
    int n = enid[j];
    float4 a = *(const float4*)&hfeat[(size_t)n * 128 + l * 4];
    A0.x += a.x; A0.y += a.y; A0.z += a.z; A0.w += a.w;
  }
  float4 A = make_float4((A0.x + A1.x) + (A2.x + A3.x), (A0.y + A1.y) + (A2.y + A3.y),
                         (A0.z + A1.z) + (A2.z + A3.z), (A0.w + A1.w) + (A2.w + A3.w));
  *(float4*)&red[q][l * 4] = A;
  __syncthreads();
  oe[(size_t)e * 128 + t] = binv[e] * (red[0][t] + red[1][t] + red[2][t] + red[3][t]);
}

// out[v,:] = Dinv[v] * sum_j oe2[neid[j],:] + bias2
__global__ __launch_bounds__(128) void node_aggregate2(const float* __restrict__ oe2,
                                                       const float* __restrict__ dinv,
                                                       const float* __restrict__ bias2,
                                                       const int* __restrict__ neid,
                                                       const unsigned* __restrict__ noff,
                                                       float* __restrict__ out) {
  __shared__ float red[4][128];
  const int v = blockIdx.x, t = threadIdx.x;
  const int q = t >> 5, l = t & 31;
  const unsigned s = noff[v], en = noff[v + 1];
  float4 A0 = make_float4(0.f, 0.f, 0.f, 0.f), A1 = A0;
  unsigned j = s + q;
  for (; j + 4 < en; j += 8) {
    int e0 = neid[j], e1 = neid[j + 4];
    float4 a0 = *(const float4*)&oe2[(size_t)e0 * 128 + l * 4];
    float4 a1 = *(const float4*)&oe2[(size_t)e1 * 128 + l * 4];
    A0.x += a0.x; A0.y += a0.y; A0.z += a0.z; A0.w += a0.w;
    A1.x += a1.x; A1.y += a1.y; A1.z += a1.z; A1.w += a1.w;
  }
  for (; j < en; j += 4) {
    int e0 = neid[j];
    float4 a = *(const float4*)&oe2[(size_t)e0 * 128 + l * 4];
    A0.x += a.x; A0.y += a.y; A0.z += a.z; A0.w += a.w;
  }
  float4 A = make_float4(A0.x + A1.x, A0.y + A1.y, A0.z + A1.z, A0.w + A1.w);
  *(float4*)&red[q][l * 4] = A;
  __syncthreads();
  out[(size_t)v * 128 + t] = dinv[v] * (red[0][t] + red[1][t] + red[2][t] + red[3][t]) + bias2[t];
}

extern "C" void kernel_launch(void* const* d_in, const int* in_sizes, int n_in,
                              void* d_out, int out_size, void* d_ws, size_t ws_size,
                              hipStream_t stream) {
  (void)n_in; (void)out_size; (void)ws_size;
  const float* x      = (const float*)d_in[0];
  const float* hea    = (const float*)d_in[1];
  const float* lin1W  = (const float*)d_in[2];
  const float* helinW = (const float*)d_in[3];
  const float* att1   = (const float*)d_in[4];
  const float* bias1  = (const float*)d_in[5];
  const float* lin2W  = (const float*)d_in[6];
  const float* bias2  = (const float*)d_in[7];
  const int* node_idx = (const int*)d_in[8];
  const int* edge_idx = (const int*)d_in[9];
  float* out = (float*)d_out;

  const int N   = in_sizes[0] / 128;
  const int M   = in_sizes[1] / 128;
  const int NNZ = in_sizes[8];
  const int NBE = (M + 63) >> E_SHIFT;
  const int NBN = (N + 127) >> N_SHIFT;

  char* base = (char*)d_ws;
  size_t off = 0;
  auto alloc = [&](size_t bytes) -> char* {
    char* p = base + off;
    off = (off + bytes + 255) & ~(size_t)255;
    return p;
  };
  float* x1    = (float*)alloc((size_t)N * 128 * 4);  // x1; later oe2 (M rows)
  float* hbuf  = (float*)alloc((size_t)N * 128 * 4);  // h
  float* heoe  = (float*)alloc((size_t)M * 128 * 4);  // out_e -> oe_pre
  float* ai    = (float*)alloc((size_t)N * 4 * 4);
  float* aj    = (float*)alloc((size_t)M * 4 * 4);
  float* u     = (float*)alloc(512 * 4);
  float* WT1   = (float*)alloc(128 * 128 * 4);
  float* WT2   = (float*)alloc(128 * 128 * 4);
  float* dinv  = (float*)alloc((size_t)N * 4);
  float* binv  = (float*)alloc((size_t)M * 4);
  float* rden  = (float*)alloc((size_t)N * 4 * 4);
  char* zstart = base + off;                           // ---- zeroed region ----
  unsigned* bcnt_e = (unsigned*)alloc((size_t)NBE * 4);
  unsigned* bcnt_n = (unsigned*)alloc((size_t)NBN * 4);
  size_t zbytes = (size_t)((base + off) - zstart);     // ---- end zero region ----
  float* alpha_e  = (float*)alloc((size_t)NNZ * 4 * 4);
  float* ealpha_n = (float*)alloc((size_t)NNZ * 4 * 4);
  unsigned* tmp_e = (unsigned*)alloc((size_t)NNZ * 4);
  unsigned* tmp_n = (unsigned*)alloc((size_t)NNZ * 4);
  unsigned* noff  = (unsigned*)alloc((size_t)(N + 1) * 4);
  unsigned* eoff  = (unsigned*)alloc((size_t)(M + 1) * 4);
  unsigned* bbase_e = (unsigned*)alloc((size_t)(NBE + 1) * 4);
  unsigned* bbase_n = (unsigned*)alloc((size_t)(NBN + 1) * 4);
  unsigned* bcur_e = (unsigned*)alloc((size_t)NBE * 4);
  unsigned* bcur_n = (unsigned*)alloc((size_t)NBN * 4);
  int* enid       = (int*)alloc((size_t)NNZ * 4);
  int* neid       = (int*)alloc((size_t)NNZ * 4);

  hipMemsetAsync(zstart, 0, zbytes, stream);

  const int g_pchunk = (NNZ + PCHUNK - 1) / PCHUNK;
  bucket_count<<<g_pchunk, 256, 0, stream>>>(node_idx, edge_idx, bcnt_e, bcnt_n, NNZ);
  bucket_scan<<<1, 1024, 0, stream>>>(bcnt_e, bcnt_n, bbase_e, bcur_e, bbase_n, bcur_n,
                                      eoff, noff, NBE, NBN, M, N, NNZ);
  partition2<<<g_pchunk, 256, 0, stream>>>(node_idx, edge_idx, bcur_e, bcur_n,
                                           tmp_e, tmp_n, NNZ);

  wtrans<<<64, 256, 0, stream>>>(lin1W, WT1);
  wtrans<<<64, 256, 0, stream>>>(lin2W, WT2);
  gemm128t<<<(N + GM - 1) / GM, 256, 0, stream>>>(x, WT1, x1, N, att1, ai);
  make_u<<<2, 256, 0, stream>>>(helinW, att1, u);
  att_dot_full<<<(M * 4 + 255) / 256, 256, 0, stream>>>(hea, u, aj, M);

  sort_node_exp<<<NBN, 256, 0, stream>>>(tmp_n, bbase_n, N, ai, aj, ealpha_n, neid,
                                         noff, dinv);
  node_denom2<<<(N + 255) / 256, 256, 0, stream>>>(noff, ealpha_n, rden, N);
  sort_edge_exp<<<NBE, 256, 0, stream>>>(tmp_e, bbase_e, M, ai, aj, rden, alpha_e, enid,
                                         eoff, binv);

  edge_aggregate1<<<M, 128, 0, stream>>>(x1, alpha_e, enid, eoff, heoe);
  node_aggregate1<<<N, 128, 0, stream>>>(heoe, ealpha_n, rden, dinv, bias1, neid, noff, hbuf);

  edge_aggregate2<<<M, 128, 0, stream>>>(hbuf, binv, enid, eoff, heoe);
  gemm128t<<<(M + GM - 1) / GM, 256, 0, stream>>>(heoe, WT2, x1, M, nullptr, nullptr);
  node_aggregate2<<<N, 128, 0, stream>>>(x1, dinv, bias2, neid, noff, out);
}